// Round 11
// baseline (476.614 us; speedup 1.0000x reference)
//
#include <hip/hip_runtime.h>

typedef unsigned char  u8;
typedef unsigned short u16;
typedef unsigned int   u32;
typedef __attribute__((ext_vector_type(4))) float f32x4;
typedef __attribute__((ext_vector_type(8))) __bf16 bf16x8;
typedef __attribute__((ext_vector_type(4))) u32  u32x4;
typedef __attribute__((ext_vector_type(2))) u32  u32x2;

__device__ __forceinline__ float bf2f(u16 h){ u32 u = ((u32)h)<<16; return __builtin_bit_cast(float, u); }
__device__ __forceinline__ u16  f2bf(float f){
  u32 u = __builtin_bit_cast(u32, f);
  u32 r = u + 0x7FFFu + ((u>>16)&1u);
  return (u16)(r>>16);
}

typedef const __attribute__((address_space(1))) u32 gas_u32;
typedef __attribute__((address_space(3))) u32 las_u32;
__device__ __forceinline__ void gll16(const void* g, void* l){
  __builtin_amdgcn_global_load_lds((gas_u32*)g, (las_u32*)l, 16, 0, 0);
}

__device__ __forceinline__ f32x4 mfma16(bf16x8 a, bf16x8 b, f32x4 c){
  return __builtin_amdgcn_mfma_f32_16x16x32_bf16(a, b, c, 0, 0, 0);
}

__device__ __forceinline__ bf16x8 ldsr8(const u16* p){
  u32x4 v = *(const u32x4*)p;
  return __builtin_bit_cast(bf16x8, v);
}

// XCD co-locate remap: blocks sharing an A-panel (same m-tile) land on one XCD.
// grid (Mt, Nt), Mt%8==0, (Mt*Nt)%8==0; fid%8 assumed round-robin XCD.
__device__ __forceinline__ void xcd_remap(int &m_idx, int &n_idx){
  const int Mt = gridDim.x;
  const int fid = blockIdx.x + Mt*blockIdx.y;
  const int xcd = fid & 7, k = fid >> 3;
  const int mpx = Mt >> 3;
  m_idx = xcd*mpx + (k % mpx);
  n_idx = k / mpx;
}

// ------- prologue A: batch cvt + weight cvt + conv1 weight repack -------
__global__ __launch_bounds__(256)
void prep_big(const float* __restrict__ batch,
              const float* __restrict__ wq, const float* __restrict__ wk,
              const float* __restrict__ wv, const float* __restrict__ wo,
              const float* __restrict__ w2, const float* __restrict__ w1,
              u16* __restrict__ batchc, u16* __restrict__ wqc, u16* __restrict__ w1r)
{
  const int bid = blockIdx.x, tid = threadIdx.x;
  if (bid < 4096){
    const int i = bid*1024 + tid*4;
    f32x4 v = *(const f32x4*)&batch[i];
    u32x2 o;
    o[0] = (u32)f2bf(v[0]) | ((u32)f2bf(v[1])<<16);
    o[1] = (u32)f2bf(v[2]) | ((u32)f2bf(v[3])<<16);
    *(u32x2*)&batchc[i] = o;
  } else if (bid < 4608){
    const int i = (bid-4096)*1024 + tid*4;
    const float* s; int off;
    if      (i < 65536)  { s = wq; off = i; }
    else if (i < 131072) { s = wk; off = i - 65536; }
    else if (i < 196608) { s = wv; off = i - 131072; }
    else if (i < 262144) { s = wo; off = i - 196608; }
    else                 { s = w2; off = i - 262144; }
    f32x4 v = *(const f32x4*)&s[off];
    u32x2 o;
    o[0] = (u32)f2bf(v[0]) | ((u32)f2bf(v[1])<<16);
    o[1] = (u32)f2bf(v[2]) | ((u32)f2bf(v[3])<<16);
    *(u32x2*)&wqc[i] = o;
  } else {
    const int idx = (bid-4608)*256 + tid;
    const int c = idx / 2304;
    const int t = idx - c*2304;
    const int i = t / 9;
    const int kk = t - i*9;
    w1r[c*2304 + kk*256 + i] = f2bf(w1[idx]);
  }
}

// ------- prologue B: params + mask canon + seq1p halo zero -------
__global__ __launch_bounds__(256)
void prep_small(const float* p0,const float* p1,const float* p2,const float* p3,
                const float* p4,const float* p5,const float* p6,const float* p7,
                const float* p8,const float* p9,
                u16* __restrict__ params, const void* __restrict__ mraw,
                u16* __restrict__ cmask, u16* __restrict__ seq1p)
{
  const int bid = blockIdx.x, tid = threadIdx.x;
  if (bid == 0){
    const float* ps[10] = {p0,p1,p2,p3,p4,p5,p6,p7,p8,p9};
    const int  off[10] = {0,256,512,768,1024,1280,1536,1792,2048,3072};
    const int  len[10] = {256,256,256,256,256,256,256,256,1024,256};
    for (int a=0;a<10;++a)
      for (int i=tid;i<len[a];i+=256)
        params[off[a]+i] = f2bf(ps[a][i]);
  } else if (bid == 1){
    const u8*  pb8  = (const u8*)mraw;
    const u16* pb16 = (const u16*)mraw;
    const u32* pb32 = (const u32*)mraw;
    __shared__ int bad8, bad16, nz8, nz16;
    if (tid==0){ bad8=0; bad16=0; nz8=0; nz16=0; }
    __syncthreads();
    for (int i=tid;i<16384;i+=256){
      u8 v = pb8[i]; int row = i & 2047;
      if (v>1) atomicOr(&bad8,1);
      if (v){ atomicOr(&nz8,1); if (row<1024) atomicOr(&bad8,1); }
      if (row>0 && pb8[i-1]==1 && v==0) atomicOr(&bad8,1);
    }
    for (int i=tid;i<8192;i+=256){
      u16 v = pb16[i]; int row = i & 2047;
      if (!(v==0 || v==0x3F80)) atomicOr(&bad16,1);
      if (v){ atomicOr(&nz16,1); if (row<1024) atomicOr(&bad16,1); }
      if (row>0 && pb16[i-1]==0x3F80 && v==0) atomicOr(&bad16,1);
    }
    __syncthreads();
    const int mode = (!bad8 && nz8) ? 1 : ((!bad16 && nz16) ? 2 : 0);
    for (int i=tid;i<16384;i+=256){
      u16 m;
      if (mode==1)      m = pb8[i]  ? 1 : 0;
      else if (mode==2) m = pb16[i] ? 1 : 0;
      else              m = pb32[i] ? 1 : 0;
      cmask[i] = m;
    }
  } else {
    const int idx = (bid-2)*256 + tid;     // 16384 halo elems
    const int b = idx>>11, t = idx&2047;
    const int r = t>>8, c = t&255;
    const int row = (r<4) ? r : (2052 + r - 4);
    seq1p[((size_t)b*2056 + row)*256 + c] = 0;
  }
}

// ------- GEMM: C = A·W^T + bias [+res]; optional padded residual indexing -------
template<bool OUT_F32, bool ADD_RES, bool RES_F32, bool RES_PAD>
__global__ __launch_bounds__(256)
void gemm_nt(const u16* __restrict__ A, const u16* __restrict__ W,
             const u16* __restrict__ bias, const void* __restrict__ res,
             void* __restrict__ out, int K)
{
  __shared__ __align__(16) u16 aL[2][4096];
  __shared__ __align__(16) u16 bL[2][4096];
  const int tid = threadIdx.x, lane = tid&63, w = tid>>6;
  const int wm = w>>1, wn = w&1, lr = lane&15, lg = lane>>4;
  int mi, ni; xcd_remap(mi, ni);
  const int m0 = mi*128, n0 = ni*128;
  const int nk = K>>5;

  f32x4 acc[4][4];
#pragma unroll
  for (int i=0;i<4;++i)
#pragma unroll
    for (int j=0;j<4;++j) acc[i][j] = f32x4{0.f,0.f,0.f,0.f};

  auto stage = [&](int buf, int kk){
#pragma unroll
    for (int i=0;i<2;++i){
      const int chunk = w*2+i;
      const int boff  = chunk*1024 + lane*16;
      const int r = boff>>6;
      const int cb = (boff&63) ^ (((r>>1)&3)<<4);
      const int c = cb>>1;
      gll16(&A[(size_t)(m0+r)*K + kk*32 + c], &aL[buf][chunk*512]);
      gll16(&W[(size_t)(n0+r)*K + kk*32 + c], &bL[buf][chunk*512]);
    }
  };

  stage(0,0);
  __syncthreads();
  for (int kk=0; kk<nk; ++kk){
    if (kk+1<nk) stage((kk+1)&1, kk+1);
    const u16* ab = aL[kk&1];
    const u16* bb = bL[kk&1];
    bf16x8 af[4], bv[4];
#pragma unroll
    for (int m=0;m<4;++m){
      const int ra = wm*64+m*16+lr;
      af[m] = ldsr8(&ab[(ra*64 + ((lg*16) ^ (((ra>>1)&3)<<4)))>>1]);
    }
#pragma unroll
    for (int n=0;n<4;++n){
      const int rb = wn*64+n*16+lr;
      bv[n] = ldsr8(&bb[(rb*64 + ((lg*16) ^ (((rb>>1)&3)<<4)))>>1]);
    }
#pragma unroll
    for (int m=0;m<4;++m)
#pragma unroll
      for (int n=0;n<4;++n)
        acc[m][n] = mfma16(af[m], bv[n], acc[m][n]);
    __syncthreads();
  }
#pragma unroll
  for (int m=0;m<4;++m)
#pragma unroll
    for (int n=0;n<4;++n)
#pragma unroll
      for (int r=0;r<4;++r){
        const int row = m0 + wm*64 + m*16 + lg*4 + r;
        const int col = n0 + wn*64 + n*16 + lr;
        float v = acc[m][n][r] + bf2f(bias[col]);
        if constexpr (ADD_RES){
          size_t ri = (size_t)row*256 + col;
          if constexpr (RES_PAD) ri = ((size_t)row + (row>>11)*8 + 4)*256 + col;
          if constexpr (RES_F32) v += ((const float*)res)[ri];
          else                   v += bf2f(((const u16*)res)[ri]);
        }
        if constexpr (OUT_F32) ((float*)out)[(size_t)row*256 + col] = v;
        else                   ((u16*)out)[(size_t)row*256 + col] = f2bf(v);
      }
}

// ------- fused QKV GEMM: W = [wq;wk;wv] (768 x 256); out array picked by col>>8 -------
__global__ __launch_bounds__(256)
void gemm_qkv(const u16* __restrict__ A, const u16* __restrict__ W,
              const u16* __restrict__ bias, u16* __restrict__ qbase)
{
  __shared__ __align__(16) u16 aL[2][4096];
  __shared__ __align__(16) u16 bL[2][4096];
  const int tid = threadIdx.x, lane = tid&63, w = tid>>6;
  const int wm = w>>1, wn = w&1, lr = lane&15, lg = lane>>4;
  int mi, ni; xcd_remap(mi, ni);
  const int m0 = mi*128, n0 = ni*128;

  f32x4 acc[4][4];
#pragma unroll
  for (int i=0;i<4;++i)
#pragma unroll
    for (int j=0;j<4;++j) acc[i][j] = f32x4{0.f,0.f,0.f,0.f};

  auto stage = [&](int buf, int kk){
#pragma unroll
    for (int i=0;i<2;++i){
      const int chunk = w*2+i;
      const int boff  = chunk*1024 + lane*16;
      const int r = boff>>6;
      const int cb = (boff&63) ^ (((r>>1)&3)<<4);
      const int c = cb>>1;
      gll16(&A[(size_t)(m0+r)*256 + kk*32 + c], &aL[buf][chunk*512]);
      gll16(&W[(size_t)(n0+r)*256 + kk*32 + c], &bL[buf][chunk*512]);
    }
  };

  stage(0,0);
  __syncthreads();
  for (int kk=0; kk<8; ++kk){
    if (kk+1<8) stage((kk+1)&1, kk+1);
    const u16* ab = aL[kk&1];
    const u16* bb = bL[kk&1];
    bf16x8 af[4], bv[4];
#pragma unroll
    for (int m=0;m<4;++m){
      const int ra = wm*64+m*16+lr;
      af[m] = ldsr8(&ab[(ra*64 + ((lg*16) ^ (((ra>>1)&3)<<4)))>>1]);
    }
#pragma unroll
    for (int n=0;n<4;++n){
      const int rb = wn*64+n*16+lr;
      bv[n] = ldsr8(&bb[(rb*64 + ((lg*16) ^ (((rb>>1)&3)<<4)))>>1]);
    }
#pragma unroll
    for (int m=0;m<4;++m)
#pragma unroll
      for (int n=0;n<4;++n)
        acc[m][n] = mfma16(af[m], bv[n], acc[m][n]);
    __syncthreads();
  }
#pragma unroll
  for (int m=0;m<4;++m)
#pragma unroll
    for (int n=0;n<4;++n)
#pragma unroll
      for (int r=0;r<4;++r){
        const int row = m0 + wm*64 + m*16 + lg*4 + r;
        const int col = n0 + wn*64 + n*16 + lr;
        const int which = col>>8, ch = col&255;
        float v = acc[m][n][r] + bf2f(bias[col]);
        qbase[(size_t)which*4194304 + (size_t)row*256 + ch] = f2bf(v);
      }
}

// ------- conv1 as m97-style GEMM over padded input: K = 2304 (tap-major) -------
__global__ __launch_bounds__(256)
void conv1_gemm(const u16* __restrict__ Ap,   // [8][2056][256] zero-haloed
                const u16* __restrict__ W1r,  // [1024][2304], k = tap*256+i
                const u16* __restrict__ b1, u16* __restrict__ Hout)
{
  __shared__ __align__(16) u16 aL[2][4096];
  __shared__ __align__(16) u16 bL[2][4096];
  const int tid = threadIdx.x, lane = tid&63, w = tid>>6;
  const int wm = w>>1, wn = w&1, lr = lane&15, lg = lane>>4;
  int mi, ni; xcd_remap(mi, ni);
  const int m0 = mi*128, n0 = ni*128;
  const int b = m0>>11, s0 = m0&2047;
  const size_t abase = ((size_t)b*2056 + s0)*256;

  f32x4 acc[4][4];
#pragma unroll
  for (int i=0;i<4;++i)
#pragma unroll
    for (int j=0;j<4;++j) acc[i][j] = f32x4{0.f,0.f,0.f,0.f};

  auto stage = [&](int buf, int kk){
    const int tap = kk>>3, ch0 = (kk&7)*32;
#pragma unroll
    for (int i=0;i<2;++i){
      const int chunk = w*2+i;
      const int boff  = chunk*1024 + lane*16;
      const int r = boff>>6;
      const int cb = (boff&63) ^ (((r>>1)&3)<<4);
      const int c = cb>>1;
      gll16(&Ap[abase + (size_t)(tap + r)*256 + ch0 + c], &aL[buf][chunk*512]);
      gll16(&W1r[(size_t)(n0+r)*2304 + kk*32 + c], &bL[buf][chunk*512]);
    }
  };

  stage(0,0);
  __syncthreads();
  for (int kk=0; kk<72; ++kk){
    if (kk+1<72) stage((kk+1)&1, kk+1);
    const u16* ab = aL[kk&1];
    const u16* bb = bL[kk&1];
    bf16x8 af[4], bv[4];
#pragma unroll
    for (int m=0;m<4;++m){
      const int ra = wm*64+m*16+lr;
      af[m] = ldsr8(&ab[(ra*64 + ((lg*16) ^ (((ra>>1)&3)<<4)))>>1]);
    }
#pragma unroll
    for (int n=0;n<4;++n){
      const int rb = wn*64+n*16+lr;
      bv[n] = ldsr8(&bb[(rb*64 + ((lg*16) ^ (((rb>>1)&3)<<4)))>>1]);
    }
#pragma unroll
    for (int m=0;m<4;++m)
#pragma unroll
      for (int n=0;n<4;++n)
        acc[m][n] = mfma16(af[m], bv[n], acc[m][n]);
    __syncthreads();
  }
#pragma unroll
  for (int m=0;m<4;++m)
#pragma unroll
    for (int n=0;n<4;++n)
#pragma unroll
      for (int r=0;r<4;++r){
        const int row = m0 + wm*64 + m*16 + lg*4 + r;
        const int col = n0 + wn*64 + n*16 + lr;
        float v = acc[m][n][r] + bf2f(b1[col]);
        v = v>0.f ? v : 0.f;
        Hout[(size_t)row*1024 + col] = f2bf(v);
      }
}

// ------- V [16384][256] -> VT [b][h][128][2048] -------
__global__ __launch_bounds__(256)
void vtrans(const u16* __restrict__ V, u16* __restrict__ VT)
{
  __shared__ u16 t[64][72];
  const int tid = threadIdx.x;
  const int s0 = blockIdx.x*64;
  const int d0 = blockIdx.y*64;
#pragma unroll
  for (int i=0;i<2;++i){
    const int chunk = tid + i*256;
    const int sr = chunk>>3, c8 = (chunk&7)*8;
    u32x4 raw = *(const u32x4*)&V[(size_t)(s0+sr)*256 + d0 + c8];
#pragma unroll
    for (int j=0;j<4;++j){
      t[sr][c8+2*j]   = (u16)(raw[j]&0xffffu);
      t[sr][c8+2*j+1] = (u16)(raw[j]>>16);
    }
  }
  __syncthreads();
  const int b = s0>>11;
#pragma unroll
  for (int i=0;i<2;++i){
    const int chunk = tid + i*256;
    const int dr = chunk>>3, s8 = (chunk&7)*8;
    const int dg = d0 + dr;
    const int hh = dg>>7, dh = dg&127;
    u32x4 o;
#pragma unroll
    for (int j=0;j<4;++j)
      o[j] = (u32)t[s8+2*j][dr] | ((u32)t[s8+2*j+1][dr]<<16);
    *(u32x4*)&VT[((size_t)((b*2+hh)*128 + dh))*2048 + (s0&2047) + s8] = o;
  }
}

// ------- flash attention: barrier-free, K/V read direct from L2, 64-row q-tiles -------
// grid (32, 8, 2); wave w owns q rows q0+w*16..+15; P in per-wave LDS only.
__global__ __launch_bounds__(256)
void attn_fwd(const u16* __restrict__ Q, const u16* __restrict__ Kb,
              const u16* __restrict__ VT, const u16* __restrict__ cmask,
              u16* __restrict__ ctx)
{
  __shared__ __align__(16) u16 pls[4][16*128];
  const int tid = threadIdx.x, lane = tid&63, w = tid>>6;
  const int qt = blockIdx.x, b = blockIdx.y, hh = blockIdx.z;
  const int q0 = qt*64;
  const int lr = lane&15, lg = lane>>4;
  u16* pw = pls[w];

  bf16x8 qf[4];
#pragma unroll
  for (int d=0;d<4;++d)
    qf[d] = *(const bf16x8*)&Q[((size_t)(b*2048+q0+w*16+lr))*256 + hh*128 + d*32 + lg*8];

  f32x4 oacc[8];
  float mrun[4], lrun[4];
#pragma unroll
  for (int n=0;n<8;++n) oacc[n] = f32x4{0.f,0.f,0.f,0.f};
#pragma unroll
  for (int r=0;r<4;++r){ mrun[r] = -1e30f; lrun[r] = 0.f; }

  const size_t kbase = (size_t)(b*2048)*256 + hh*128;
  const size_t vbase = (size_t)((b*2+hh)*128)*2048;

  for (int kt=0; kt<16; ++kt){
    const int kv0 = kt*128;
    if (cmask[b*2048 + kv0] != 0) break;
    // ---- QK^T (K direct from global/L2) ----
    f32x4 sacc[8];
#pragma unroll
    for (int n=0;n<8;++n) sacc[n] = f32x4{0.f,0.f,0.f,0.f};
#pragma unroll
    for (int dk=0;dk<4;++dk){
      bf16x8 bk[8];
#pragma unroll
      for (int n=0;n<8;++n)
        bk[n] = *(const bf16x8*)&Kb[kbase + (size_t)(kv0+n*16+lr)*256 + dk*32 + lg*8];
#pragma unroll
      for (int n=0;n<8;++n)
        sacc[n] = mfma16(qf[dk], bk[n], sacc[n]);
    }
    // ---- scale + key mask ----
    float madd[8];
#pragma unroll
    for (int n=0;n<8;++n)
      madd[n] = cmask[b*2048 + kv0 + n*16 + lr] ? -1e30f : 0.f;
#pragma unroll
    for (int n=0;n<8;++n)
#pragma unroll
      for (int r=0;r<4;++r)
        sacc[n][r] = sacc[n][r]*0.0625f + madd[n];
    // ---- online softmax (row on 16 lanes of lg group) ----
#pragma unroll
    for (int r=0;r<4;++r){
      float rm = sacc[0][r];
#pragma unroll
      for (int n=1;n<8;++n) rm = fmaxf(rm, sacc[n][r]);
#pragma unroll
      for (int x=1;x<16;x<<=1) rm = fmaxf(rm, __shfl_xor(rm, x));
      const float mnew = fmaxf(mrun[r], rm);
      const float alpha = __expf(mrun[r] - mnew);
      float rsum = 0.f;
#pragma unroll
      for (int n=0;n<8;++n){
        float p = __expf(sacc[n][r] - mnew);
        sacc[n][r] = p;
        rsum += p;
      }
#pragma unroll
      for (int x=1;x<16;x<<=1) rsum += __shfl_xor(rsum, x);
      lrun[r] = alpha*lrun[r] + rsum;
      mrun[r] = mnew;
#pragma unroll
      for (int n=0;n<8;++n) oacc[n][r] *= alpha;
    }
    // ---- P -> per-wave LDS (swizzled rows, same-wave only, no barrier) ----
#pragma unroll
    for (int n=0;n<8;++n)
#pragma unroll
      for (int r=0;r<4;++r){
        const int row = lg*4 + r;
        pw[(row*256 + (((n*16+lr)*2) ^ ((row&7)<<4)))>>1] = f2bf(sacc[n][r]);
      }
    // ---- PV (V^T direct from global/L2) ----
#pragma unroll
    for (int ks=0;ks<4;++ks){
      bf16x8 pa = ldsr8(&pw[(lr*256 + ((ks*64 + lg*16) ^ ((lr&7)<<4)))>>1]);
#pragma unroll
      for (int n=0;n<8;++n){
        bf16x8 bvv = *(const bf16x8*)&VT[vbase + (size_t)(n*16+lr)*2048 + kv0 + ks*32 + lg*8];
        oacc[n] = mfma16(pa, bvv, oacc[n]);
      }
    }
  }
#pragma unroll
  for (int r=0;r<4;++r){
    const float inv = lrun[r] > 0.f ? 1.f/lrun[r] : 0.f;
    const int row = q0 + w*16 + lg*4 + r;
#pragma unroll
    for (int n=0;n<8;++n){
      const int col = hh*128 + n*16 + lr;
      ctx[((size_t)(b*2048+row))*256 + col] = f2bf(oacc[n][r]*inv);
    }
  }
}

// ------- LayerNorm + mask-zero (bf16 in -> padded bf16 out) -------
__global__ __launch_bounds__(256)
void ln_mask_b(const u16* __restrict__ X, const u16* __restrict__ g,
               const u16* __restrict__ bta, const u16* __restrict__ cmask,
               u16* __restrict__ outp)
{
  const int w = threadIdx.x>>6, lane = threadIdx.x&63;
  const int row = blockIdx.x*4 + w;
  const u16* xr = X + (size_t)row*256;
  u32x2 rawv = *(const u32x2*)&xr[lane*4];
  float xv[4];
  xv[0]=bf2f((u16)(rawv[0]&0xffffu)); xv[1]=bf2f((u16)(rawv[0]>>16));
  xv[2]=bf2f((u16)(rawv[1]&0xffffu)); xv[3]=bf2f((u16)(rawv[1]>>16));
  float s = xv[0]+xv[1]+xv[2]+xv[3];
#pragma unroll
  for (int x=1;x<64;x<<=1) s += __shfl_xor(s, x);
  const float mu = s * (1.f/256.f);
  float d[4];
#pragma unroll
  for (int j=0;j<4;++j) d[j]=xv[j]-mu;
  float sq = d[0]*d[0]+d[1]*d[1]+d[2]*d[2]+d[3]*d[3];
#pragma unroll
  for (int x=1;x<64;x<<=1) sq += __shfl_xor(sq, x);
  const float rs = rsqrtf(sq*(1.f/256.f) + 1e-5f);
  const int msk = cmask[row];
  u16 o4[4];
#pragma unroll
  for (int j=0;j<4;++j){
    const int c = lane*4 + j;
    float y = d[j]*rs*bf2f(g[c]) + bf2f(bta[c]);
    o4[j] = msk ? (u16)0 : f2bf(y);
  }
  u32x2 ov;
  ov[0] = (u32)o4[0] | ((u32)o4[1]<<16);
  ov[1] = (u32)o4[2] | ((u32)o4[3]<<16);
  const size_t prow = (size_t)row + (row>>11)*8 + 4;
  *(u32x2*)&outp[prow*256 + lane*4] = ov;
}

// ------- final LayerNorm + mask-zero (bf16 in -> f32 out) -------
__global__ __launch_bounds__(256)
void ln_out(const u16* __restrict__ X, const u16* __restrict__ g,
            const u16* __restrict__ bta, const u16* __restrict__ cmask,
            float* __restrict__ out)
{
  const int w = threadIdx.x>>6, lane = threadIdx.x&63;
  const int row = blockIdx.x*4 + w;
  const u16* xr = X + (size_t)row*256;
  u32x2 rawv = *(const u32x2*)&xr[lane*4];
  float xv[4];
  xv[0]=bf2f((u16)(rawv[0]&0xffffu)); xv[1]=bf2f((u16)(rawv[0]>>16));
  xv[2]=bf2f((u16)(rawv[1]&0xffffu)); xv[3]=bf2f((u16)(rawv[1]>>16));
  float s = xv[0]+xv[1]+xv[2]+xv[3];
#pragma unroll
  for (int x=1;x<64;x<<=1) s += __shfl_xor(s, x);
  const float mu = s * (1.f/256.f);
  float d[4];
#pragma unroll
  for (int j=0;j<4;++j) d[j]=xv[j]-mu;
  float sq = d[0]*d[0]+d[1]*d[1]+d[2]*d[2]+d[3]*d[3];
#pragma unroll
  for (int x=1;x<64;x<<=1) sq += __shfl_xor(sq, x);
  const float rs = rsqrtf(sq*(1.f/256.f) + 1e-5f);
  const int msk = cmask[row];
  f32x4 ov;
#pragma unroll
  for (int j=0;j<4;++j){
    const int c = lane*4 + j;
    float y = d[j]*rs*bf2f(g[c]) + bf2f(bta[c]);
    ov[j] = msk ? 0.f : y;
  }
  *(f32x4*)&out[(size_t)row*256 + lane*4] = ov;
}

extern "C" void kernel_launch(void* const* d_in, const int* in_sizes, int n_in,
                              void* d_out, int out_size, void* d_ws, size_t ws_size,
                              hipStream_t stream)
{
  (void)in_sizes; (void)n_in; (void)out_size; (void)ws_size;
  const float* batch=(const float*)d_in[0];  const void* mraw = d_in[1];
  const float* wq=(const float*)d_in[2];  const float* bq=(const float*)d_in[3];
  const float* wk=(const float*)d_in[4];  const float* bk=(const float*)d_in[5];
  const float* wv=(const float*)d_in[6];  const float* bvv=(const float*)d_in[7];
  const float* wo=(const float*)d_in[8];  const float* bo=(const float*)d_in[9];
  const float* g1=(const float*)d_in[10]; const float* be1=(const float*)d_in[11];
  const float* w1=(const float*)d_in[12]; const float* b1=(const float*)d_in[13];
  const float* w2=(const float*)d_in[14]; const float* b2=(const float*)d_in[15];
  const float* g2=(const float*)d_in[16]; const float* be2=(const float*)d_in[17];

  char* ws = (char*)d_ws;
  const size_t M = 1024u*1024u;
  u16*   batchc = (u16*)(ws);          // 0..8M   (dead after QKV gemm)
  u16*   VT     = (u16*)(ws);          // 0..8M   (over batchc; live vtrans..attn)
  u16*   q      = (u16*)(ws + 8*M);    // 8..16M  (dead after attn)
  u16*   tmpb   = (u16*)(ws + 8*M);    // 8..16M  (over q; outproj out, live ..ln_mask_b)
  u16*   kbuf   = (u16*)(ws + 16*M);   // 16..24M (dead after attn)
  u16*   v      = (u16*)(ws + 24*M);   // 24..32M (dead after vtrans)
  u16*   ctx    = (u16*)(ws + 32*M);   // 32..40M (dead after outproj)
  u16*   h      = (u16*)(ws);          // 0..32M  (over VT,tmpb,kbuf,v; live conv1..conv2)
  u16*   x2     = (u16*)(ws + 32*M);   // 32..40M (over ctx; conv2 out, live ..ln_out)
  u16*   seq1p  = (u16*)(ws + 40*M);   // 40..48.1M padded [8][2056][256]
  u16*   wqc    = (u16*)(ws + 49*M);   // wq|wk|wv (768x256), then wo, then w2
  u16*   woc    = wqc + 196608;
  u16*   w2c    = wqc + 262144;
  u16*   w1r    = (u16*)(ws + 50*M);   // 2359296 u16 (4.5 MB)
  u16*   params = w1r + 2359296;
  u16*   cmask  = params + 4096;

  dim3 blk(256,1,1);

  prep_big<<<dim3(13824,1,1), blk, 0, stream>>>(batch, wq, wk, wv, wo, w2, w1,
                                                batchc, wqc, w1r);
  prep_small<<<dim3(66,1,1), blk, 0, stream>>>(bq,bk,bvv,bo,g1,be1,g2,be2,b1,b2,
                                               params, mraw, cmask, seq1p);

  gemm_qkv<<<dim3(128,6,1), blk, 0, stream>>>(batchc, wqc, params, q);

  vtrans<<<dim3(256,4,1), blk, 0, stream>>>(v, VT);

  attn_fwd<<<dim3(32,8,2), blk, 0, stream>>>(q, kbuf, VT, cmask, ctx);

  gemm_nt<false,true,true,false><<<dim3(128,2,1), blk, 0, stream>>>(ctx, woc, params+768, (const void*)batch, (void*)tmpb, 256);
  ln_mask_b<<<dim3(4096,1,1), blk, 0, stream>>>(tmpb, params+1024, params+1280, cmask, seq1p);

  conv1_gemm<<<dim3(128,8,1), blk, 0, stream>>>(seq1p, w1r, params+2048, h);

  gemm_nt<false,true,false,true><<<dim3(128,2,1), blk, 0, stream>>>(h, w2c, params+3072, (const void*)seq1p, (void*)x2, 1024);
  ln_out<<<dim3(4096,1,1), blk, 0, stream>>>(x2, params+1536, params+1792, cmask, (float*)d_out);
}

// Round 12
// 341.343 us; speedup vs baseline: 1.3963x; 1.3963x over previous
//
#include <hip/hip_runtime.h>

typedef unsigned char  u8;
typedef unsigned short u16;
typedef unsigned int   u32;
typedef __attribute__((ext_vector_type(4))) float f32x4;
typedef __attribute__((ext_vector_type(8))) __bf16 bf16x8;
typedef __attribute__((ext_vector_type(4))) u32  u32x4;
typedef __attribute__((ext_vector_type(2))) u32  u32x2;

__device__ __forceinline__ float bf2f(u16 h){ u32 u = ((u32)h)<<16; return __builtin_bit_cast(float, u); }
__device__ __forceinline__ u16  f2bf(float f){
  u32 u = __builtin_bit_cast(u32, f);
  u32 r = u + 0x7FFFu + ((u>>16)&1u);
  return (u16)(r>>16);
}

typedef const __attribute__((address_space(1))) u32 gas_u32;
typedef __attribute__((address_space(3))) u32 las_u32;
__device__ __forceinline__ void gll16(const void* g, void* l){
  __builtin_amdgcn_global_load_lds((gas_u32*)g, (las_u32*)l, 16, 0, 0);
}

__device__ __forceinline__ f32x4 mfma16(bf16x8 a, bf16x8 b, f32x4 c){
  return __builtin_amdgcn_mfma_f32_16x16x32_bf16(a, b, c, 0, 0, 0);
}

__device__ __forceinline__ bf16x8 ldsr8(const u16* p){
  u32x4 v = *(const u32x4*)p;
  return __builtin_bit_cast(bf16x8, v);
}

// XCD co-locate remap: blocks sharing an A-panel (same m-tile) land on one XCD.
__device__ __forceinline__ void xcd_remap(int &m_idx, int &n_idx){
  const int Mt = gridDim.x;
  const int fid = blockIdx.x + Mt*blockIdx.y;
  const int xcd = fid & 7, k = fid >> 3;
  const int mpx = Mt >> 3;
  m_idx = xcd*mpx + (k % mpx);
  n_idx = k / mpx;
}

// ------- prologue A: batch cvt + weight cvt + conv1 weight repack -------
__global__ __launch_bounds__(256)
void prep_big(const float* __restrict__ batch,
              const float* __restrict__ wq, const float* __restrict__ wk,
              const float* __restrict__ wv, const float* __restrict__ wo,
              const float* __restrict__ w2, const float* __restrict__ w1,
              u16* __restrict__ batchc, u16* __restrict__ wqc, u16* __restrict__ w1r)
{
  const int bid = blockIdx.x, tid = threadIdx.x;
  if (bid < 4096){
    const int i = bid*1024 + tid*4;
    f32x4 v = *(const f32x4*)&batch[i];
    u32x2 o;
    o[0] = (u32)f2bf(v[0]) | ((u32)f2bf(v[1])<<16);
    o[1] = (u32)f2bf(v[2]) | ((u32)f2bf(v[3])<<16);
    *(u32x2*)&batchc[i] = o;
  } else if (bid < 4608){
    const int i = (bid-4096)*1024 + tid*4;
    const float* s; int off;
    if      (i < 65536)  { s = wq; off = i; }
    else if (i < 131072) { s = wk; off = i - 65536; }
    else if (i < 196608) { s = wv; off = i - 131072; }
    else if (i < 262144) { s = wo; off = i - 196608; }
    else                 { s = w2; off = i - 262144; }
    f32x4 v = *(const f32x4*)&s[off];
    u32x2 o;
    o[0] = (u32)f2bf(v[0]) | ((u32)f2bf(v[1])<<16);
    o[1] = (u32)f2bf(v[2]) | ((u32)f2bf(v[3])<<16);
    *(u32x2*)&wqc[i] = o;
  } else {
    const int idx = (bid-4608)*256 + tid;
    const int c = idx / 2304;
    const int t = idx - c*2304;
    const int i = t / 9;
    const int kk = t - i*9;
    w1r[c*2304 + kk*256 + i] = f2bf(w1[idx]);
  }
}

// ------- prologue B: params + mask canon + seq1p halo zero -------
__global__ __launch_bounds__(256)
void prep_small(const float* p0,const float* p1,const float* p2,const float* p3,
                const float* p4,const float* p5,const float* p6,const float* p7,
                const float* p8,const float* p9,
                u16* __restrict__ params, const void* __restrict__ mraw,
                u16* __restrict__ cmask, u16* __restrict__ seq1p)
{
  const int bid = blockIdx.x, tid = threadIdx.x;
  if (bid == 0){
    const float* ps[10] = {p0,p1,p2,p3,p4,p5,p6,p7,p8,p9};
    const int  off[10] = {0,256,512,768,1024,1280,1536,1792,2048,3072};
    const int  len[10] = {256,256,256,256,256,256,256,256,1024,256};
    for (int a=0;a<10;++a)
      for (int i=tid;i<len[a];i+=256)
        params[off[a]+i] = f2bf(ps[a][i]);
  } else if (bid == 1){
    const u8*  pb8  = (const u8*)mraw;
    const u16* pb16 = (const u16*)mraw;
    const u32* pb32 = (const u32*)mraw;
    __shared__ int bad8, bad16, nz8, nz16;
    if (tid==0){ bad8=0; bad16=0; nz8=0; nz16=0; }
    __syncthreads();
    for (int i=tid;i<16384;i+=256){
      u8 v = pb8[i]; int row = i & 2047;
      if (v>1) atomicOr(&bad8,1);
      if (v){ atomicOr(&nz8,1); if (row<1024) atomicOr(&bad8,1); }
      if (row>0 && pb8[i-1]==1 && v==0) atomicOr(&bad8,1);
    }
    for (int i=tid;i<8192;i+=256){
      u16 v = pb16[i]; int row = i & 2047;
      if (!(v==0 || v==0x3F80)) atomicOr(&bad16,1);
      if (v){ atomicOr(&nz16,1); if (row<1024) atomicOr(&bad16,1); }
      if (row>0 && pb16[i-1]==0x3F80 && v==0) atomicOr(&bad16,1);
    }
    __syncthreads();
    const int mode = (!bad8 && nz8) ? 1 : ((!bad16 && nz16) ? 2 : 0);
    for (int i=tid;i<16384;i+=256){
      u16 m;
      if (mode==1)      m = pb8[i]  ? 1 : 0;
      else if (mode==2) m = pb16[i] ? 1 : 0;
      else              m = pb32[i] ? 1 : 0;
      cmask[i] = m;
    }
  } else {
    const int idx = (bid-2)*256 + tid;     // 16384 halo elems
    const int b = idx>>11, t = idx&2047;
    const int r = t>>8, c = t&255;
    const int row = (r<4) ? r : (2052 + r - 4);
    seq1p[((size_t)b*2056 + row)*256 + c] = 0;
  }
}

// ------- GEMM: C = A·W^T + bias [+res]; optional padded residual indexing -------
template<bool OUT_F32, bool ADD_RES, bool RES_F32, bool RES_PAD>
__global__ __launch_bounds__(256)
void gemm_nt(const u16* __restrict__ A, const u16* __restrict__ W,
             const u16* __restrict__ bias, const void* __restrict__ res,
             void* __restrict__ out, int K)
{
  __shared__ __align__(16) u16 aL[2][4096];
  __shared__ __align__(16) u16 bL[2][4096];
  const int tid = threadIdx.x, lane = tid&63, w = tid>>6;
  const int wm = w>>1, wn = w&1, lr = lane&15, lg = lane>>4;
  int mi, ni; xcd_remap(mi, ni);
  const int m0 = mi*128, n0 = ni*128;
  const int nk = K>>5;

  f32x4 acc[4][4];
#pragma unroll
  for (int i=0;i<4;++i)
#pragma unroll
    for (int j=0;j<4;++j) acc[i][j] = f32x4{0.f,0.f,0.f,0.f};

  auto stage = [&](int buf, int kk){
#pragma unroll
    for (int i=0;i<2;++i){
      const int chunk = w*2+i;
      const int boff  = chunk*1024 + lane*16;
      const int r = boff>>6;
      const int cb = (boff&63) ^ (((r>>1)&3)<<4);
      const int c = cb>>1;
      gll16(&A[(size_t)(m0+r)*K + kk*32 + c], &aL[buf][chunk*512]);
      gll16(&W[(size_t)(n0+r)*K + kk*32 + c], &bL[buf][chunk*512]);
    }
  };

  stage(0,0);
  __syncthreads();
  for (int kk=0; kk<nk; ++kk){
    if (kk+1<nk) stage((kk+1)&1, kk+1);
    const u16* ab = aL[kk&1];
    const u16* bb = bL[kk&1];
    bf16x8 af[4], bv[4];
#pragma unroll
    for (int m=0;m<4;++m){
      const int ra = wm*64+m*16+lr;
      af[m] = ldsr8(&ab[(ra*64 + ((lg*16) ^ (((ra>>1)&3)<<4)))>>1]);
    }
#pragma unroll
    for (int n=0;n<4;++n){
      const int rb = wn*64+n*16+lr;
      bv[n] = ldsr8(&bb[(rb*64 + ((lg*16) ^ (((rb>>1)&3)<<4)))>>1]);
    }
#pragma unroll
    for (int m=0;m<4;++m)
#pragma unroll
      for (int n=0;n<4;++n)
        acc[m][n] = mfma16(af[m], bv[n], acc[m][n]);
    __syncthreads();
  }
#pragma unroll
  for (int m=0;m<4;++m)
#pragma unroll
    for (int n=0;n<4;++n)
#pragma unroll
      for (int r=0;r<4;++r){
        const int row = m0 + wm*64 + m*16 + lg*4 + r;
        const int col = n0 + wn*64 + n*16 + lr;
        float v = acc[m][n][r] + bf2f(bias[col]);
        if constexpr (ADD_RES){
          size_t ri = (size_t)row*256 + col;
          if constexpr (RES_PAD) ri = ((size_t)row + (row>>11)*8 + 4)*256 + col;
          if constexpr (RES_F32) v += ((const float*)res)[ri];
          else                   v += bf2f(((const u16*)res)[ri]);
        }
        if constexpr (OUT_F32) ((float*)out)[(size_t)row*256 + col] = v;
        else                   ((u16*)out)[(size_t)row*256 + col] = f2bf(v);
      }
}

// ------- fused QKV GEMM: W = [wq;wk;wv] (768 x 256); out array picked by col>>8 -------
__global__ __launch_bounds__(256)
void gemm_qkv(const u16* __restrict__ A, const u16* __restrict__ W,
              const u16* __restrict__ bias, u16* __restrict__ qbase)
{
  __shared__ __align__(16) u16 aL[2][4096];
  __shared__ __align__(16) u16 bL[2][4096];
  const int tid = threadIdx.x, lane = tid&63, w = tid>>6;
  const int wm = w>>1, wn = w&1, lr = lane&15, lg = lane>>4;
  int mi, ni; xcd_remap(mi, ni);
  const int m0 = mi*128, n0 = ni*128;

  f32x4 acc[4][4];
#pragma unroll
  for (int i=0;i<4;++i)
#pragma unroll
    for (int j=0;j<4;++j) acc[i][j] = f32x4{0.f,0.f,0.f,0.f};

  auto stage = [&](int buf, int kk){
#pragma unroll
    for (int i=0;i<2;++i){
      const int chunk = w*2+i;
      const int boff  = chunk*1024 + lane*16;
      const int r = boff>>6;
      const int cb = (boff&63) ^ (((r>>1)&3)<<4);
      const int c = cb>>1;
      gll16(&A[(size_t)(m0+r)*256 + kk*32 + c], &aL[buf][chunk*512]);
      gll16(&W[(size_t)(n0+r)*256 + kk*32 + c], &bL[buf][chunk*512]);
    }
  };

  stage(0,0);
  __syncthreads();
  for (int kk=0; kk<8; ++kk){
    if (kk+1<8) stage((kk+1)&1, kk+1);
    const u16* ab = aL[kk&1];
    const u16* bb = bL[kk&1];
    bf16x8 af[4], bv[4];
#pragma unroll
    for (int m=0;m<4;++m){
      const int ra = wm*64+m*16+lr;
      af[m] = ldsr8(&ab[(ra*64 + ((lg*16) ^ (((ra>>1)&3)<<4)))>>1]);
    }
#pragma unroll
    for (int n=0;n<4;++n){
      const int rb = wn*64+n*16+lr;
      bv[n] = ldsr8(&bb[(rb*64 + ((lg*16) ^ (((rb>>1)&3)<<4)))>>1]);
    }
#pragma unroll
    for (int m=0;m<4;++m)
#pragma unroll
      for (int n=0;n<4;++n)
        acc[m][n] = mfma16(af[m], bv[n], acc[m][n]);
    __syncthreads();
  }
#pragma unroll
  for (int m=0;m<4;++m)
#pragma unroll
    for (int n=0;n<4;++n)
#pragma unroll
      for (int r=0;r<4;++r){
        const int row = m0 + wm*64 + m*16 + lg*4 + r;
        const int col = n0 + wn*64 + n*16 + lr;
        const int which = col>>8, ch = col&255;
        float v = acc[m][n][r] + bf2f(bias[col]);
        qbase[(size_t)which*4194304 + (size_t)row*256 + ch] = f2bf(v);
      }
}

// ------- conv1 as m97-style GEMM over padded input: K = 2304 (tap-major) -------
__global__ __launch_bounds__(256)
void conv1_gemm(const u16* __restrict__ Ap,   // [8][2056][256] zero-haloed
                const u16* __restrict__ W1r,  // [1024][2304], k = tap*256+i
                const u16* __restrict__ b1, u16* __restrict__ Hout)
{
  __shared__ __align__(16) u16 aL[2][4096];
  __shared__ __align__(16) u16 bL[2][4096];
  const int tid = threadIdx.x, lane = tid&63, w = tid>>6;
  const int wm = w>>1, wn = w&1, lr = lane&15, lg = lane>>4;
  int mi, ni; xcd_remap(mi, ni);
  const int m0 = mi*128, n0 = ni*128;
  const int b = m0>>11, s0 = m0&2047;
  const size_t abase = ((size_t)b*2056 + s0)*256;

  f32x4 acc[4][4];
#pragma unroll
  for (int i=0;i<4;++i)
#pragma unroll
    for (int j=0;j<4;++j) acc[i][j] = f32x4{0.f,0.f,0.f,0.f};

  auto stage = [&](int buf, int kk){
    const int tap = kk>>3, ch0 = (kk&7)*32;
#pragma unroll
    for (int i=0;i<2;++i){
      const int chunk = w*2+i;
      const int boff  = chunk*1024 + lane*16;
      const int r = boff>>6;
      const int cb = (boff&63) ^ (((r>>1)&3)<<4);
      const int c = cb>>1;
      gll16(&Ap[abase + (size_t)(tap + r)*256 + ch0 + c], &aL[buf][chunk*512]);
      gll16(&W1r[(size_t)(n0+r)*2304 + kk*32 + c], &bL[buf][chunk*512]);
    }
  };

  stage(0,0);
  __syncthreads();
  for (int kk=0; kk<72; ++kk){
    if (kk+1<72) stage((kk+1)&1, kk+1);
    const u16* ab = aL[kk&1];
    const u16* bb = bL[kk&1];
    bf16x8 af[4], bv[4];
#pragma unroll
    for (int m=0;m<4;++m){
      const int ra = wm*64+m*16+lr;
      af[m] = ldsr8(&ab[(ra*64 + ((lg*16) ^ (((ra>>1)&3)<<4)))>>1]);
    }
#pragma unroll
    for (int n=0;n<4;++n){
      const int rb = wn*64+n*16+lr;
      bv[n] = ldsr8(&bb[(rb*64 + ((lg*16) ^ (((rb>>1)&3)<<4)))>>1]);
    }
#pragma unroll
    for (int m=0;m<4;++m)
#pragma unroll
      for (int n=0;n<4;++n)
        acc[m][n] = mfma16(af[m], bv[n], acc[m][n]);
    __syncthreads();
  }
#pragma unroll
  for (int m=0;m<4;++m)
#pragma unroll
    for (int n=0;n<4;++n)
#pragma unroll
      for (int r=0;r<4;++r){
        const int row = m0 + wm*64 + m*16 + lg*4 + r;
        const int col = n0 + wn*64 + n*16 + lr;
        float v = acc[m][n][r] + bf2f(b1[col]);
        v = v>0.f ? v : 0.f;
        Hout[(size_t)row*1024 + col] = f2bf(v);
      }
}

// ------- V [16384][256] -> VT [b][h][128][2048] -------
__global__ __launch_bounds__(256)
void vtrans(const u16* __restrict__ V, u16* __restrict__ VT)
{
  __shared__ u16 t[64][72];
  const int tid = threadIdx.x;
  const int s0 = blockIdx.x*64;
  const int d0 = blockIdx.y*64;
#pragma unroll
  for (int i=0;i<2;++i){
    const int chunk = tid + i*256;
    const int sr = chunk>>3, c8 = (chunk&7)*8;
    u32x4 raw = *(const u32x4*)&V[(size_t)(s0+sr)*256 + d0 + c8];
#pragma unroll
    for (int j=0;j<4;++j){
      t[sr][c8+2*j]   = (u16)(raw[j]&0xffffu);
      t[sr][c8+2*j+1] = (u16)(raw[j]>>16);
    }
  }
  __syncthreads();
  const int b = s0>>11;
#pragma unroll
  for (int i=0;i<2;++i){
    const int chunk = tid + i*256;
    const int dr = chunk>>3, s8 = (chunk&7)*8;
    const int dg = d0 + dr;
    const int hh = dg>>7, dh = dg&127;
    u32x4 o;
#pragma unroll
    for (int j=0;j<4;++j)
      o[j] = (u32)t[s8+2*j][dr] | ((u32)t[s8+2*j+1][dr]<<16);
    *(u32x4*)&VT[((size_t)((b*2+hh)*128 + dh))*2048 + (s0&2047) + s8] = o;
  }
}

// ------- flash attention: KVBLK=64, double-buffered gll16 staging, 1 barrier/tile -------
// grid (32, 8, 2); 64 q-rows/block; wave w owns rows q0+w*16..+15; P per-wave LDS.
__global__ __launch_bounds__(256)
void attn_fwd(const u16* __restrict__ Q, const u16* __restrict__ Kb,
              const u16* __restrict__ VT, const u16* __restrict__ cmask,
              u16* __restrict__ ctx)
{
  __shared__ __align__(16) u16 kls[2][64*128];   // [kv][d] 256B rows, sw (r&7)<<4
  __shared__ __align__(16) u16 vtls[2][128*64];  // [d][kv] 128B rows, sw (r&7)<<4
  __shared__ __align__(16) u16 pls[4][16*64];    // per-wave P, 128B rows
  const int tid = threadIdx.x, lane = tid&63, w = tid>>6;
  const int qt = blockIdx.x, b = blockIdx.y, hh = blockIdx.z;
  const int q0 = qt*64;
  const int lr = lane&15, lg = lane>>4;
  u16* pw = pls[w];

  bf16x8 qf[4];
#pragma unroll
  for (int d=0;d<4;++d)
    qf[d] = *(const bf16x8*)&Q[((size_t)(b*2048+q0+w*16+lr))*256 + hh*128 + d*32 + lg*8];

  f32x4 oacc[8];
  float mrun[4], lrun[4];
#pragma unroll
  for (int n=0;n<8;++n) oacc[n] = f32x4{0.f,0.f,0.f,0.f};
#pragma unroll
  for (int r=0;r<4;++r){ mrun[r] = -1e30f; lrun[r] = 0.f; }

  const size_t kbase = (size_t)(b*2048)*256 + hh*128;
  const size_t vbase = (size_t)((b*2+hh)*128)*2048;

  auto stage = [&](int buf, int kt){
    const int kv0 = kt*64;
#pragma unroll
    for (int i=0;i<4;++i){                       // K tile: 16 KB, 64 rows x 256B
      const int chunk = w*4+i;
      const int boff = chunk*1024 + lane*16;
      const int r = boff>>8;
      const int cb = (boff&255) ^ ((r&7)<<4);
      gll16(&Kb[kbase + (size_t)(kv0+r)*256 + (cb>>1)], &kls[buf][chunk*512]);
    }
#pragma unroll
    for (int i=0;i<4;++i){                       // VT tile: 16 KB, 128 rows x 128B
      const int chunk = w*4+i;
      const int boff = chunk*1024 + lane*16;
      const int r = boff>>7;
      const int cb = (boff&127) ^ ((r&7)<<4);
      gll16(&VT[vbase + (size_t)r*2048 + kv0 + (cb>>1)], &vtls[buf][chunk*512]);
    }
  };

  stage(0, 0);
  __syncthreads();

  for (int kt=0; kt<32; ++kt){
    const int kv0 = kt*64;
    if (cmask[b*2048 + kv0] != 0) break;
    const int buf = kt&1;
    if (kt+1 < 32) stage(buf^1, kt+1);           // prefetch overlaps this tile's compute
    // ---- QK^T ----
    f32x4 sacc[4];
#pragma unroll
    for (int n=0;n<4;++n) sacc[n] = f32x4{0.f,0.f,0.f,0.f};
#pragma unroll
    for (int dk=0;dk<4;++dk){
      bf16x8 bk[4];
#pragma unroll
      for (int n=0;n<4;++n){
        const int rb = n*16+lr;
        bk[n] = ldsr8(&kls[buf][(rb*256 + ((dk*64+lg*16) ^ ((rb&7)<<4)))>>1]);
      }
#pragma unroll
      for (int n=0;n<4;++n)
        sacc[n] = mfma16(qf[dk], bk[n], sacc[n]);
    }
    // ---- scale + key mask ----
    float madd[4];
#pragma unroll
    for (int n=0;n<4;++n)
      madd[n] = cmask[b*2048 + kv0 + n*16 + lr] ? -1e30f : 0.f;
#pragma unroll
    for (int n=0;n<4;++n)
#pragma unroll
      for (int r=0;r<4;++r)
        sacc[n][r] = sacc[n][r]*0.0625f + madd[n];
    // ---- online softmax ----
#pragma unroll
    for (int r=0;r<4;++r){
      float rm = sacc[0][r];
#pragma unroll
      for (int n=1;n<4;++n) rm = fmaxf(rm, sacc[n][r]);
#pragma unroll
      for (int x=1;x<16;x<<=1) rm = fmaxf(rm, __shfl_xor(rm, x));
      const float mnew = fmaxf(mrun[r], rm);
      const float alpha = __expf(mrun[r] - mnew);
      float rsum = 0.f;
#pragma unroll
      for (int n=0;n<4;++n){
        float p = __expf(sacc[n][r] - mnew);
        sacc[n][r] = p;
        rsum += p;
      }
#pragma unroll
      for (int x=1;x<16;x<<=1) rsum += __shfl_xor(rsum, x);
      lrun[r] = alpha*lrun[r] + rsum;
      mrun[r] = mnew;
#pragma unroll
      for (int n=0;n<8;++n) oacc[n][r] *= alpha;
    }
    // ---- P -> per-wave LDS (same-wave only, no barrier) ----
#pragma unroll
    for (int n=0;n<4;++n)
#pragma unroll
      for (int r=0;r<4;++r){
        const int row = lg*4 + r;
        pw[(row*128 + (((n*16+lr)*2) ^ ((row&7)<<4)))>>1] = f2bf(sacc[n][r]);
      }
    // ---- PV ----
#pragma unroll
    for (int ks=0;ks<2;++ks){
      bf16x8 pa = ldsr8(&pw[(lr*128 + ((ks*64+lg*16) ^ ((lr&7)<<4)))>>1]);
#pragma unroll
      for (int n=0;n<8;++n){
        const int rv = n*16+lr;
        bf16x8 bvv = ldsr8(&vtls[buf][(rv*128 + ((ks*64+lg*16) ^ ((rv&7)<<4)))>>1]);
        oacc[n] = mfma16(pa, bvv, oacc[n]);
      }
    }
    __syncthreads();   // all waves done with buf -> safe for next prefetch overwrite
  }
#pragma unroll
  for (int r=0;r<4;++r){
    const float inv = lrun[r] > 0.f ? 1.f/lrun[r] : 0.f;
    const int row = q0 + w*16 + lg*4 + r;
#pragma unroll
    for (int n=0;n<8;++n){
      const int col = hh*128 + n*16 + lr;
      ctx[((size_t)(b*2048+row))*256 + col] = f2bf(oacc[n][r]*inv);
    }
  }
}

// ------- LayerNorm + mask-zero (bf16 in -> padded bf16 out) -------
__global__ __launch_bounds__(256)
void ln_mask_b(const u16* __restrict__ X, const u16* __restrict__ g,
               const u16* __restrict__ bta, const u16* __restrict__ cmask,
               u16* __restrict__ outp)
{
  const int w = threadIdx.x>>6, lane = threadIdx.x&63;
  const int row = blockIdx.x*4 + w;
  const u16* xr = X + (size_t)row*256;
  u32x2 rawv = *(const u32x2*)&xr[lane*4];
  float xv[4];
  xv[0]=bf2f((u16)(rawv[0]&0xffffu)); xv[1]=bf2f((u16)(rawv[0]>>16));
  xv[2]=bf2f((u16)(rawv[1]&0xffffu)); xv[3]=bf2f((u16)(rawv[1]>>16));
  float s = xv[0]+xv[1]+xv[2]+xv[3];
#pragma unroll
  for (int x=1;x<64;x<<=1) s += __shfl_xor(s, x);
  const float mu = s * (1.f/256.f);
  float d[4];
#pragma unroll
  for (int j=0;j<4;++j) d[j]=xv[j]-mu;
  float sq = d[0]*d[0]+d[1]*d[1]+d[2]*d[2]+d[3]*d[3];
#pragma unroll
  for (int x=1;x<64;x<<=1) sq += __shfl_xor(sq, x);
  const float rs = rsqrtf(sq*(1.f/256.f) + 1e-5f);
  const int msk = cmask[row];
  u16 o4[4];
#pragma unroll
  for (int j=0;j<4;++j){
    const int c = lane*4 + j;
    float y = d[j]*rs*bf2f(g[c]) + bf2f(bta[c]);
    o4[j] = msk ? (u16)0 : f2bf(y);
  }
  u32x2 ov;
  ov[0] = (u32)o4[0] | ((u32)o4[1]<<16);
  ov[1] = (u32)o4[2] | ((u32)o4[3]<<16);
  const size_t prow = (size_t)row + (row>>11)*8 + 4;
  *(u32x2*)&outp[prow*256 + lane*4] = ov;
}

// ------- final LayerNorm + mask-zero (bf16 in -> f32 out) -------
__global__ __launch_bounds__(256)
void ln_out(const u16* __restrict__ X, const u16* __restrict__ g,
            const u16* __restrict__ bta, const u16* __restrict__ cmask,
            float* __restrict__ out)
{
  const int w = threadIdx.x>>6, lane = threadIdx.x&63;
  const int row = blockIdx.x*4 + w;
  const u16* xr = X + (size_t)row*256;
  u32x2 rawv = *(const u32x2*)&xr[lane*4];
  float xv[4];
  xv[0]=bf2f((u16)(rawv[0]&0xffffu)); xv[1]=bf2f((u16)(rawv[0]>>16));
  xv[2]=bf2f((u16)(rawv[1]&0xffffu)); xv[3]=bf2f((u16)(rawv[1]>>16));
  float s = xv[0]+xv[1]+xv[2]+xv[3];
#pragma unroll
  for (int x=1;x<64;x<<=1) s += __shfl_xor(s, x);
  const float mu = s * (1.f/256.f);
  float d[4];
#pragma unroll
  for (int j=0;j<4;++j) d[j]=xv[j]-mu;
  float sq = d[0]*d[0]+d[1]*d[1]+d[2]*d[2]+d[3]*d[3];
#pragma unroll
  for (int x=1;x<64;x<<=1) sq += __shfl_xor(sq, x);
  const float rs = rsqrtf(sq*(1.f/256.f) + 1e-5f);
  const int msk = cmask[row];
  f32x4 ov;
#pragma unroll
  for (int j=0;j<4;++j){
    const int c = lane*4 + j;
    float y = d[j]*rs*bf2f(g[c]) + bf2f(bta[c]);
    ov[j] = msk ? 0.f : y;
  }
  *(f32x4*)&out[(size_t)row*256 + lane*4] = ov;
}

extern "C" void kernel_launch(void* const* d_in, const int* in_sizes, int n_in,
                              void* d_out, int out_size, void* d_ws, size_t ws_size,
                              hipStream_t stream)
{
  (void)in_sizes; (void)n_in; (void)out_size; (void)ws_size;
  const float* batch=(const float*)d_in[0];  const void* mraw = d_in[1];
  const float* wq=(const float*)d_in[2];  const float* bq=(const float*)d_in[3];
  const float* wk=(const float*)d_in[4];  const float* bk=(const float*)d_in[5];
  const float* wv=(const float*)d_in[6];  const float* bvv=(const float*)d_in[7];
  const float* wo=(const float*)d_in[8];  const float* bo=(const float*)d_in[9];
  const float* g1=(const float*)d_in[10]; const float* be1=(const float*)d_in[11];
  const float* w1=(const float*)d_in[12]; const float* b1=(const float*)d_in[13];
  const float* w2=(const float*)d_in[14]; const float* b2=(const float*)d_in[15];
  const float* g2=(const float*)d_in[16]; const float* be2=(const float*)d_in[17];

  char* ws = (char*)d_ws;
  const size_t M = 1024u*1024u;
  u16*   batchc = (u16*)(ws);          // 0..8M   (dead after QKV gemm)
  u16*   VT     = (u16*)(ws);          // 0..8M   (over batchc; live vtrans..attn)
  u16*   q      = (u16*)(ws + 8*M);    // 8..16M  (dead after attn)
  u16*   tmpb   = (u16*)(ws + 8*M);    // 8..16M  (over q; outproj out, live ..ln_mask_b)
  u16*   kbuf   = (u16*)(ws + 16*M);   // 16..24M (dead after attn)
  u16*   v      = (u16*)(ws + 24*M);   // 24..32M (dead after vtrans)
  u16*   ctx    = (u16*)(ws + 32*M);   // 32..40M (dead after outproj)
  u16*   h      = (u16*)(ws);          // 0..32M  (over VT,tmpb,kbuf,v; live conv1..conv2)
  u16*   x2     = (u16*)(ws + 32*M);   // 32..40M (over ctx; conv2 out, live ..ln_out)
  u16*   seq1p  = (u16*)(ws + 40*M);   // 40..48.1M padded [8][2056][256]
  u16*   wqc    = (u16*)(ws + 49*M);   // wq|wk|wv (768x256), then wo, then w2
  u16*   woc    = wqc + 196608;
  u16*   w2c    = wqc + 262144;
  u16*   w1r    = (u16*)(ws + 50*M);   // 2359296 u16 (4.5 MB)
  u16*   params = w1r + 2359296;
  u16*   cmask  = params + 4096;

  dim3 blk(256,1,1);

  prep_big<<<dim3(13824,1,1), blk, 0, stream>>>(batch, wq, wk, wv, wo, w2, w1,
                                                batchc, wqc, w1r);
  prep_small<<<dim3(66,1,1), blk, 0, stream>>>(bq,bk,bvv,bo,g1,be1,g2,be2,b1,b2,
                                               params, mraw, cmask, seq1p);

  gemm_qkv<<<dim3(128,6,1), blk, 0, stream>>>(batchc, wqc, params, q);

  vtrans<<<dim3(256,4,1), blk, 0, stream>>>(v, VT);

  attn_fwd<<<dim3(32,8,2), blk, 0, stream>>>(q, kbuf, VT, cmask, ctx);

  gemm_nt<false,true,true,false><<<dim3(128,2,1), blk, 0, stream>>>(ctx, woc, params+768, (const void*)batch, (void*)tmpb, 256);
  ln_mask_b<<<dim3(4096,1,1), blk, 0, stream>>>(tmpb, params+1024, params+1280, cmask, seq1p);

  conv1_gemm<<<dim3(128,8,1), blk, 0, stream>>>(seq1p, w1r, params+2048, h);

  gemm_nt<false,true,false,true><<<dim3(128,2,1), blk, 0, stream>>>(h, w2c, params+3072, (const void*)seq1p, (void*)x2, 1024);
  ln_out<<<dim3(4096,1,1), blk, 0, stream>>>(x2, params+1536, params+1792, cmask, (float*)d_out);
}

// Round 13
// 339.752 us; speedup vs baseline: 1.4028x; 1.0047x over previous
//
#include <hip/hip_runtime.h>

typedef unsigned char  u8;
typedef unsigned short u16;
typedef unsigned int   u32;
typedef __attribute__((ext_vector_type(4))) float f32x4;
typedef __attribute__((ext_vector_type(8))) __bf16 bf16x8;
typedef __attribute__((ext_vector_type(4))) u32  u32x4;
typedef __attribute__((ext_vector_type(2))) u32  u32x2;

__device__ __forceinline__ float bf2f(u16 h){ u32 u = ((u32)h)<<16; return __builtin_bit_cast(float, u); }
__device__ __forceinline__ u16  f2bf(float f){
  u32 u = __builtin_bit_cast(u32, f);
  u32 r = u + 0x7FFFu + ((u>>16)&1u);
  return (u16)(r>>16);
}

typedef const __attribute__((address_space(1))) u32 gas_u32;
typedef __attribute__((address_space(3))) u32 las_u32;
__device__ __forceinline__ void gll16(const void* g, void* l){
  __builtin_amdgcn_global_load_lds((gas_u32*)g, (las_u32*)l, 16, 0, 0);
}

__device__ __forceinline__ f32x4 mfma16(bf16x8 a, bf16x8 b, f32x4 c){
  return __builtin_amdgcn_mfma_f32_16x16x32_bf16(a, b, c, 0, 0, 0);
}

__device__ __forceinline__ bf16x8 ldsr8(const u16* p){
  u32x4 v = *(const u32x4*)p;
  return __builtin_bit_cast(bf16x8, v);
}

// XCD co-locate remap: blocks sharing an A-panel (same m-tile) land on one XCD.
__device__ __forceinline__ void xcd_remap(int &m_idx, int &n_idx){
  const int Mt = gridDim.x;
  const int fid = blockIdx.x + Mt*blockIdx.y;
  const int xcd = fid & 7, k = fid >> 3;
  const int mpx = Mt >> 3;
  m_idx = xcd*mpx + (k % mpx);
  n_idx = k / mpx;
}

// ------- prologue A: batch cvt + weight cvt + conv1 weight repack -------
__global__ __launch_bounds__(256)
void prep_big(const float* __restrict__ batch,
              const float* __restrict__ wq, const float* __restrict__ wk,
              const float* __restrict__ wv, const float* __restrict__ wo,
              const float* __restrict__ w2, const float* __restrict__ w1,
              u16* __restrict__ batchc, u16* __restrict__ wqc, u16* __restrict__ w1r)
{
  const int bid = blockIdx.x, tid = threadIdx.x;
  if (bid < 4096){
    const int i = bid*1024 + tid*4;
    f32x4 v = *(const f32x4*)&batch[i];
    u32x2 o;
    o[0] = (u32)f2bf(v[0]) | ((u32)f2bf(v[1])<<16);
    o[1] = (u32)f2bf(v[2]) | ((u32)f2bf(v[3])<<16);
    *(u32x2*)&batchc[i] = o;
  } else if (bid < 4608){
    const int i = (bid-4096)*1024 + tid*4;
    const float* s; int off;
    if      (i < 65536)  { s = wq; off = i; }
    else if (i < 131072) { s = wk; off = i - 65536; }
    else if (i < 196608) { s = wv; off = i - 131072; }
    else if (i < 262144) { s = wo; off = i - 196608; }
    else                 { s = w2; off = i - 262144; }
    f32x4 v = *(const f32x4*)&s[off];
    u32x2 o;
    o[0] = (u32)f2bf(v[0]) | ((u32)f2bf(v[1])<<16);
    o[1] = (u32)f2bf(v[2]) | ((u32)f2bf(v[3])<<16);
    *(u32x2*)&wqc[i] = o;
  } else {
    const int idx = (bid-4608)*256 + tid;
    const int c = idx / 2304;
    const int t = idx - c*2304;
    const int i = t / 9;
    const int kk = t - i*9;
    w1r[c*2304 + kk*256 + i] = f2bf(w1[idx]);
  }
}

// ------- prologue B: params + mask canon + seq1p halo zero -------
__global__ __launch_bounds__(256)
void prep_small(const float* p0,const float* p1,const float* p2,const float* p3,
                const float* p4,const float* p5,const float* p6,const float* p7,
                const float* p8,const float* p9,
                u16* __restrict__ params, const void* __restrict__ mraw,
                u16* __restrict__ cmask, u16* __restrict__ seq1p)
{
  const int bid = blockIdx.x, tid = threadIdx.x;
  if (bid == 0){
    const float* ps[10] = {p0,p1,p2,p3,p4,p5,p6,p7,p8,p9};
    const int  off[10] = {0,256,512,768,1024,1280,1536,1792,2048,3072};
    const int  len[10] = {256,256,256,256,256,256,256,256,1024,256};
    for (int a=0;a<10;++a)
      for (int i=tid;i<len[a];i+=256)
        params[off[a]+i] = f2bf(ps[a][i]);
  } else if (bid == 1){
    const u8*  pb8  = (const u8*)mraw;
    const u16* pb16 = (const u16*)mraw;
    const u32* pb32 = (const u32*)mraw;
    __shared__ int bad8, bad16, nz8, nz16;
    if (tid==0){ bad8=0; bad16=0; nz8=0; nz16=0; }
    __syncthreads();
    for (int i=tid;i<16384;i+=256){
      u8 v = pb8[i]; int row = i & 2047;
      if (v>1) atomicOr(&bad8,1);
      if (v){ atomicOr(&nz8,1); if (row<1024) atomicOr(&bad8,1); }
      if (row>0 && pb8[i-1]==1 && v==0) atomicOr(&bad8,1);
    }
    for (int i=tid;i<8192;i+=256){
      u16 v = pb16[i]; int row = i & 2047;
      if (!(v==0 || v==0x3F80)) atomicOr(&bad16,1);
      if (v){ atomicOr(&nz16,1); if (row<1024) atomicOr(&bad16,1); }
      if (row>0 && pb16[i-1]==0x3F80 && v==0) atomicOr(&bad16,1);
    }
    __syncthreads();
    const int mode = (!bad8 && nz8) ? 1 : ((!bad16 && nz16) ? 2 : 0);
    for (int i=tid;i<16384;i+=256){
      u16 m;
      if (mode==1)      m = pb8[i]  ? 1 : 0;
      else if (mode==2) m = pb16[i] ? 1 : 0;
      else              m = pb32[i] ? 1 : 0;
      cmask[i] = m;
    }
  } else {
    const int idx = (bid-2)*256 + tid;     // 16384 halo elems
    const int b = idx>>11, t = idx&2047;
    const int r = t>>8, c = t&255;
    const int row = (r<4) ? r : (2052 + r - 4);
    seq1p[((size_t)b*2056 + row)*256 + c] = 0;
  }
}

// ------- GEMM: C = A·W^T + bias [+res]; optional padded residual; optional masked-tile skip -------
template<bool OUT_F32, bool ADD_RES, bool RES_F32, bool RES_PAD, bool SKIPM>
__global__ __launch_bounds__(256)
void gemm_nt(const u16* __restrict__ A, const u16* __restrict__ W,
             const u16* __restrict__ bias, const void* __restrict__ res,
             void* __restrict__ out, int K, const u16* __restrict__ cmask)
{
  __shared__ __align__(16) u16 aL[2][4096];
  __shared__ __align__(16) u16 bL[2][4096];
  const int tid = threadIdx.x, lane = tid&63, w = tid>>6;
  const int wm = w>>1, wn = w&1, lr = lane&15, lg = lane>>4;
  int mi, ni; xcd_remap(mi, ni);
  const int m0 = mi*128, n0 = ni*128;
  if constexpr (SKIPM){
    if (cmask[m0] != 0) return;   // whole 128-row tile masked -> output is dont-care
  }
  const int nk = K>>5;

  f32x4 acc[4][4];
#pragma unroll
  for (int i=0;i<4;++i)
#pragma unroll
    for (int j=0;j<4;++j) acc[i][j] = f32x4{0.f,0.f,0.f,0.f};

  auto stage = [&](int buf, int kk){
#pragma unroll
    for (int i=0;i<2;++i){
      const int chunk = w*2+i;
      const int boff  = chunk*1024 + lane*16;
      const int r = boff>>6;
      const int cb = (boff&63) ^ (((r>>1)&3)<<4);
      const int c = cb>>1;
      gll16(&A[(size_t)(m0+r)*K + kk*32 + c], &aL[buf][chunk*512]);
      gll16(&W[(size_t)(n0+r)*K + kk*32 + c], &bL[buf][chunk*512]);
    }
  };

  stage(0,0);
  __syncthreads();
  for (int kk=0; kk<nk; ++kk){
    if (kk+1<nk) stage((kk+1)&1, kk+1);
    const u16* ab = aL[kk&1];
    const u16* bb = bL[kk&1];
    bf16x8 af[4], bv[4];
#pragma unroll
    for (int m=0;m<4;++m){
      const int ra = wm*64+m*16+lr;
      af[m] = ldsr8(&ab[(ra*64 + ((lg*16) ^ (((ra>>1)&3)<<4)))>>1]);
    }
#pragma unroll
    for (int n=0;n<4;++n){
      const int rb = wn*64+n*16+lr;
      bv[n] = ldsr8(&bb[(rb*64 + ((lg*16) ^ (((rb>>1)&3)<<4)))>>1]);
    }
#pragma unroll
    for (int m=0;m<4;++m)
#pragma unroll
      for (int n=0;n<4;++n)
        acc[m][n] = mfma16(af[m], bv[n], acc[m][n]);
    __syncthreads();
  }
#pragma unroll
  for (int m=0;m<4;++m)
#pragma unroll
    for (int n=0;n<4;++n)
#pragma unroll
      for (int r=0;r<4;++r){
        const int row = m0 + wm*64 + m*16 + lg*4 + r;
        const int col = n0 + wn*64 + n*16 + lr;
        float v = acc[m][n][r] + bf2f(bias[col]);
        if constexpr (ADD_RES){
          size_t ri = (size_t)row*256 + col;
          if constexpr (RES_PAD) ri = ((size_t)row + (row>>11)*8 + 4)*256 + col;
          if constexpr (RES_F32) v += ((const float*)res)[ri];
          else                   v += bf2f(((const u16*)res)[ri]);
        }
        if constexpr (OUT_F32) ((float*)out)[(size_t)row*256 + col] = v;
        else                   ((u16*)out)[(size_t)row*256 + col] = f2bf(v);
      }
}

// ------- fused QKV GEMM: W = [wq;wk;wv] (768 x 256); out array picked by col>>8 -------
// Masked m-tiles skipped: their q/k/v rows are dont-care (attn never reads masked
// K/V tiles past its break; masked-q ctx is squashed by ln_mask).
__global__ __launch_bounds__(256)
void gemm_qkv(const u16* __restrict__ A, const u16* __restrict__ W,
              const u16* __restrict__ bias, u16* __restrict__ qbase,
              const u16* __restrict__ cmask)
{
  __shared__ __align__(16) u16 aL[2][4096];
  __shared__ __align__(16) u16 bL[2][4096];
  const int tid = threadIdx.x, lane = tid&63, w = tid>>6;
  const int wm = w>>1, wn = w&1, lr = lane&15, lg = lane>>4;
  int mi, ni; xcd_remap(mi, ni);
  const int m0 = mi*128, n0 = ni*128;
  if (cmask[m0] != 0) return;

  f32x4 acc[4][4];
#pragma unroll
  for (int i=0;i<4;++i)
#pragma unroll
    for (int j=0;j<4;++j) acc[i][j] = f32x4{0.f,0.f,0.f,0.f};

  auto stage = [&](int buf, int kk){
#pragma unroll
    for (int i=0;i<2;++i){
      const int chunk = w*2+i;
      const int boff  = chunk*1024 + lane*16;
      const int r = boff>>6;
      const int cb = (boff&63) ^ (((r>>1)&3)<<4);
      const int c = cb>>1;
      gll16(&A[(size_t)(m0+r)*256 + kk*32 + c], &aL[buf][chunk*512]);
      gll16(&W[(size_t)(n0+r)*256 + kk*32 + c], &bL[buf][chunk*512]);
    }
  };

  stage(0,0);
  __syncthreads();
  for (int kk=0; kk<8; ++kk){
    if (kk+1<8) stage((kk+1)&1, kk+1);
    const u16* ab = aL[kk&1];
    const u16* bb = bL[kk&1];
    bf16x8 af[4], bv[4];
#pragma unroll
    for (int m=0;m<4;++m){
      const int ra = wm*64+m*16+lr;
      af[m] = ldsr8(&ab[(ra*64 + ((lg*16) ^ (((ra>>1)&3)<<4)))>>1]);
    }
#pragma unroll
    for (int n=0;n<4;++n){
      const int rb = wn*64+n*16+lr;
      bv[n] = ldsr8(&bb[(rb*64 + ((lg*16) ^ (((rb>>1)&3)<<4)))>>1]);
    }
#pragma unroll
    for (int m=0;m<4;++m)
#pragma unroll
      for (int n=0;n<4;++n)
        acc[m][n] = mfma16(af[m], bv[n], acc[m][n]);
    __syncthreads();
  }
#pragma unroll
  for (int m=0;m<4;++m)
#pragma unroll
    for (int n=0;n<4;++n)
#pragma unroll
      for (int r=0;r<4;++r){
        const int row = m0 + wm*64 + m*16 + lg*4 + r;
        const int col = n0 + wn*64 + n*16 + lr;
        const int which = col>>8, ch = col&255;
        float v = acc[m][n][r] + bf2f(bias[col]);
        qbase[(size_t)which*4194304 + (size_t)row*256 + ch] = f2bf(v);
      }
}

// ------- conv1 as m97-style GEMM over padded input: K = 2304 (tap-major) -------
__global__ __launch_bounds__(256)
void conv1_gemm(const u16* __restrict__ Ap,   // [8][2056][256] zero-haloed
                const u16* __restrict__ W1r,  // [1024][2304], k = tap*256+i
                const u16* __restrict__ b1, u16* __restrict__ Hout,
                const u16* __restrict__ cmask)
{
  __shared__ __align__(16) u16 aL[2][4096];
  __shared__ __align__(16) u16 bL[2][4096];
  const int tid = threadIdx.x, lane = tid&63, w = tid>>6;
  const int wm = w>>1, wn = w&1, lr = lane&15, lg = lane>>4;
  int mi, ni; xcd_remap(mi, ni);
  const int m0 = mi*128, n0 = ni*128;
  if (cmask[m0] != 0) return;   // masked token tile -> h rows are dont-care
  const int b = m0>>11, s0 = m0&2047;
  const size_t abase = ((size_t)b*2056 + s0)*256;

  f32x4 acc[4][4];
#pragma unroll
  for (int i=0;i<4;++i)
#pragma unroll
    for (int j=0;j<4;++j) acc[i][j] = f32x4{0.f,0.f,0.f,0.f};

  auto stage = [&](int buf, int kk){
    const int tap = kk>>3, ch0 = (kk&7)*32;
#pragma unroll
    for (int i=0;i<2;++i){
      const int chunk = w*2+i;
      const int boff  = chunk*1024 + lane*16;
      const int r = boff>>6;
      const int cb = (boff&63) ^ (((r>>1)&3)<<4);
      const int c = cb>>1;
      gll16(&Ap[abase + (size_t)(tap + r)*256 + ch0 + c], &aL[buf][chunk*512]);
      gll16(&W1r[(size_t)(n0+r)*2304 + kk*32 + c], &bL[buf][chunk*512]);
    }
  };

  stage(0,0);
  __syncthreads();
  for (int kk=0; kk<72; ++kk){
    if (kk+1<72) stage((kk+1)&1, kk+1);
    const u16* ab = aL[kk&1];
    const u16* bb = bL[kk&1];
    bf16x8 af[4], bv[4];
#pragma unroll
    for (int m=0;m<4;++m){
      const int ra = wm*64+m*16+lr;
      af[m] = ldsr8(&ab[(ra*64 + ((lg*16) ^ (((ra>>1)&3)<<4)))>>1]);
    }
#pragma unroll
    for (int n=0;n<4;++n){
      const int rb = wn*64+n*16+lr;
      bv[n] = ldsr8(&bb[(rb*64 + ((lg*16) ^ (((rb>>1)&3)<<4)))>>1]);
    }
#pragma unroll
    for (int m=0;m<4;++m)
#pragma unroll
      for (int n=0;n<4;++n)
        acc[m][n] = mfma16(af[m], bv[n], acc[m][n]);
    __syncthreads();
  }
#pragma unroll
  for (int m=0;m<4;++m)
#pragma unroll
    for (int n=0;n<4;++n)
#pragma unroll
      for (int r=0;r<4;++r){
        const int row = m0 + wm*64 + m*16 + lg*4 + r;
        const int col = n0 + wn*64 + n*16 + lr;
        float v = acc[m][n][r] + bf2f(b1[col]);
        v = v>0.f ? v : 0.f;
        Hout[(size_t)row*1024 + col] = f2bf(v);
      }
}

// ------- V [16384][256] -> VT [b][h][128][2048] -------
__global__ __launch_bounds__(256)
void vtrans(const u16* __restrict__ V, u16* __restrict__ VT)
{
  __shared__ u16 t[64][72];
  const int tid = threadIdx.x;
  const int s0 = blockIdx.x*64;
  const int d0 = blockIdx.y*64;
#pragma unroll
  for (int i=0;i<2;++i){
    const int chunk = tid + i*256;
    const int sr = chunk>>3, c8 = (chunk&7)*8;
    u32x4 raw = *(const u32x4*)&V[(size_t)(s0+sr)*256 + d0 + c8];
#pragma unroll
    for (int j=0;j<4;++j){
      t[sr][c8+2*j]   = (u16)(raw[j]&0xffffu);
      t[sr][c8+2*j+1] = (u16)(raw[j]>>16);
    }
  }
  __syncthreads();
  const int b = s0>>11;
#pragma unroll
  for (int i=0;i<2;++i){
    const int chunk = tid + i*256;
    const int dr = chunk>>3, s8 = (chunk&7)*8;
    const int dg = d0 + dr;
    const int hh = dg>>7, dh = dg&127;
    u32x4 o;
#pragma unroll
    for (int j=0;j<4;++j)
      o[j] = (u32)t[s8+2*j][dr] | ((u32)t[s8+2*j+1][dr]<<16);
    *(u32x4*)&VT[((size_t)((b*2+hh)*128 + dh))*2048 + (s0&2047) + s8] = o;
  }
}

// ------- flash attention: KVBLK=64, double-buffered gll16 staging, 1 barrier/tile -------
__global__ __launch_bounds__(256)
void attn_fwd(const u16* __restrict__ Q, const u16* __restrict__ Kb,
              const u16* __restrict__ VT, const u16* __restrict__ cmask,
              u16* __restrict__ ctx)
{
  __shared__ __align__(16) u16 kls[2][64*128];   // [kv][d] 256B rows, sw (r&7)<<4
  __shared__ __align__(16) u16 vtls[2][128*64];  // [d][kv] 128B rows, sw (r&7)<<4
  __shared__ __align__(16) u16 pls[4][16*64];    // per-wave P, 128B rows
  const int tid = threadIdx.x, lane = tid&63, w = tid>>6;
  const int qt = blockIdx.x, b = blockIdx.y, hh = blockIdx.z;
  const int q0 = qt*64;
  if (cmask[b*2048 + q0] != 0) return;   // whole q-tile masked -> ctx dont-care
  const int lr = lane&15, lg = lane>>4;
  u16* pw = pls[w];

  bf16x8 qf[4];
#pragma unroll
  for (int d=0;d<4;++d)
    qf[d] = *(const bf16x8*)&Q[((size_t)(b*2048+q0+w*16+lr))*256 + hh*128 + d*32 + lg*8];

  f32x4 oacc[8];
  float mrun[4], lrun[4];
#pragma unroll
  for (int n=0;n<8;++n) oacc[n] = f32x4{0.f,0.f,0.f,0.f};
#pragma unroll
  for (int r=0;r<4;++r){ mrun[r] = -1e30f; lrun[r] = 0.f; }

  const size_t kbase = (size_t)(b*2048)*256 + hh*128;
  const size_t vbase = (size_t)((b*2+hh)*128)*2048;

  auto stage = [&](int buf, int kt){
    const int kv0 = kt*64;
#pragma unroll
    for (int i=0;i<4;++i){                       // K tile: 16 KB, 64 rows x 256B
      const int chunk = w*4+i;
      const int boff = chunk*1024 + lane*16;
      const int r = boff>>8;
      const int cb = (boff&255) ^ ((r&7)<<4);
      gll16(&Kb[kbase + (size_t)(kv0+r)*256 + (cb>>1)], &kls[buf][chunk*512]);
    }
#pragma unroll
    for (int i=0;i<4;++i){                       // VT tile: 16 KB, 128 rows x 128B
      const int chunk = w*4+i;
      const int boff = chunk*1024 + lane*16;
      const int r = boff>>7;
      const int cb = (boff&127) ^ ((r&7)<<4);
      gll16(&VT[vbase + (size_t)r*2048 + kv0 + (cb>>1)], &vtls[buf][chunk*512]);
    }
  };

  stage(0, 0);
  __syncthreads();

  for (int kt=0; kt<32; ++kt){
    const int kv0 = kt*64;
    if (cmask[b*2048 + kv0] != 0) break;
    const int buf = kt&1;
    if (kt+1 < 32) stage(buf^1, kt+1);           // prefetch overlaps this tile's compute
    // ---- QK^T ----
    f32x4 sacc[4];
#pragma unroll
    for (int n=0;n<4;++n) sacc[n] = f32x4{0.f,0.f,0.f,0.f};
#pragma unroll
    for (int dk=0;dk<4;++dk){
      bf16x8 bk[4];
#pragma unroll
      for (int n=0;n<4;++n){
        const int rb = n*16+lr;
        bk[n] = ldsr8(&kls[buf][(rb*256 + ((dk*64+lg*16) ^ ((rb&7)<<4)))>>1]);
      }
#pragma unroll
      for (int n=0;n<4;++n)
        sacc[n] = mfma16(qf[dk], bk[n], sacc[n]);
    }
    // ---- scale + key mask ----
    float madd[4];
#pragma unroll
    for (int n=0;n<4;++n)
      madd[n] = cmask[b*2048 + kv0 + n*16 + lr] ? -1e30f : 0.f;
#pragma unroll
    for (int n=0;n<4;++n)
#pragma unroll
      for (int r=0;r<4;++r)
        sacc[n][r] = sacc[n][r]*0.0625f + madd[n];
    // ---- online softmax ----
#pragma unroll
    for (int r=0;r<4;++r){
      float rm = sacc[0][r];
#pragma unroll
      for (int n=1;n<4;++n) rm = fmaxf(rm, sacc[n][r]);
#pragma unroll
      for (int x=1;x<16;x<<=1) rm = fmaxf(rm, __shfl_xor(rm, x));
      const float mnew = fmaxf(mrun[r], rm);
      const float alpha = __expf(mrun[r] - mnew);
      float rsum = 0.f;
#pragma unroll
      for (int n=0;n<4;++n){
        float p = __expf(sacc[n][r] - mnew);
        sacc[n][r] = p;
        rsum += p;
      }
#pragma unroll
      for (int x=1;x<16;x<<=1) rsum += __shfl_xor(rsum, x);
      lrun[r] = alpha*lrun[r] + rsum;
      mrun[r] = mnew;
#pragma unroll
      for (int n=0;n<8;++n) oacc[n][r] *= alpha;
    }
    // ---- P -> per-wave LDS (same-wave only, no barrier) ----
#pragma unroll
    for (int n=0;n<4;++n)
#pragma unroll
      for (int r=0;r<4;++r){
        const int row = lg*4 + r;
        pw[(row*128 + (((n*16+lr)*2) ^ ((row&7)<<4)))>>1] = f2bf(sacc[n][r]);
      }
    // ---- PV ----
#pragma unroll
    for (int ks=0;ks<2;++ks){
      bf16x8 pa = ldsr8(&pw[(lr*128 + ((ks*64+lg*16) ^ ((lr&7)<<4)))>>1]);
#pragma unroll
      for (int n=0;n<8;++n){
        const int rv = n*16+lr;
        bf16x8 bvv = ldsr8(&vtls[buf][(rv*128 + ((ks*64+lg*16) ^ ((rv&7)<<4)))>>1]);
        oacc[n] = mfma16(pa, bvv, oacc[n]);
      }
    }
    __syncthreads();   // all waves done with buf -> safe for next prefetch overwrite
  }
#pragma unroll
  for (int r=0;r<4;++r){
    const float inv = lrun[r] > 0.f ? 1.f/lrun[r] : 0.f;
    const int row = q0 + w*16 + lg*4 + r;
#pragma unroll
    for (int n=0;n<8;++n){
      const int col = hh*128 + n*16 + lr;
      ctx[((size_t)(b*2048+row))*256 + col] = f2bf(oacc[n][r]*inv);
    }
  }
}

// ------- LayerNorm + mask-zero (bf16 in -> padded bf16 out) -------
__global__ __launch_bounds__(256)
void ln_mask_b(const u16* __restrict__ X, const u16* __restrict__ g,
               const u16* __restrict__ bta, const u16* __restrict__ cmask,
               u16* __restrict__ outp)
{
  const int w = threadIdx.x>>6, lane = threadIdx.x&63;
  const int row = blockIdx.x*4 + w;
  const u16* xr = X + (size_t)row*256;
  u32x2 rawv = *(const u32x2*)&xr[lane*4];
  float xv[4];
  xv[0]=bf2f((u16)(rawv[0]&0xffffu)); xv[1]=bf2f((u16)(rawv[0]>>16));
  xv[2]=bf2f((u16)(rawv[1]&0xffffu)); xv[3]=bf2f((u16)(rawv[1]>>16));
  float s = xv[0]+xv[1]+xv[2]+xv[3];
#pragma unroll
  for (int x=1;x<64;x<<=1) s += __shfl_xor(s, x);
  const float mu = s * (1.f/256.f);
  float d[4];
#pragma unroll
  for (int j=0;j<4;++j) d[j]=xv[j]-mu;
  float sq = d[0]*d[0]+d[1]*d[1]+d[2]*d[2]+d[3]*d[3];
#pragma unroll
  for (int x=1;x<64;x<<=1) sq += __shfl_xor(sq, x);
  const float rs = rsqrtf(sq*(1.f/256.f) + 1e-5f);
  const int msk = cmask[row];
  u16 o4[4];
#pragma unroll
  for (int j=0;j<4;++j){
    const int c = lane*4 + j;
    float y = d[j]*rs*bf2f(g[c]) + bf2f(bta[c]);
    o4[j] = msk ? (u16)0 : f2bf(y);
  }
  u32x2 ov;
  ov[0] = (u32)o4[0] | ((u32)o4[1]<<16);
  ov[1] = (u32)o4[2] | ((u32)o4[3]<<16);
  const size_t prow = (size_t)row + (row>>11)*8 + 4;
  *(u32x2*)&outp[prow*256 + lane*4] = ov;
}

// ------- final LayerNorm + mask-zero (bf16 in -> f32 out) -------
__global__ __launch_bounds__(256)
void ln_out(const u16* __restrict__ X, const u16* __restrict__ g,
            const u16* __restrict__ bta, const u16* __restrict__ cmask,
            float* __restrict__ out)
{
  const int w = threadIdx.x>>6, lane = threadIdx.x&63;
  const int row = blockIdx.x*4 + w;
  const u16* xr = X + (size_t)row*256;
  u32x2 rawv = *(const u32x2*)&xr[lane*4];
  float xv[4];
  xv[0]=bf2f((u16)(rawv[0]&0xffffu)); xv[1]=bf2f((u16)(rawv[0]>>16));
  xv[2]=bf2f((u16)(rawv[1]&0xffffu)); xv[3]=bf2f((u16)(rawv[1]>>16));
  float s = xv[0]+xv[1]+xv[2]+xv[3];
#pragma unroll
  for (int x=1;x<64;x<<=1) s += __shfl_xor(s, x);
  const float mu = s * (1.f/256.f);
  float d[4];
#pragma unroll
  for (int j=0;j<4;++j) d[j]=xv[j]-mu;
  float sq = d[0]*d[0]+d[1]*d[1]+d[2]*d[2]+d[3]*d[3];
#pragma unroll
  for (int x=1;x<64;x<<=1) sq += __shfl_xor(sq, x);
  const float rs = rsqrtf(sq*(1.f/256.f) + 1e-5f);
  const int msk = cmask[row];
  f32x4 ov;
#pragma unroll
  for (int j=0;j<4;++j){
    const int c = lane*4 + j;
    float y = d[j]*rs*bf2f(g[c]) + bf2f(bta[c]);
    ov[j] = msk ? 0.f : y;
  }
  *(f32x4*)&out[(size_t)row*256 + lane*4] = ov;
}

extern "C" void kernel_launch(void* const* d_in, const int* in_sizes, int n_in,
                              void* d_out, int out_size, void* d_ws, size_t ws_size,
                              hipStream_t stream)
{
  (void)in_sizes; (void)n_in; (void)out_size; (void)ws_size;
  const float* batch=(const float*)d_in[0];  const void* mraw = d_in[1];
  const float* wq=(const float*)d_in[2];  const float* bq=(const float*)d_in[3];
  const float* wk=(const float*)d_in[4];  const float* bk=(const float*)d_in[5];
  const float* wv=(const float*)d_in[6];  const float* bvv=(const float*)d_in[7];
  const float* wo=(const float*)d_in[8];  const float* bo=(const float*)d_in[9];
  const float* g1=(const float*)d_in[10]; const float* be1=(const float*)d_in[11];
  const float* w1=(const float*)d_in[12]; const float* b1=(const float*)d_in[13];
  const float* w2=(const float*)d_in[14]; const float* b2=(const float*)d_in[15];
  const float* g2=(const float*)d_in[16]; const float* be2=(const float*)d_in[17];

  char* ws = (char*)d_ws;
  const size_t M = 1024u*1024u;
  u16*   batchc = (u16*)(ws);          // 0..8M   (dead after QKV gemm)
  u16*   VT     = (u16*)(ws);          // 0..8M   (over batchc; live vtrans..attn)
  u16*   q      = (u16*)(ws + 8*M);    // 8..16M  (dead after attn)
  u16*   tmpb   = (u16*)(ws + 8*M);    // 8..16M  (over q; outproj out, live ..ln_mask_b)
  u16*   kbuf   = (u16*)(ws + 16*M);   // 16..24M (dead after attn)
  u16*   v      = (u16*)(ws + 24*M);   // 24..32M (dead after vtrans)
  u16*   ctx    = (u16*)(ws + 32*M);   // 32..40M (dead after outproj)
  u16*   h      = (u16*)(ws);          // 0..32M  (over VT,tmpb,kbuf,v; live conv1..conv2)
  u16*   x2     = (u16*)(ws + 32*M);   // 32..40M (over ctx; conv2 out, live ..ln_out)
  u16*   seq1p  = (u16*)(ws + 40*M);   // 40..48.1M padded [8][2056][256]
  u16*   wqc    = (u16*)(ws + 49*M);   // wq|wk|wv (768x256), then wo, then w2
  u16*   woc    = wqc + 196608;
  u16*   w2c    = wqc + 262144;
  u16*   w1r    = (u16*)(ws + 50*M);   // 2359296 u16 (4.5 MB)
  u16*   params = w1r + 2359296;
  u16*   cmask  = params + 4096;

  dim3 blk(256,1,1);

  prep_big<<<dim3(13824,1,1), blk, 0, stream>>>(batch, wq, wk, wv, wo, w2, w1,
                                                batchc, wqc, w1r);
  prep_small<<<dim3(66,1,1), blk, 0, stream>>>(bq,bk,bvv,bo,g1,be1,g2,be2,b1,b2,
                                               params, mraw, cmask, seq1p);

  gemm_qkv<<<dim3(128,6,1), blk, 0, stream>>>(batchc, wqc, params, q, cmask);

  vtrans<<<dim3(256,4,1), blk, 0, stream>>>(v, VT);

  attn_fwd<<<dim3(32,8,2), blk, 0, stream>>>(q, kbuf, VT, cmask, ctx);

  gemm_nt<false,true,true,false,true><<<dim3(128,2,1), blk, 0, stream>>>(ctx, woc, params+768, (const void*)batch, (void*)tmpb, 256, cmask);
  ln_mask_b<<<dim3(4096,1,1), blk, 0, stream>>>(tmpb, params+1024, params+1280, cmask, seq1p);

  conv1_gemm<<<dim3(128,8,1), blk, 0, stream>>>(seq1p, w1r, params+2048, h, cmask);

  gemm_nt<false,true,false,true,true><<<dim3(128,2,1), blk, 0, stream>>>(h, w2c, params+3072, (const void*)seq1p, (void*)x2, 1024, cmask);
  ln_out<<<dim3(4096,1,1), blk, 0, stream>>>(x2, params+1536, params+1792, cmask, (float*)d_out);
}

// Round 14
// 328.384 us; speedup vs baseline: 1.4514x; 1.0346x over previous
//
#include <hip/hip_runtime.h>

typedef unsigned char  u8;
typedef unsigned short u16;
typedef unsigned int   u32;
typedef __attribute__((ext_vector_type(4))) float f32x4;
typedef __attribute__((ext_vector_type(8))) __bf16 bf16x8;
typedef __attribute__((ext_vector_type(4))) u32  u32x4;
typedef __attribute__((ext_vector_type(2))) u32  u32x2;

__device__ __forceinline__ float bf2f(u16 h){ u32 u = ((u32)h)<<16; return __builtin_bit_cast(float, u); }
__device__ __forceinline__ u16  f2bf(float f){
  u32 u = __builtin_bit_cast(u32, f);
  u32 r = u + 0x7FFFu + ((u>>16)&1u);
  return (u16)(r>>16);
}

typedef const __attribute__((address_space(1))) u32 gas_u32;
typedef __attribute__((address_space(3))) u32 las_u32;
__device__ __forceinline__ void gll16(const void* g, void* l){
  __builtin_amdgcn_global_load_lds((gas_u32*)g, (las_u32*)l, 16, 0, 0);
}

__device__ __forceinline__ f32x4 mfma16(bf16x8 a, bf16x8 b, f32x4 c){
  return __builtin_amdgcn_mfma_f32_16x16x32_bf16(a, b, c, 0, 0, 0);
}

__device__ __forceinline__ bf16x8 ldsr8(const u16* p){
  u32x4 v = *(const u32x4*)p;
  return __builtin_bit_cast(bf16x8, v);
}

// XCD co-locate remap: blocks sharing an A-panel (same m-tile) land on one XCD.
__device__ __forceinline__ void xcd_remap(int &m_idx, int &n_idx){
  const int Mt = gridDim.x;
  const int fid = blockIdx.x + Mt*blockIdx.y;
  const int xcd = fid & 7, k = fid >> 3;
  const int mpx = Mt >> 3;
  m_idx = xcd*mpx + (k % mpx);
  n_idx = k / mpx;
}

// ------- prologue A: batch cvt + weight cvt + conv1 weight repack -------
__global__ __launch_bounds__(256)
void prep_big(const float* __restrict__ batch,
              const float* __restrict__ wq, const float* __restrict__ wk,
              const float* __restrict__ wv, const float* __restrict__ wo,
              const float* __restrict__ w2, const float* __restrict__ w1,
              u16* __restrict__ batchc, u16* __restrict__ wqc, u16* __restrict__ w1r)
{
  const int bid = blockIdx.x, tid = threadIdx.x;
  if (bid < 4096){
    const int i = bid*1024 + tid*4;
    f32x4 v = *(const f32x4*)&batch[i];
    u32x2 o;
    o[0] = (u32)f2bf(v[0]) | ((u32)f2bf(v[1])<<16);
    o[1] = (u32)f2bf(v[2]) | ((u32)f2bf(v[3])<<16);
    *(u32x2*)&batchc[i] = o;
  } else if (bid < 4608){
    const int i = (bid-4096)*1024 + tid*4;
    const float* s; int off;
    if      (i < 65536)  { s = wq; off = i; }
    else if (i < 131072) { s = wk; off = i - 65536; }
    else if (i < 196608) { s = wv; off = i - 131072; }
    else if (i < 262144) { s = wo; off = i - 196608; }
    else                 { s = w2; off = i - 262144; }
    f32x4 v = *(const f32x4*)&s[off];
    u32x2 o;
    o[0] = (u32)f2bf(v[0]) | ((u32)f2bf(v[1])<<16);
    o[1] = (u32)f2bf(v[2]) | ((u32)f2bf(v[3])<<16);
    *(u32x2*)&wqc[i] = o;
  } else {
    const int idx = (bid-4608)*256 + tid;
    const int c = idx / 2304;
    const int t = idx - c*2304;
    const int i = t / 9;
    const int kk = t - i*9;
    w1r[c*2304 + kk*256 + i] = f2bf(w1[idx]);
  }
}

// ------- prologue B: params + mask canon + seq1p halo zero -------
__global__ __launch_bounds__(256)
void prep_small(const float* p0,const float* p1,const float* p2,const float* p3,
                const float* p4,const float* p5,const float* p6,const float* p7,
                const float* p8,const float* p9,
                u16* __restrict__ params, const void* __restrict__ mraw,
                u16* __restrict__ cmask, u16* __restrict__ seq1p)
{
  const int bid = blockIdx.x, tid = threadIdx.x;
  if (bid == 0){
    const float* ps[10] = {p0,p1,p2,p3,p4,p5,p6,p7,p8,p9};
    const int  off[10] = {0,256,512,768,1024,1280,1536,1792,2048,3072};
    const int  len[10] = {256,256,256,256,256,256,256,256,1024,256};
    for (int a=0;a<10;++a)
      for (int i=tid;i<len[a];i+=256)
        params[off[a]+i] = f2bf(ps[a][i]);
  } else if (bid == 1){
    const u8*  pb8  = (const u8*)mraw;
    const u16* pb16 = (const u16*)mraw;
    const u32* pb32 = (const u32*)mraw;
    __shared__ int bad8, bad16, nz8, nz16;
    if (tid==0){ bad8=0; bad16=0; nz8=0; nz16=0; }
    __syncthreads();
    for (int i=tid;i<16384;i+=256){
      u8 v = pb8[i]; int row = i & 2047;
      if (v>1) atomicOr(&bad8,1);
      if (v){ atomicOr(&nz8,1); if (row<1024) atomicOr(&bad8,1); }
      if (row>0 && pb8[i-1]==1 && v==0) atomicOr(&bad8,1);
    }
    for (int i=tid;i<8192;i+=256){
      u16 v = pb16[i]; int row = i & 2047;
      if (!(v==0 || v==0x3F80)) atomicOr(&bad16,1);
      if (v){ atomicOr(&nz16,1); if (row<1024) atomicOr(&bad16,1); }
      if (row>0 && pb16[i-1]==0x3F80 && v==0) atomicOr(&bad16,1);
    }
    __syncthreads();
    const int mode = (!bad8 && nz8) ? 1 : ((!bad16 && nz16) ? 2 : 0);
    for (int i=tid;i<16384;i+=256){
      u16 m;
      if (mode==1)      m = pb8[i]  ? 1 : 0;
      else if (mode==2) m = pb16[i] ? 1 : 0;
      else              m = pb32[i] ? 1 : 0;
      cmask[i] = m;
    }
  } else {
    const int idx = (bid-2)*256 + tid;     // 16384 halo elems
    const int b = idx>>11, t = idx&2047;
    const int r = t>>8, c = t&255;
    const int row = (r<4) ? r : (2052 + r - 4);
    seq1p[((size_t)b*2056 + row)*256 + c] = 0;
  }
}

// ------- GEMM: C = A·W^T + bias [+res]; optional padded residual; optional masked-tile skip -------
template<bool OUT_F32, bool ADD_RES, bool RES_F32, bool RES_PAD, bool SKIPM>
__global__ __launch_bounds__(256)
void gemm_nt(const u16* __restrict__ A, const u16* __restrict__ W,
             const u16* __restrict__ bias, const void* __restrict__ res,
             void* __restrict__ out, int K, const u16* __restrict__ cmask)
{
  __shared__ __align__(16) u16 aL[2][4096];
  __shared__ __align__(16) u16 bL[2][4096];
  const int tid = threadIdx.x, lane = tid&63, w = tid>>6;
  const int wm = w>>1, wn = w&1, lr = lane&15, lg = lane>>4;
  int mi, ni; xcd_remap(mi, ni);
  const int m0 = mi*128, n0 = ni*128;
  if constexpr (SKIPM){
    if (cmask[m0] != 0) return;   // whole 128-row tile masked -> output is dont-care
  }
  const int nk = K>>5;

  f32x4 acc[4][4];
#pragma unroll
  for (int i=0;i<4;++i)
#pragma unroll
    for (int j=0;j<4;++j) acc[i][j] = f32x4{0.f,0.f,0.f,0.f};

  auto stage = [&](int buf, int kk){
#pragma unroll
    for (int i=0;i<2;++i){
      const int chunk = w*2+i;
      const int boff  = chunk*1024 + lane*16;
      const int r = boff>>6;
      const int cb = (boff&63) ^ (((r>>1)&3)<<4);
      const int c = cb>>1;
      gll16(&A[(size_t)(m0+r)*K + kk*32 + c], &aL[buf][chunk*512]);
      gll16(&W[(size_t)(n0+r)*K + kk*32 + c], &bL[buf][chunk*512]);
    }
  };

  stage(0,0);
  __syncthreads();
  for (int kk=0; kk<nk; ++kk){
    if (kk+1<nk) stage((kk+1)&1, kk+1);
    const u16* ab = aL[kk&1];
    const u16* bb = bL[kk&1];
    bf16x8 af[4], bv[4];
#pragma unroll
    for (int m=0;m<4;++m){
      const int ra = wm*64+m*16+lr;
      af[m] = ldsr8(&ab[(ra*64 + ((lg*16) ^ (((ra>>1)&3)<<4)))>>1]);
    }
#pragma unroll
    for (int n=0;n<4;++n){
      const int rb = wn*64+n*16+lr;
      bv[n] = ldsr8(&bb[(rb*64 + ((lg*16) ^ (((rb>>1)&3)<<4)))>>1]);
    }
#pragma unroll
    for (int m=0;m<4;++m)
#pragma unroll
      for (int n=0;n<4;++n)
        acc[m][n] = mfma16(af[m], bv[n], acc[m][n]);
    __syncthreads();
  }
#pragma unroll
  for (int m=0;m<4;++m)
#pragma unroll
    for (int n=0;n<4;++n)
#pragma unroll
      for (int r=0;r<4;++r){
        const int row = m0 + wm*64 + m*16 + lg*4 + r;
        const int col = n0 + wn*64 + n*16 + lr;
        float v = acc[m][n][r] + bf2f(bias[col]);
        if constexpr (ADD_RES){
          size_t ri = (size_t)row*256 + col;
          if constexpr (RES_PAD) ri = ((size_t)row + (row>>11)*8 + 4)*256 + col;
          if constexpr (RES_F32) v += ((const float*)res)[ri];
          else                   v += bf2f(((const u16*)res)[ri]);
        }
        if constexpr (OUT_F32) ((float*)out)[(size_t)row*256 + col] = v;
        else                   ((u16*)out)[(size_t)row*256 + col] = f2bf(v);
      }
}

// ------- fused QKV GEMM: W = [wq;wk;wv] (768 x 256); out array picked by col>>8 -------
__global__ __launch_bounds__(256)
void gemm_qkv(const u16* __restrict__ A, const u16* __restrict__ W,
              const u16* __restrict__ bias, u16* __restrict__ qbase,
              const u16* __restrict__ cmask)
{
  __shared__ __align__(16) u16 aL[2][4096];
  __shared__ __align__(16) u16 bL[2][4096];
  const int tid = threadIdx.x, lane = tid&63, w = tid>>6;
  const int wm = w>>1, wn = w&1, lr = lane&15, lg = lane>>4;
  int mi, ni; xcd_remap(mi, ni);
  const int m0 = mi*128, n0 = ni*128;
  if (cmask[m0] != 0) return;

  f32x4 acc[4][4];
#pragma unroll
  for (int i=0;i<4;++i)
#pragma unroll
    for (int j=0;j<4;++j) acc[i][j] = f32x4{0.f,0.f,0.f,0.f};

  auto stage = [&](int buf, int kk){
#pragma unroll
    for (int i=0;i<2;++i){
      const int chunk = w*2+i;
      const int boff  = chunk*1024 + lane*16;
      const int r = boff>>6;
      const int cb = (boff&63) ^ (((r>>1)&3)<<4);
      const int c = cb>>1;
      gll16(&A[(size_t)(m0+r)*256 + kk*32 + c], &aL[buf][chunk*512]);
      gll16(&W[(size_t)(n0+r)*256 + kk*32 + c], &bL[buf][chunk*512]);
    }
  };

  stage(0,0);
  __syncthreads();
  for (int kk=0; kk<8; ++kk){
    if (kk+1<8) stage((kk+1)&1, kk+1);
    const u16* ab = aL[kk&1];
    const u16* bb = bL[kk&1];
    bf16x8 af[4], bv[4];
#pragma unroll
    for (int m=0;m<4;++m){
      const int ra = wm*64+m*16+lr;
      af[m] = ldsr8(&ab[(ra*64 + ((lg*16) ^ (((ra>>1)&3)<<4)))>>1]);
    }
#pragma unroll
    for (int n=0;n<4;++n){
      const int rb = wn*64+n*16+lr;
      bv[n] = ldsr8(&bb[(rb*64 + ((lg*16) ^ (((rb>>1)&3)<<4)))>>1]);
    }
#pragma unroll
    for (int m=0;m<4;++m)
#pragma unroll
      for (int n=0;n<4;++n)
        acc[m][n] = mfma16(af[m], bv[n], acc[m][n]);
    __syncthreads();
  }
#pragma unroll
  for (int m=0;m<4;++m)
#pragma unroll
    for (int n=0;n<4;++n)
#pragma unroll
      for (int r=0;r<4;++r){
        const int row = m0 + wm*64 + m*16 + lg*4 + r;
        const int col = n0 + wn*64 + n*16 + lr;
        const int which = col>>8, ch = col&255;
        float v = acc[m][n][r] + bf2f(bias[col]);
        qbase[(size_t)which*4194304 + (size_t)row*256 + ch] = f2bf(v);
      }
}

// ------- conv1 as m97-style GEMM over padded input: K = 2304 (tap-major) -------
// __launch_bounds__(256,4): force <=64 VGPR (+64 AGPR = 128) -> 4 waves/SIMD, 4 blocks/CU
__global__ __launch_bounds__(256, 4)
void conv1_gemm(const u16* __restrict__ Ap,   // [8][2056][256] zero-haloed
                const u16* __restrict__ W1r,  // [1024][2304], k = tap*256+i
                const u16* __restrict__ b1, u16* __restrict__ Hout,
                const u16* __restrict__ cmask, int nbase)
{
  __shared__ __align__(16) u16 aL[2][4096];
  __shared__ __align__(16) u16 bL[2][4096];
  const int tid = threadIdx.x, lane = tid&63, w = tid>>6;
  const int wm = w>>1, wn = w&1, lr = lane&15, lg = lane>>4;
  int mi, ni; xcd_remap(mi, ni);
  const int m0 = mi*128, n0 = ni*128 + nbase;
  if (cmask[m0] != 0) return;   // masked token tile -> h rows are dont-care
  const int b = m0>>11, s0 = m0&2047;
  const size_t abase = ((size_t)b*2056 + s0)*256;

  f32x4 acc[4][4];
#pragma unroll
  for (int i=0;i<4;++i)
#pragma unroll
    for (int j=0;j<4;++j) acc[i][j] = f32x4{0.f,0.f,0.f,0.f};

  auto stage = [&](int buf, int kk){
    const int tap = kk>>3, ch0 = (kk&7)*32;
#pragma unroll
    for (int i=0;i<2;++i){
      const int chunk = w*2+i;
      const int boff  = chunk*1024 + lane*16;
      const int r = boff>>6;
      const int cb = (boff&63) ^ (((r>>1)&3)<<4);
      const int c = cb>>1;
      gll16(&Ap[abase + (size_t)(tap + r)*256 + ch0 + c], &aL[buf][chunk*512]);
      gll16(&W1r[(size_t)(n0+r)*2304 + kk*32 + c], &bL[buf][chunk*512]);
    }
  };

  stage(0,0);
  __syncthreads();
  for (int kk=0; kk<72; ++kk){
    if (kk+1<72) stage((kk+1)&1, kk+1);
    const u16* ab = aL[kk&1];
    const u16* bb = bL[kk&1];
    bf16x8 af[4], bv[4];
#pragma unroll
    for (int m=0;m<4;++m){
      const int ra = wm*64+m*16+lr;
      af[m] = ldsr8(&ab[(ra*64 + ((lg*16) ^ (((ra>>1)&3)<<4)))>>1]);
    }
#pragma unroll
    for (int n=0;n<4;++n){
      const int rb = wn*64+n*16+lr;
      bv[n] = ldsr8(&bb[(rb*64 + ((lg*16) ^ (((rb>>1)&3)<<4)))>>1]);
    }
#pragma unroll
    for (int m=0;m<4;++m)
#pragma unroll
      for (int n=0;n<4;++n)
        acc[m][n] = mfma16(af[m], bv[n], acc[m][n]);
    __syncthreads();
  }
#pragma unroll
  for (int m=0;m<4;++m)
#pragma unroll
    for (int n=0;n<4;++n)
#pragma unroll
      for (int r=0;r<4;++r){
        const int row = m0 + wm*64 + m*16 + lg*4 + r;
        const int col = n0 + wn*64 + n*16 + lr;
        float v = acc[m][n][r] + bf2f(b1[col]);
        v = v>0.f ? v : 0.f;
        Hout[(size_t)row*1024 + col] = f2bf(v);
      }
}

// ------- V [16384][256] -> VT [b][h][128][2048] -------
__global__ __launch_bounds__(256)
void vtrans(const u16* __restrict__ V, u16* __restrict__ VT)
{
  __shared__ u16 t[64][72];
  const int tid = threadIdx.x;
  const int s0 = blockIdx.x*64;
  const int d0 = blockIdx.y*64;
#pragma unroll
  for (int i=0;i<2;++i){
    const int chunk = tid + i*256;
    const int sr = chunk>>3, c8 = (chunk&7)*8;
    u32x4 raw = *(const u32x4*)&V[(size_t)(s0+sr)*256 + d0 + c8];
#pragma unroll
    for (int j=0;j<4;++j){
      t[sr][c8+2*j]   = (u16)(raw[j]&0xffffu);
      t[sr][c8+2*j+1] = (u16)(raw[j]>>16);
    }
  }
  __syncthreads();
  const int b = s0>>11;
#pragma unroll
  for (int i=0;i<2;++i){
    const int chunk = tid + i*256;
    const int dr = chunk>>3, s8 = (chunk&7)*8;
    const int dg = d0 + dr;
    const int hh = dg>>7, dh = dg&127;
    u32x4 o;
#pragma unroll
    for (int j=0;j<4;++j)
      o[j] = (u32)t[s8+2*j][dr] | ((u32)t[s8+2*j+1][dr]<<16);
    *(u32x4*)&VT[((size_t)((b*2+hh)*128 + dh))*2048 + (s0&2047) + s8] = o;
  }
}

// ------- flash attention: KVBLK=64, double-buffered gll16 staging, 1 barrier/tile -------
__global__ __launch_bounds__(256)
void attn_fwd(const u16* __restrict__ Q, const u16* __restrict__ Kb,
              const u16* __restrict__ VT, const u16* __restrict__ cmask,
              u16* __restrict__ ctx)
{
  __shared__ __align__(16) u16 kls[2][64*128];   // [kv][d] 256B rows, sw (r&7)<<4
  __shared__ __align__(16) u16 vtls[2][128*64];  // [d][kv] 128B rows, sw (r&7)<<4
  __shared__ __align__(16) u16 pls[4][16*64];    // per-wave P, 128B rows
  const int tid = threadIdx.x, lane = tid&63, w = tid>>6;
  const int qt = blockIdx.x, b = blockIdx.y, hh = blockIdx.z;
  const int q0 = qt*64;
  if (cmask[b*2048 + q0] != 0) return;   // whole q-tile masked -> ctx dont-care
  const int lr = lane&15, lg = lane>>4;
  u16* pw = pls[w];

  bf16x8 qf[4];
#pragma unroll
  for (int d=0;d<4;++d)
    qf[d] = *(const bf16x8*)&Q[((size_t)(b*2048+q0+w*16+lr))*256 + hh*128 + d*32 + lg*8];

  f32x4 oacc[8];
  float mrun[4], lrun[4];
#pragma unroll
  for (int n=0;n<8;++n) oacc[n] = f32x4{0.f,0.f,0.f,0.f};
#pragma unroll
  for (int r=0;r<4;++r){ mrun[r] = -1e30f; lrun[r] = 0.f; }

  const size_t kbase = (size_t)(b*2048)*256 + hh*128;
  const size_t vbase = (size_t)((b*2+hh)*128)*2048;

  auto stage = [&](int buf, int kt){
    const int kv0 = kt*64;
#pragma unroll
    for (int i=0;i<4;++i){                       // K tile: 16 KB, 64 rows x 256B
      const int chunk = w*4+i;
      const int boff = chunk*1024 + lane*16;
      const int r = boff>>8;
      const int cb = (boff&255) ^ ((r&7)<<4);
      gll16(&Kb[kbase + (size_t)(kv0+r)*256 + (cb>>1)], &kls[buf][chunk*512]);
    }
#pragma unroll
    for (int i=0;i<4;++i){                       // VT tile: 16 KB, 128 rows x 128B
      const int chunk = w*4+i;
      const int boff = chunk*1024 + lane*16;
      const int r = boff>>7;
      const int cb = (boff&127) ^ ((r&7)<<4);
      gll16(&VT[vbase + (size_t)r*2048 + kv0 + (cb>>1)], &vtls[buf][chunk*512]);
    }
  };

  stage(0, 0);
  __syncthreads();

  for (int kt=0; kt<32; ++kt){
    const int kv0 = kt*64;
    if (cmask[b*2048 + kv0] != 0) break;
    const int buf = kt&1;
    if (kt+1 < 32) stage(buf^1, kt+1);           // prefetch overlaps this tile's compute
    // ---- QK^T ----
    f32x4 sacc[4];
#pragma unroll
    for (int n=0;n<4;++n) sacc[n] = f32x4{0.f,0.f,0.f,0.f};
#pragma unroll
    for (int dk=0;dk<4;++dk){
      bf16x8 bk[4];
#pragma unroll
      for (int n=0;n<4;++n){
        const int rb = n*16+lr;
        bk[n] = ldsr8(&kls[buf][(rb*256 + ((dk*64+lg*16) ^ ((rb&7)<<4)))>>1]);
      }
#pragma unroll
      for (int n=0;n<4;++n)
        sacc[n] = mfma16(qf[dk], bk[n], sacc[n]);
    }
    // ---- scale + key mask ----
    float madd[4];
#pragma unroll
    for (int n=0;n<4;++n)
      madd[n] = cmask[b*2048 + kv0 + n*16 + lr] ? -1e30f : 0.f;
#pragma unroll
    for (int n=0;n<4;++n)
#pragma unroll
      for (int r=0;r<4;++r)
        sacc[n][r] = sacc[n][r]*0.0625f + madd[n];
    // ---- online softmax ----
#pragma unroll
    for (int r=0;r<4;++r){
      float rm = sacc[0][r];
#pragma unroll
      for (int n=1;n<4;++n) rm = fmaxf(rm, sacc[n][r]);
#pragma unroll
      for (int x=1;x<16;x<<=1) rm = fmaxf(rm, __shfl_xor(rm, x));
      const float mnew = fmaxf(mrun[r], rm);
      const float alpha = __expf(mrun[r] - mnew);
      float rsum = 0.f;
#pragma unroll
      for (int n=0;n<4;++n){
        float p = __expf(sacc[n][r] - mnew);
        sacc[n][r] = p;
        rsum += p;
      }
#pragma unroll
      for (int x=1;x<16;x<<=1) rsum += __shfl_xor(rsum, x);
      lrun[r] = alpha*lrun[r] + rsum;
      mrun[r] = mnew;
#pragma unroll
      for (int n=0;n<8;++n) oacc[n][r] *= alpha;
    }
    // ---- P -> per-wave LDS (same-wave only, no barrier) ----
#pragma unroll
    for (int n=0;n<4;++n)
#pragma unroll
      for (int r=0;r<4;++r){
        const int row = lg*4 + r;
        pw[(row*128 + (((n*16+lr)*2) ^ ((row&7)<<4)))>>1] = f2bf(sacc[n][r]);
      }
    // ---- PV ----
#pragma unroll
    for (int ks=0;ks<2;++ks){
      bf16x8 pa = ldsr8(&pw[(lr*128 + ((ks*64+lg*16) ^ ((lr&7)<<4)))>>1]);
#pragma unroll
      for (int n=0;n<8;++n){
        const int rv = n*16+lr;
        bf16x8 bvv = ldsr8(&vtls[buf][(rv*128 + ((ks*64+lg*16) ^ ((rv&7)<<4)))>>1]);
        oacc[n] = mfma16(pa, bvv, oacc[n]);
      }
    }
    __syncthreads();   // all waves done with buf -> safe for next prefetch overwrite
  }
#pragma unroll
  for (int r=0;r<4;++r){
    const float inv = lrun[r] > 0.f ? 1.f/lrun[r] : 0.f;
    const int row = q0 + w*16 + lg*4 + r;
#pragma unroll
    for (int n=0;n<8;++n){
      const int col = hh*128 + n*16 + lr;
      ctx[((size_t)(b*2048+row))*256 + col] = f2bf(oacc[n][r]*inv);
    }
  }
}

// ------- LayerNorm + mask-zero (bf16 in -> padded bf16 out) -------
__global__ __launch_bounds__(256)
void ln_mask_b(const u16* __restrict__ X, const u16* __restrict__ g,
               const u16* __restrict__ bta, const u16* __restrict__ cmask,
               u16* __restrict__ outp)
{
  const int w = threadIdx.x>>6, lane = threadIdx.x&63;
  const int row = blockIdx.x*4 + w;
  const u16* xr = X + (size_t)row*256;
  u32x2 rawv = *(const u32x2*)&xr[lane*4];
  float xv[4];
  xv[0]=bf2f((u16)(rawv[0]&0xffffu)); xv[1]=bf2f((u16)(rawv[0]>>16));
  xv[2]=bf2f((u16)(rawv[1]&0xffffu)); xv[3]=bf2f((u16)(rawv[1]>>16));
  float s = xv[0]+xv[1]+xv[2]+xv[3];
#pragma unroll
  for (int x=1;x<64;x<<=1) s += __shfl_xor(s, x);
  const float mu = s * (1.f/256.f);
  float d[4];
#pragma unroll
  for (int j=0;j<4;++j) d[j]=xv[j]-mu;
  float sq = d[0]*d[0]+d[1]*d[1]+d[2]*d[2]+d[3]*d[3];
#pragma unroll
  for (int x=1;x<64;x<<=1) sq += __shfl_xor(sq, x);
  const float rs = rsqrtf(sq*(1.f/256.f) + 1e-5f);
  const int msk = cmask[row];
  u16 o4[4];
#pragma unroll
  for (int j=0;j<4;++j){
    const int c = lane*4 + j;
    float y = d[j]*rs*bf2f(g[c]) + bf2f(bta[c]);
    o4[j] = msk ? (u16)0 : f2bf(y);
  }
  u32x2 ov;
  ov[0] = (u32)o4[0] | ((u32)o4[1]<<16);
  ov[1] = (u32)o4[2] | ((u32)o4[3]<<16);
  const size_t prow = (size_t)row + (row>>11)*8 + 4;
  *(u32x2*)&outp[prow*256 + lane*4] = ov;
}

// ------- final LayerNorm + mask-zero (bf16 in -> f32 out) -------
__global__ __launch_bounds__(256)
void ln_out(const u16* __restrict__ X, const u16* __restrict__ g,
            const u16* __restrict__ bta, const u16* __restrict__ cmask,
            float* __restrict__ out)
{
  const int w = threadIdx.x>>6, lane = threadIdx.x&63;
  const int row = blockIdx.x*4 + w;
  const u16* xr = X + (size_t)row*256;
  u32x2 rawv = *(const u32x2*)&xr[lane*4];
  float xv[4];
  xv[0]=bf2f((u16)(rawv[0]&0xffffu)); xv[1]=bf2f((u16)(rawv[0]>>16));
  xv[2]=bf2f((u16)(rawv[1]&0xffffu)); xv[3]=bf2f((u16)(rawv[1]>>16));
  float s = xv[0]+xv[1]+xv[2]+xv[3];
#pragma unroll
  for (int x=1;x<64;x<<=1) s += __shfl_xor(s, x);
  const float mu = s * (1.f/256.f);
  float d[4];
#pragma unroll
  for (int j=0;j<4;++j) d[j]=xv[j]-mu;
  float sq = d[0]*d[0]+d[1]*d[1]+d[2]*d[2]+d[3]*d[3];
#pragma unroll
  for (int x=1;x<64;x<<=1) sq += __shfl_xor(sq, x);
  const float rs = rsqrtf(sq*(1.f/256.f) + 1e-5f);
  const int msk = cmask[row];
  f32x4 ov;
#pragma unroll
  for (int j=0;j<4;++j){
    const int c = lane*4 + j;
    float y = d[j]*rs*bf2f(g[c]) + bf2f(bta[c]);
    ov[j] = msk ? 0.f : y;
  }
  *(f32x4*)&out[(size_t)row*256 + lane*4] = ov;
}

extern "C" void kernel_launch(void* const* d_in, const int* in_sizes, int n_in,
                              void* d_out, int out_size, void* d_ws, size_t ws_size,
                              hipStream_t stream)
{
  (void)in_sizes; (void)n_in; (void)out_size; (void)ws_size;
  const float* batch=(const float*)d_in[0];  const void* mraw = d_in[1];
  const float* wq=(const float*)d_in[2];  const float* bq=(const float*)d_in[3];
  const float* wk=(const float*)d_in[4];  const float* bk=(const float*)d_in[5];
  const float* wv=(const float*)d_in[6];  const float* bvv=(const float*)d_in[7];
  const float* wo=(const float*)d_in[8];  const float* bo=(const float*)d_in[9];
  const float* g1=(const float*)d_in[10]; const float* be1=(const float*)d_in[11];
  const float* w1=(const float*)d_in[12]; const float* b1=(const float*)d_in[13];
  const float* w2=(const float*)d_in[14]; const float* b2=(const float*)d_in[15];
  const float* g2=(const float*)d_in[16]; const float* be2=(const float*)d_in[17];

  char* ws = (char*)d_ws;
  const size_t M = 1024u*1024u;
  u16*   batchc = (u16*)(ws);          // 0..8M   (dead after QKV gemm)
  u16*   VT     = (u16*)(ws);          // 0..8M   (over batchc; live vtrans..attn)
  u16*   q      = (u16*)(ws + 8*M);    // 8..16M  (dead after attn)
  u16*   tmpb   = (u16*)(ws + 8*M);    // 8..16M  (over q; outproj out, live ..ln_mask_b)
  u16*   kbuf   = (u16*)(ws + 16*M);   // 16..24M (dead after attn)
  u16*   v      = (u16*)(ws + 24*M);   // 24..32M (dead after vtrans)
  u16*   ctx    = (u16*)(ws + 32*M);   // 32..40M (dead after outproj)
  u16*   h      = (u16*)(ws);          // 0..32M  (over VT,tmpb,kbuf,v; live conv1..conv2)
  u16*   x2     = (u16*)(ws + 32*M);   // 32..40M (over ctx; conv2 out, live ..ln_out)
  u16*   seq1p  = (u16*)(ws + 40*M);   // 40..48.1M padded [8][2056][256]
  u16*   wqc    = (u16*)(ws + 49*M);   // wq|wk|wv (768x256), then wo, then w2
  u16*   woc    = wqc + 196608;
  u16*   w2c    = wqc + 262144;
  u16*   w1r    = (u16*)(ws + 50*M);   // 2359296 u16 (4.5 MB)
  u16*   params = w1r + 2359296;
  u16*   cmask  = params + 4096;

  dim3 blk(256,1,1);

  prep_big<<<dim3(13824,1,1), blk, 0, stream>>>(batch, wq, wk, wv, wo, w2, w1,
                                                batchc, wqc, w1r);
  prep_small<<<dim3(66,1,1), blk, 0, stream>>>(bq,bk,bvv,bo,g1,be1,g2,be2,b1,b2,
                                               params, mraw, cmask, seq1p);

  gemm_qkv<<<dim3(128,6,1), blk, 0, stream>>>(batchc, wqc, params, q, cmask);

  vtrans<<<dim3(256,4,1), blk, 0, stream>>>(v, VT);

  attn_fwd<<<dim3(32,8,2), blk, 0, stream>>>(q, kbuf, VT, cmask, ctx);

  gemm_nt<false,true,true,false,true><<<dim3(128,2,1), blk, 0, stream>>>(ctx, woc, params+768, (const void*)batch, (void*)tmpb, 256, cmask);
  ln_mask_b<<<dim3(4096,1,1), blk, 0, stream>>>(tmpb, params+1024, params+1280, cmask, seq1p);

  conv1_gemm<<<dim3(128,4,1), blk, 0, stream>>>(seq1p, w1r, params+2048, h, cmask, 0);
  conv1_gemm<<<dim3(128,4,1), blk, 0, stream>>>(seq1p, w1r, params+2048, h, cmask, 512);

  gemm_nt<false,true,false,true,true><<<dim3(128,2,1), blk, 0, stream>>>(h, w2c, params+3072, (const void*)seq1p, (void*)x2, 1024, cmask);
  ln_out<<<dim3(4096,1,1), blk, 0, stream>>>(x2, params+1536, params+1792, cmask, (float*)d_out);
}

// Round 15
// 319.788 us; speedup vs baseline: 1.4904x; 1.0269x over previous
//
#include <hip/hip_runtime.h>

typedef unsigned char  u8;
typedef unsigned short u16;
typedef unsigned int   u32;
typedef __attribute__((ext_vector_type(4))) float f32x4;
typedef __attribute__((ext_vector_type(8))) __bf16 bf16x8;
typedef __attribute__((ext_vector_type(4))) u32  u32x4;
typedef __attribute__((ext_vector_type(2))) u32  u32x2;

__device__ __forceinline__ float bf2f(u16 h){ u32 u = ((u32)h)<<16; return __builtin_bit_cast(float, u); }
__device__ __forceinline__ u16  f2bf(float f){
  u32 u = __builtin_bit_cast(u32, f);
  u32 r = u + 0x7FFFu + ((u>>16)&1u);
  return (u16)(r>>16);
}

typedef const __attribute__((address_space(1))) u32 gas_u32;
typedef __attribute__((address_space(3))) u32 las_u32;
__device__ __forceinline__ void gll16(const void* g, void* l){
  __builtin_amdgcn_global_load_lds((gas_u32*)g, (las_u32*)l, 16, 0, 0);
}

__device__ __forceinline__ f32x4 mfma16(bf16x8 a, bf16x8 b, f32x4 c){
  return __builtin_amdgcn_mfma_f32_16x16x32_bf16(a, b, c, 0, 0, 0);
}

__device__ __forceinline__ bf16x8 ldsr8(const u16* p){
  u32x4 v = *(const u32x4*)p;
  return __builtin_bit_cast(bf16x8, v);
}

// XCD co-locate remap: blocks sharing an A-panel (same m-tile) land on one XCD.
__device__ __forceinline__ void xcd_remap(int &m_idx, int &n_idx){
  const int Mt = gridDim.x;
  const int fid = blockIdx.x + Mt*blockIdx.y;
  const int xcd = fid & 7, k = fid >> 3;
  const int mpx = Mt >> 3;
  m_idx = xcd*mpx + (k % mpx);
  n_idx = k / mpx;
}

// ------- prologue A: batch cvt + weight cvt + conv1 weight repack -------
__global__ __launch_bounds__(256)
void prep_big(const float* __restrict__ batch,
              const float* __restrict__ wq, const float* __restrict__ wk,
              const float* __restrict__ wv, const float* __restrict__ wo,
              const float* __restrict__ w2, const float* __restrict__ w1,
              u16* __restrict__ batchc, u16* __restrict__ wqc, u16* __restrict__ w1r)
{
  const int bid = blockIdx.x, tid = threadIdx.x;
  if (bid < 4096){
    const int i = bid*1024 + tid*4;
    f32x4 v = *(const f32x4*)&batch[i];
    u32x2 o;
    o[0] = (u32)f2bf(v[0]) | ((u32)f2bf(v[1])<<16);
    o[1] = (u32)f2bf(v[2]) | ((u32)f2bf(v[3])<<16);
    *(u32x2*)&batchc[i] = o;
  } else if (bid < 4608){
    const int i = (bid-4096)*1024 + tid*4;
    const float* s; int off;
    if      (i < 65536)  { s = wq; off = i; }
    else if (i < 131072) { s = wk; off = i - 65536; }
    else if (i < 196608) { s = wv; off = i - 131072; }
    else if (i < 262144) { s = wo; off = i - 196608; }
    else                 { s = w2; off = i - 262144; }
    f32x4 v = *(const f32x4*)&s[off];
    u32x2 o;
    o[0] = (u32)f2bf(v[0]) | ((u32)f2bf(v[1])<<16);
    o[1] = (u32)f2bf(v[2]) | ((u32)f2bf(v[3])<<16);
    *(u32x2*)&wqc[i] = o;
  } else {
    const int idx = (bid-4608)*256 + tid;
    const int c = idx / 2304;
    const int t = idx - c*2304;
    const int i = t / 9;
    const int kk = t - i*9;
    w1r[c*2304 + kk*256 + i] = f2bf(w1[idx]);
  }
}

// ------- prologue B: params + mask canon + lengths + seq1p halo zero -------
__global__ __launch_bounds__(256)
void prep_small(const float* p0,const float* p1,const float* p2,const float* p3,
                const float* p4,const float* p5,const float* p6,const float* p7,
                const float* p8,const float* p9,
                u16* __restrict__ params, const void* __restrict__ mraw,
                u16* __restrict__ cmask, u32* __restrict__ lengths,
                u16* __restrict__ seq1p)
{
  const int bid = blockIdx.x, tid = threadIdx.x;
  if (bid == 0){
    const float* ps[10] = {p0,p1,p2,p3,p4,p5,p6,p7,p8,p9};
    const int  off[10] = {0,256,512,768,1024,1280,1536,1792,2048,3072};
    const int  len[10] = {256,256,256,256,256,256,256,256,1024,256};
    for (int a=0;a<10;++a)
      for (int i=tid;i<len[a];i+=256)
        params[off[a]+i] = f2bf(ps[a][i]);
  } else if (bid == 1){
    const u8*  pb8  = (const u8*)mraw;
    const u16* pb16 = (const u16*)mraw;
    const u32* pb32 = (const u32*)mraw;
    __shared__ int bad8, bad16, nz8, nz16;
    __shared__ int slen[8];
    if (tid==0){ bad8=0; bad16=0; nz8=0; nz16=0; }
    if (tid<8) slen[tid] = 2048;
    __syncthreads();
    for (int i=tid;i<16384;i+=256){
      u8 v = pb8[i]; int row = i & 2047;
      if (v>1) atomicOr(&bad8,1);
      if (v){ atomicOr(&nz8,1); if (row<1024) atomicOr(&bad8,1); }
      if (row>0 && pb8[i-1]==1 && v==0) atomicOr(&bad8,1);
    }
    for (int i=tid;i<8192;i+=256){
      u16 v = pb16[i]; int row = i & 2047;
      if (!(v==0 || v==0x3F80)) atomicOr(&bad16,1);
      if (v){ atomicOr(&nz16,1); if (row<1024) atomicOr(&bad16,1); }
      if (row>0 && pb16[i-1]==0x3F80 && v==0) atomicOr(&bad16,1);
    }
    __syncthreads();
    const int mode = (!bad8 && nz8) ? 1 : ((!bad16 && nz16) ? 2 : 0);
    for (int i=tid;i<16384;i+=256){
      u16 m;
      if (mode==1)      m = pb8[i]  ? 1 : 0;
      else if (mode==2) m = pb16[i] ? 1 : 0;
      else              m = pb32[i] ? 1 : 0;
      cmask[i] = m;
      if (m) atomicMin(&slen[i>>11], i&2047);
    }
    __syncthreads();
    if (tid<8) lengths[tid] = (u32)slen[tid];
  } else {
    const int idx = (bid-2)*256 + tid;     // 16384 halo elems
    const int b = idx>>11, t = idx&2047;
    const int r = t>>8, c = t&255;
    const int row = (r<4) ? r : (2052 + r - 4);
    seq1p[((size_t)b*2056 + row)*256 + c] = 0;
  }
}

// ------- GEMM: C = A·W^T + bias [+res]; optional padded residual; optional masked-tile skip -------
template<bool OUT_F32, bool ADD_RES, bool RES_F32, bool RES_PAD, bool SKIPM>
__global__ __launch_bounds__(256)
void gemm_nt(const u16* __restrict__ A, const u16* __restrict__ W,
             const u16* __restrict__ bias, const void* __restrict__ res,
             void* __restrict__ out, int K, const u16* __restrict__ cmask)
{
  __shared__ __align__(16) u16 aL[2][4096];
  __shared__ __align__(16) u16 bL[2][4096];
  const int tid = threadIdx.x, lane = tid&63, w = tid>>6;
  const int wm = w>>1, wn = w&1, lr = lane&15, lg = lane>>4;
  int mi, ni; xcd_remap(mi, ni);
  const int m0 = mi*128, n0 = ni*128;
  if constexpr (SKIPM){
    if (cmask[m0] != 0) return;
  }
  const int nk = K>>5;

  f32x4 acc[4][4];
#pragma unroll
  for (int i=0;i<4;++i)
#pragma unroll
    for (int j=0;j<4;++j) acc[i][j] = f32x4{0.f,0.f,0.f,0.f};

  auto stage = [&](int buf, int kk){
#pragma unroll
    for (int i=0;i<2;++i){
      const int chunk = w*2+i;
      const int boff  = chunk*1024 + lane*16;
      const int r = boff>>6;
      const int cb = (boff&63) ^ (((r>>1)&3)<<4);
      const int c = cb>>1;
      gll16(&A[(size_t)(m0+r)*K + kk*32 + c], &aL[buf][chunk*512]);
      gll16(&W[(size_t)(n0+r)*K + kk*32 + c], &bL[buf][chunk*512]);
    }
  };

  stage(0,0);
  __syncthreads();
  for (int kk=0; kk<nk; ++kk){
    if (kk+1<nk) stage((kk+1)&1, kk+1);
    const u16* ab = aL[kk&1];
    const u16* bb = bL[kk&1];
    bf16x8 af[4], bv[4];
#pragma unroll
    for (int m=0;m<4;++m){
      const int ra = wm*64+m*16+lr;
      af[m] = ldsr8(&ab[(ra*64 + ((lg*16) ^ (((ra>>1)&3)<<4)))>>1]);
    }
#pragma unroll
    for (int n=0;n<4;++n){
      const int rb = wn*64+n*16+lr;
      bv[n] = ldsr8(&bb[(rb*64 + ((lg*16) ^ (((rb>>1)&3)<<4)))>>1]);
    }
#pragma unroll
    for (int m=0;m<4;++m)
#pragma unroll
      for (int n=0;n<4;++n)
        acc[m][n] = mfma16(af[m], bv[n], acc[m][n]);
    __syncthreads();
  }
#pragma unroll
  for (int m=0;m<4;++m)
#pragma unroll
    for (int n=0;n<4;++n)
#pragma unroll
      for (int r=0;r<4;++r){
        const int row = m0 + wm*64 + m*16 + lg*4 + r;
        const int col = n0 + wn*64 + n*16 + lr;
        float v = acc[m][n][r] + bf2f(bias[col]);
        if constexpr (ADD_RES){
          size_t ri = (size_t)row*256 + col;
          if constexpr (RES_PAD) ri = ((size_t)row + (row>>11)*8 + 4)*256 + col;
          if constexpr (RES_F32) v += ((const float*)res)[ri];
          else                   v += bf2f(((const u16*)res)[ri]);
        }
        if constexpr (OUT_F32) ((float*)out)[(size_t)row*256 + col] = v;
        else                   ((u16*)out)[(size_t)row*256 + col] = f2bf(v);
      }
}

// ------- fused QKV GEMM: W = [wq;wk;wv] (768 x 256); out array picked by col>>8 -------
__global__ __launch_bounds__(256)
void gemm_qkv(const u16* __restrict__ A, const u16* __restrict__ W,
              const u16* __restrict__ bias, u16* __restrict__ qbase,
              const u16* __restrict__ cmask)
{
  __shared__ __align__(16) u16 aL[2][4096];
  __shared__ __align__(16) u16 bL[2][4096];
  const int tid = threadIdx.x, lane = tid&63, w = tid>>6;
  const int wm = w>>1, wn = w&1, lr = lane&15, lg = lane>>4;
  int mi, ni; xcd_remap(mi, ni);
  const int m0 = mi*128, n0 = ni*128;
  if (cmask[m0] != 0) return;

  f32x4 acc[4][4];
#pragma unroll
  for (int i=0;i<4;++i)
#pragma unroll
    for (int j=0;j<4;++j) acc[i][j] = f32x4{0.f,0.f,0.f,0.f};

  auto stage = [&](int buf, int kk){
#pragma unroll
    for (int i=0;i<2;++i){
      const int chunk = w*2+i;
      const int boff  = chunk*1024 + lane*16;
      const int r = boff>>6;
      const int cb = (boff&63) ^ (((r>>1)&3)<<4);
      const int c = cb>>1;
      gll16(&A[(size_t)(m0+r)*256 + kk*32 + c], &aL[buf][chunk*512]);
      gll16(&W[(size_t)(n0+r)*256 + kk*32 + c], &bL[buf][chunk*512]);
    }
  };

  stage(0,0);
  __syncthreads();
  for (int kk=0; kk<8; ++kk){
    if (kk+1<8) stage((kk+1)&1, kk+1);
    const u16* ab = aL[kk&1];
    const u16* bb = bL[kk&1];
    bf16x8 af[4], bv[4];
#pragma unroll
    for (int m=0;m<4;++m){
      const int ra = wm*64+m*16+lr;
      af[m] = ldsr8(&ab[(ra*64 + ((lg*16) ^ (((ra>>1)&3)<<4)))>>1]);
    }
#pragma unroll
    for (int n=0;n<4;++n){
      const int rb = wn*64+n*16+lr;
      bv[n] = ldsr8(&bb[(rb*64 + ((lg*16) ^ (((rb>>1)&3)<<4)))>>1]);
    }
#pragma unroll
    for (int m=0;m<4;++m)
#pragma unroll
      for (int n=0;n<4;++n)
        acc[m][n] = mfma16(af[m], bv[n], acc[m][n]);
    __syncthreads();
  }
#pragma unroll
  for (int m=0;m<4;++m)
#pragma unroll
    for (int n=0;n<4;++n)
#pragma unroll
      for (int r=0;r<4;++r){
        const int row = m0 + wm*64 + m*16 + lg*4 + r;
        const int col = n0 + wn*64 + n*16 + lr;
        const int which = col>>8, ch = col&255;
        float v = acc[m][n][r] + bf2f(bias[col]);
        qbase[(size_t)which*4194304 + (size_t)row*256 + ch] = f2bf(v);
      }
}

// ------- conv1 as m97-style GEMM over padded input: K = 2304 (tap-major) -------
__global__ __launch_bounds__(256, 4)
void conv1_gemm(const u16* __restrict__ Ap, const u16* __restrict__ W1r,
                const u16* __restrict__ b1, u16* __restrict__ Hout,
                const u16* __restrict__ cmask, int nbase)
{
  __shared__ __align__(16) u16 aL[2][4096];
  __shared__ __align__(16) u16 bL[2][4096];
  const int tid = threadIdx.x, lane = tid&63, w = tid>>6;
  const int wm = w>>1, wn = w&1, lr = lane&15, lg = lane>>4;
  int mi, ni; xcd_remap(mi, ni);
  const int m0 = mi*128, n0 = ni*128 + nbase;
  if (cmask[m0] != 0) return;
  const int b = m0>>11, s0 = m0&2047;
  const size_t abase = ((size_t)b*2056 + s0)*256;

  f32x4 acc[4][4];
#pragma unroll
  for (int i=0;i<4;++i)
#pragma unroll
    for (int j=0;j<4;++j) acc[i][j] = f32x4{0.f,0.f,0.f,0.f};

  auto stage = [&](int buf, int kk){
    const int tap = kk>>3, ch0 = (kk&7)*32;
#pragma unroll
    for (int i=0;i<2;++i){
      const int chunk = w*2+i;
      const int boff  = chunk*1024 + lane*16;
      const int r = boff>>6;
      const int cb = (boff&63) ^ (((r>>1)&3)<<4);
      const int c = cb>>1;
      gll16(&Ap[abase + (size_t)(tap + r)*256 + ch0 + c], &aL[buf][chunk*512]);
      gll16(&W1r[(size_t)(n0+r)*2304 + kk*32 + c], &bL[buf][chunk*512]);
    }
  };

  stage(0,0);
  __syncthreads();
  for (int kk=0; kk<72; ++kk){
    if (kk+1<72) stage((kk+1)&1, kk+1);
    const u16* ab = aL[kk&1];
    const u16* bb = bL[kk&1];
    bf16x8 af[4], bv[4];
#pragma unroll
    for (int m=0;m<4;++m){
      const int ra = wm*64+m*16+lr;
      af[m] = ldsr8(&ab[(ra*64 + ((lg*16) ^ (((ra>>1)&3)<<4)))>>1]);
    }
#pragma unroll
    for (int n=0;n<4;++n){
      const int rb = wn*64+n*16+lr;
      bv[n] = ldsr8(&bb[(rb*64 + ((lg*16) ^ (((rb>>1)&3)<<4)))>>1]);
    }
#pragma unroll
    for (int m=0;m<4;++m)
#pragma unroll
      for (int n=0;n<4;++n)
        acc[m][n] = mfma16(af[m], bv[n], acc[m][n]);
    __syncthreads();
  }
#pragma unroll
  for (int m=0;m<4;++m)
#pragma unroll
    for (int n=0;n<4;++n)
#pragma unroll
      for (int r=0;r<4;++r){
        const int row = m0 + wm*64 + m*16 + lg*4 + r;
        const int col = n0 + wn*64 + n*16 + lr;
        float v = acc[m][n][r] + bf2f(b1[col]);
        v = v>0.f ? v : 0.f;
        Hout[(size_t)row*1024 + col] = f2bf(v);
      }
}

// ------- V [16384][256] -> VT [b][h][128][2048] -------
__global__ __launch_bounds__(256)
void vtrans(const u16* __restrict__ V, u16* __restrict__ VT)
{
  __shared__ u16 t[64][72];
  const int tid = threadIdx.x;
  const int s0 = blockIdx.x*64;
  const int d0 = blockIdx.y*64;
#pragma unroll
  for (int i=0;i<2;++i){
    const int chunk = tid + i*256;
    const int sr = chunk>>3, c8 = (chunk&7)*8;
    u32x4 raw = *(const u32x4*)&V[(size_t)(s0+sr)*256 + d0 + c8];
#pragma unroll
    for (int j=0;j<4;++j){
      t[sr][c8+2*j]   = (u16)(raw[j]&0xffffu);
      t[sr][c8+2*j+1] = (u16)(raw[j]>>16);
    }
  }
  __syncthreads();
  const int b = s0>>11;
#pragma unroll
  for (int i=0;i<2;++i){
    const int chunk = tid + i*256;
    const int dr = chunk>>3, s8 = (chunk&7)*8;
    const int dg = d0 + dr;
    const int hh = dg>>7, dh = dg&127;
    u32x4 o;
#pragma unroll
    for (int j=0;j<4;++j)
      o[j] = (u32)t[s8+2*j][dr] | ((u32)t[s8+2*j+1][dr]<<16);
    *(u32x4*)&VT[((size_t)((b*2+hh)*128 + dh))*2048 + (s0&2047) + s8] = o;
  }
}

// ------- flash attention: KVBLK=64, dbuf gll16 staging, 1 barrier/tile, arithmetic mask -------
// flat grid 512; fid bits: [2:0]=qt[2:0] (XCD spread), [5:3]=b (batch interleave),
// [7:6]=qt[4:3], [8]=hh.
__global__ __launch_bounds__(256)
void attn_fwd(const u16* __restrict__ Q, const u16* __restrict__ Kb,
              const u16* __restrict__ VT, const u32* __restrict__ lengths,
              u16* __restrict__ ctx)
{
  __shared__ __align__(16) u16 kls[2][64*128];
  __shared__ __align__(16) u16 vtls[2][128*64];
  __shared__ __align__(16) u16 pls[4][16*64];
  const int tid = threadIdx.x, lane = tid&63, w = tid>>6;
  const int fid = blockIdx.x;
  const int qt = (fid&7) | (((fid>>6)&3)<<3);
  const int b  = (fid>>3)&7;
  const int hh = fid>>8;
  const int q0 = qt*64;
  const int L  = (int)lengths[b];
  if (q0 >= L) return;
  const int nkt = (L + 63) >> 6;
  const int lr = lane&15, lg = lane>>4;
  u16* pw = pls[w];

  bf16x8 qf[4];
#pragma unroll
  for (int d=0;d<4;++d)
    qf[d] = *(const bf16x8*)&Q[((size_t)(b*2048+q0+w*16+lr))*256 + hh*128 + d*32 + lg*8];

  f32x4 oacc[8];
  float mrun[4], lrun[4];
#pragma unroll
  for (int n=0;n<8;++n) oacc[n] = f32x4{0.f,0.f,0.f,0.f};
#pragma unroll
  for (int r=0;r<4;++r){ mrun[r] = -1e30f; lrun[r] = 0.f; }

  const size_t kbase = (size_t)(b*2048)*256 + hh*128;
  const size_t vbase = (size_t)((b*2+hh)*128)*2048;

  auto stage = [&](int buf, int kt){
    const int kv0 = kt*64;
#pragma unroll
    for (int i=0;i<4;++i){
      const int chunk = w*4+i;
      const int boff = chunk*1024 + lane*16;
      const int r = boff>>8;
      const int cb = (boff&255) ^ ((r&7)<<4);
      gll16(&Kb[kbase + (size_t)(kv0+r)*256 + (cb>>1)], &kls[buf][chunk*512]);
    }
#pragma unroll
    for (int i=0;i<4;++i){
      const int chunk = w*4+i;
      const int boff = chunk*1024 + lane*16;
      const int r = boff>>7;
      const int cb = (boff&127) ^ ((r&7)<<4);
      gll16(&VT[vbase + (size_t)r*2048 + kv0 + (cb>>1)], &vtls[buf][chunk*512]);
    }
  };

  stage(0, 0);
  __syncthreads();

  for (int kt=0; kt<nkt; ++kt){
    const int kv0 = kt*64;
    const int buf = kt&1;
    if (kt+1 < nkt) stage(buf^1, kt+1);
    // ---- QK^T ----
    f32x4 sacc[4];
#pragma unroll
    for (int n=0;n<4;++n) sacc[n] = f32x4{0.f,0.f,0.f,0.f};
    __builtin_amdgcn_s_setprio(1);
#pragma unroll
    for (int dk=0;dk<4;++dk){
      bf16x8 bk[4];
#pragma unroll
      for (int n=0;n<4;++n){
        const int rb = n*16+lr;
        bk[n] = ldsr8(&kls[buf][(rb*256 + ((dk*64+lg*16) ^ ((rb&7)<<4)))>>1]);
      }
#pragma unroll
      for (int n=0;n<4;++n)
        sacc[n] = mfma16(qf[dk], bk[n], sacc[n]);
    }
    __builtin_amdgcn_s_setprio(0);
    // ---- scale + arithmetic key mask ----
#pragma unroll
    for (int n=0;n<4;++n){
      const float madd = (kv0 + n*16 + lr < L) ? 0.f : -1e30f;
#pragma unroll
      for (int r=0;r<4;++r)
        sacc[n][r] = sacc[n][r]*0.0625f + madd;
    }
    // ---- online softmax ----
#pragma unroll
    for (int r=0;r<4;++r){
      float rm = sacc[0][r];
#pragma unroll
      for (int n=1;n<4;++n) rm = fmaxf(rm, sacc[n][r]);
#pragma unroll
      for (int x=1;x<16;x<<=1) rm = fmaxf(rm, __shfl_xor(rm, x));
      const float mnew = fmaxf(mrun[r], rm);
      const float alpha = __expf(mrun[r] - mnew);
      float rsum = 0.f;
#pragma unroll
      for (int n=0;n<4;++n){
        float p = __expf(sacc[n][r] - mnew);
        sacc[n][r] = p;
        rsum += p;
      }
#pragma unroll
      for (int x=1;x<16;x<<=1) rsum += __shfl_xor(rsum, x);
      lrun[r] = alpha*lrun[r] + rsum;
      mrun[r] = mnew;
#pragma unroll
      for (int n=0;n<8;++n) oacc[n][r] *= alpha;
    }
    // ---- P -> per-wave LDS (same-wave only, no barrier) ----
#pragma unroll
    for (int n=0;n<4;++n)
#pragma unroll
      for (int r=0;r<4;++r){
        const int row = lg*4 + r;
        pw[(row*128 + (((n*16+lr)*2) ^ ((row&7)<<4)))>>1] = f2bf(sacc[n][r]);
      }
    // ---- PV ----
    __builtin_amdgcn_s_setprio(1);
#pragma unroll
    for (int ks=0;ks<2;++ks){
      bf16x8 pa = ldsr8(&pw[(lr*128 + ((ks*64+lg*16) ^ ((lr&7)<<4)))>>1]);
#pragma unroll
      for (int n=0;n<8;++n){
        const int rv = n*16+lr;
        bf16x8 bvv = ldsr8(&vtls[buf][(rv*128 + ((ks*64+lg*16) ^ ((rv&7)<<4)))>>1]);
        oacc[n] = mfma16(pa, bvv, oacc[n]);
      }
    }
    __builtin_amdgcn_s_setprio(0);
    __syncthreads();
  }
#pragma unroll
  for (int r=0;r<4;++r){
    const float inv = lrun[r] > 0.f ? 1.f/lrun[r] : 0.f;
    const int row = q0 + w*16 + lg*4 + r;
#pragma unroll
    for (int n=0;n<8;++n){
      const int col = hh*128 + n*16 + lr;
      ctx[((size_t)(b*2048+row))*256 + col] = f2bf(oacc[n][r]*inv);
    }
  }
}

// ------- LayerNorm + mask-zero (bf16 in -> padded bf16 out) -------
__global__ __launch_bounds__(256)
void ln_mask_b(const u16* __restrict__ X, const u16* __restrict__ g,
               const u16* __restrict__ bta, const u16* __restrict__ cmask,
               u16* __restrict__ outp)
{
  const int w = threadIdx.x>>6, lane = threadIdx.x&63;
  const int row = blockIdx.x*4 + w;
  const u16* xr = X + (size_t)row*256;
  u32x2 rawv = *(const u32x2*)&xr[lane*4];
  float xv[4];
  xv[0]=bf2f((u16)(rawv[0]&0xffffu)); xv[1]=bf2f((u16)(rawv[0]>>16));
  xv[2]=bf2f((u16)(rawv[1]&0xffffu)); xv[3]=bf2f((u16)(rawv[1]>>16));
  float s = xv[0]+xv[1]+xv[2]+xv[3];
#pragma unroll
  for (int x=1;x<64;x<<=1) s += __shfl_xor(s, x);
  const float mu = s * (1.f/256.f);
  float d[4];
#pragma unroll
  for (int j=0;j<4;++j) d[j]=xv[j]-mu;
  float sq = d[0]*d[0]+d[1]*d[1]+d[2]*d[2]+d[3]*d[3];
#pragma unroll
  for (int x=1;x<64;x<<=1) sq += __shfl_xor(sq, x);
  const float rs = rsqrtf(sq*(1.f/256.f) + 1e-5f);
  const int msk = cmask[row];
  u16 o4[4];
#pragma unroll
  for (int j=0;j<4;++j){
    const int c = lane*4 + j;
    float y = d[j]*rs*bf2f(g[c]) + bf2f(bta[c]);
    o4[j] = msk ? (u16)0 : f2bf(y);
  }
  u32x2 ov;
  ov[0] = (u32)o4[0] | ((u32)o4[1]<<16);
  ov[1] = (u32)o4[2] | ((u32)o4[3]<<16);
  const size_t prow = (size_t)row + (row>>11)*8 + 4;
  *(u32x2*)&outp[prow*256 + lane*4] = ov;
}

// ------- final LayerNorm + mask-zero (bf16 in -> f32 out) -------
__global__ __launch_bounds__(256)
void ln_out(const u16* __restrict__ X, const u16* __restrict__ g,
            const u16* __restrict__ bta, const u16* __restrict__ cmask,
            float* __restrict__ out)
{
  const int w = threadIdx.x>>6, lane = threadIdx.x&63;
  const int row = blockIdx.x*4 + w;
  const u16* xr = X + (size_t)row*256;
  u32x2 rawv = *(const u32x2*)&xr[lane*4];
  float xv[4];
  xv[0]=bf2f((u16)(rawv[0]&0xffffu)); xv[1]=bf2f((u16)(rawv[0]>>16));
  xv[2]=bf2f((u16)(rawv[1]&0xffffu)); xv[3]=bf2f((u16)(rawv[1]>>16));
  float s = xv[0]+xv[1]+xv[2]+xv[3];
#pragma unroll
  for (int x=1;x<64;x<<=1) s += __shfl_xor(s, x);
  const float mu = s * (1.f/256.f);
  float d[4];
#pragma unroll
  for (int j=0;j<4;++j) d[j]=xv[j]-mu;
  float sq = d[0]*d[0]+d[1]*d[1]+d[2]*d[2]+d[3]*d[3];
#pragma unroll
  for (int x=1;x<64;x<<=1) sq += __shfl_xor(sq, x);
  const float rs = rsqrtf(sq*(1.f/256.f) + 1e-5f);
  const int msk = cmask[row];
  f32x4 ov;
#pragma unroll
  for (int j=0;j<4;++j){
    const int c = lane*4 + j;
    float y = d[j]*rs*bf2f(g[c]) + bf2f(bta[c]);
    ov[j] = msk ? 0.f : y;
  }
  *(f32x4*)&out[(size_t)row*256 + lane*4] = ov;
}

extern "C" void kernel_launch(void* const* d_in, const int* in_sizes, int n_in,
                              void* d_out, int out_size, void* d_ws, size_t ws_size,
                              hipStream_t stream)
{
  (void)in_sizes; (void)n_in; (void)out_size; (void)ws_size;
  const float* batch=(const float*)d_in[0];  const void* mraw = d_in[1];
  const float* wq=(const float*)d_in[2];  const float* bq=(const float*)d_in[3];
  const float* wk=(const float*)d_in[4];  const float* bk=(const float*)d_in[5];
  const float* wv=(const float*)d_in[6];  const float* bvv=(const float*)d_in[7];
  const float* wo=(const float*)d_in[8];  const float* bo=(const float*)d_in[9];
  const float* g1=(const float*)d_in[10]; const float* be1=(const float*)d_in[11];
  const float* w1=(const float*)d_in[12]; const float* b1=(const float*)d_in[13];
  const float* w2=(const float*)d_in[14]; const float* b2=(const float*)d_in[15];
  const float* g2=(const float*)d_in[16]; const float* be2=(const float*)d_in[17];

  char* ws = (char*)d_ws;
  const size_t M = 1024u*1024u;
  u16*   batchc = (u16*)(ws);          // 0..8M   (dead after QKV gemm)
  u16*   VT     = (u16*)(ws);          // 0..8M   (over batchc; live vtrans..attn)
  u16*   q      = (u16*)(ws + 8*M);    // 8..16M  (dead after attn)
  u16*   tmpb   = (u16*)(ws + 8*M);    // 8..16M  (over q; outproj out, live ..ln_mask_b)
  u16*   kbuf   = (u16*)(ws + 16*M);   // 16..24M (dead after attn)
  u16*   v      = (u16*)(ws + 24*M);   // 24..32M (dead after vtrans)
  u16*   ctx    = (u16*)(ws + 32*M);   // 32..40M (dead after outproj)
  u16*   h      = (u16*)(ws);          // 0..32M  (over VT,tmpb,kbuf,v; live conv1..conv2)
  u16*   x2     = (u16*)(ws + 32*M);   // 32..40M (over ctx; conv2 out, live ..ln_out)
  u16*   seq1p  = (u16*)(ws + 40*M);   // 40..48.1M padded [8][2056][256]
  u16*   wqc    = (u16*)(ws + 49*M);   // wq|wk|wv (768x256), then wo, then w2
  u16*   woc    = wqc + 196608;
  u16*   w2c    = wqc + 262144;
  u16*   w1r    = (u16*)(ws + 50*M);   // 2359296 u16 (4.5 MB)
  u16*   params = w1r + 2359296;
  u16*   cmask  = params + 4096;
  u32*   lengths= (u32*)(cmask + 16384);

  dim3 blk(256,1,1);

  prep_big<<<dim3(13824,1,1), blk, 0, stream>>>(batch, wq, wk, wv, wo, w2, w1,
                                                batchc, wqc, w1r);
  prep_small<<<dim3(66,1,1), blk, 0, stream>>>(bq,bk,bvv,bo,g1,be1,g2,be2,b1,b2,
                                               params, mraw, cmask, lengths, seq1p);

  gemm_qkv<<<dim3(128,6,1), blk, 0, stream>>>(batchc, wqc, params, q, cmask);

  vtrans<<<dim3(256,4,1), blk, 0, stream>>>(v, VT);

  attn_fwd<<<dim3(512,1,1), blk, 0, stream>>>(q, kbuf, VT, lengths, ctx);

  gemm_nt<false,true,true,false,true><<<dim3(128,2,1), blk, 0, stream>>>(ctx, woc, params+768, (const void*)batch, (void*)tmpb, 256, cmask);
  ln_mask_b<<<dim3(4096,1,1), blk, 0, stream>>>(tmpb, params+1024, params+1280, cmask, seq1p);

  conv1_gemm<<<dim3(128,4,1), blk, 0, stream>>>(seq1p, w1r, params+2048, h, cmask, 0);
  conv1_gemm<<<dim3(128,4,1), blk, 0, stream>>>(seq1p, w1r, params+2048, h, cmask, 512);

  gemm_nt<false,true,false,true,true><<<dim3(128,2,1), blk, 0, stream>>>(h, w2c, params+3072, (const void*)seq1p, (void*)x2, 1024, cmask);
  ln_out<<<dim3(4096,1,1), blk, 0, stream>>>(x2, params+1536, params+1792, cmask, (float*)d_out);
}

// Round 17
// 314.157 us; speedup vs baseline: 1.5171x; 1.0179x over previous
//
#include <hip/hip_runtime.h>

typedef unsigned char  u8;
typedef unsigned short u16;
typedef unsigned int   u32;
typedef __attribute__((ext_vector_type(4))) float f32x4;
typedef __attribute__((ext_vector_type(8))) __bf16 bf16x8;
typedef __attribute__((ext_vector_type(4))) u32  u32x4;
typedef __attribute__((ext_vector_type(2))) u32  u32x2;

__device__ __forceinline__ float bf2f(u16 h){ u32 u = ((u32)h)<<16; return __builtin_bit_cast(float, u); }
__device__ __forceinline__ u16  f2bf(float f){
  u32 u = __builtin_bit_cast(u32, f);
  u32 r = u + 0x7FFFu + ((u>>16)&1u);
  return (u16)(r>>16);
}

typedef const __attribute__((address_space(1))) u32 gas_u32;
typedef __attribute__((address_space(3))) u32 las_u32;
__device__ __forceinline__ void gll16(const void* g, void* l){
  __builtin_amdgcn_global_load_lds((gas_u32*)g, (las_u32*)l, 16, 0, 0);
}

__device__ __forceinline__ f32x4 mfma16(bf16x8 a, bf16x8 b, f32x4 c){
  return __builtin_amdgcn_mfma_f32_16x16x32_bf16(a, b, c, 0, 0, 0);
}

__device__ __forceinline__ bf16x8 ldsr8(const u16* p){
  u32x4 v = *(const u32x4*)p;
  return __builtin_bit_cast(bf16x8, v);
}

// XCD co-locate remap: blocks sharing an A-panel (same m-tile) land on one XCD.
__device__ __forceinline__ void xcd_remap(int &m_idx, int &n_idx){
  const int Mt = gridDim.x;
  const int fid = blockIdx.x + Mt*blockIdx.y;
  const int xcd = fid & 7, k = fid >> 3;
  const int mpx = Mt >> 3;
  m_idx = xcd*mpx + (k % mpx);
  n_idx = k / mpx;
}

// ------- prologue A: batch cvt + weight cvt + conv1 weight repack -------
__global__ __launch_bounds__(256)
void prep_big(const float* __restrict__ batch,
              const float* __restrict__ wq, const float* __restrict__ wk,
              const float* __restrict__ wv, const float* __restrict__ wo,
              const float* __restrict__ w2, const float* __restrict__ w1,
              u16* __restrict__ batchc, u16* __restrict__ wqc, u16* __restrict__ w1r)
{
  const int bid = blockIdx.x, tid = threadIdx.x;
  if (bid < 4096){
    const int i = bid*1024 + tid*4;
    f32x4 v = *(const f32x4*)&batch[i];
    u32x2 o;
    o[0] = (u32)f2bf(v[0]) | ((u32)f2bf(v[1])<<16);
    o[1] = (u32)f2bf(v[2]) | ((u32)f2bf(v[3])<<16);
    *(u32x2*)&batchc[i] = o;
  } else if (bid < 4608){
    const int i = (bid-4096)*1024 + tid*4;
    const float* s; int off;
    if      (i < 65536)  { s = wq; off = i; }
    else if (i < 131072) { s = wk; off = i - 65536; }
    else if (i < 196608) { s = wv; off = i - 131072; }
    else if (i < 262144) { s = wo; off = i - 196608; }
    else                 { s = w2; off = i - 262144; }
    f32x4 v = *(const f32x4*)&s[off];
    u32x2 o;
    o[0] = (u32)f2bf(v[0]) | ((u32)f2bf(v[1])<<16);
    o[1] = (u32)f2bf(v[2]) | ((u32)f2bf(v[3])<<16);
    *(u32x2*)&wqc[i] = o;
  } else {
    const int idx = (bid-4608)*256 + tid;
    const int c = idx / 2304;
    const int t = idx - c*2304;
    const int i = t / 9;
    const int kk = t - i*9;
    w1r[c*2304 + kk*256 + i] = f2bf(w1[idx]);
  }
}

// ------- prologue B: params + mask canon + lengths + seq1p halo zero -------
__global__ __launch_bounds__(256)
void prep_small(const float* p0,const float* p1,const float* p2,const float* p3,
                const float* p4,const float* p5,const float* p6,const float* p7,
                const float* p8,const float* p9,
                u16* __restrict__ params, const void* __restrict__ mraw,
                u16* __restrict__ cmask, u32* __restrict__ lengths,
                u16* __restrict__ seq1p)
{
  const int bid = blockIdx.x, tid = threadIdx.x;
  if (bid == 0){
    const float* ps[10] = {p0,p1,p2,p3,p4,p5,p6,p7,p8,p9};
    const int  off[10] = {0,256,512,768,1024,1280,1536,1792,2048,3072};
    const int  len[10] = {256,256,256,256,256,256,256,256,1024,256};
    for (int a=0;a<10;++a)
      for (int i=tid;i<len[a];i+=256)
        params[off[a]+i] = f2bf(ps[a][i]);
  } else if (bid == 1){
    const u8*  pb8  = (const u8*)mraw;
    const u16* pb16 = (const u16*)mraw;
    const u32* pb32 = (const u32*)mraw;
    __shared__ int bad8, bad16, nz8, nz16;
    __shared__ int slen[8];
    if (tid==0){ bad8=0; bad16=0; nz8=0; nz16=0; }
    if (tid<8) slen[tid] = 2048;
    __syncthreads();
    for (int i=tid;i<16384;i+=256){
      u8 v = pb8[i]; int row = i & 2047;
      if (v>1) atomicOr(&bad8,1);
      if (v){ atomicOr(&nz8,1); if (row<1024) atomicOr(&bad8,1); }
      if (row>0 && pb8[i-1]==1 && v==0) atomicOr(&bad8,1);
    }
    for (int i=tid;i<8192;i+=256){
      u16 v = pb16[i]; int row = i & 2047;
      if (!(v==0 || v==0x3F80)) atomicOr(&bad16,1);
      if (v){ atomicOr(&nz16,1); if (row<1024) atomicOr(&bad16,1); }
      if (row>0 && pb16[i-1]==0x3F80 && v==0) atomicOr(&bad16,1);
    }
    __syncthreads();
    const int mode = (!bad8 && nz8) ? 1 : ((!bad16 && nz16) ? 2 : 0);
    for (int i=tid;i<16384;i+=256){
      u16 m;
      if (mode==1)      m = pb8[i]  ? 1 : 0;
      else if (mode==2) m = pb16[i] ? 1 : 0;
      else              m = pb32[i] ? 1 : 0;
      cmask[i] = m;
      if (m) atomicMin(&slen[i>>11], i&2047);
    }
    __syncthreads();
    if (tid<8) lengths[tid] = (u32)slen[tid];
  } else {
    const int idx = (bid-2)*256 + tid;     // 16384 halo elems
    const int b = idx>>11, t = idx&2047;
    const int r = t>>8, c = t&255;
    const int row = (r<4) ? r : (2052 + r - 4);
    seq1p[((size_t)b*2056 + row)*256 + c] = 0;
  }
}

// ------- GEMM: C = A·W^T + bias [+res]; optional padded residual; optional masked-tile skip -------
template<bool OUT_F32, bool ADD_RES, bool RES_F32, bool RES_PAD, bool SKIPM>
__global__ __launch_bounds__(256)
void gemm_nt(const u16* __restrict__ A, const u16* __restrict__ W,
             const u16* __restrict__ bias, const void* __restrict__ res,
             void* __restrict__ out, int K, const u16* __restrict__ cmask)
{
  __shared__ __align__(16) u16 aL[2][4096];
  __shared__ __align__(16) u16 bL[2][4096];
  const int tid = threadIdx.x, lane = tid&63, w = tid>>6;
  const int wm = w>>1, wn = w&1, lr = lane&15, lg = lane>>4;
  int mi, ni; xcd_remap(mi, ni);
  const int m0 = mi*128, n0 = ni*128;
  if constexpr (SKIPM){
    if (cmask[m0] != 0) return;
  }
  const int nk = K>>5;

  f32x4 acc[4][4];
#pragma unroll
  for (int i=0;i<4;++i)
#pragma unroll
    for (int j=0;j<4;++j) acc[i][j] = f32x4{0.f,0.f,0.f,0.f};

  auto stage = [&](int buf, int kk){
#pragma unroll
    for (int i=0;i<2;++i){
      const int chunk = w*2+i;
      const int boff  = chunk*1024 + lane*16;
      const int r = boff>>6;
      const int cb = (boff&63) ^ (((r>>1)&3)<<4);
      const int c = cb>>1;
      gll16(&A[(size_t)(m0+r)*K + kk*32 + c], &aL[buf][chunk*512]);
      gll16(&W[(size_t)(n0+r)*K + kk*32 + c], &bL[buf][chunk*512]);
    }
  };

  stage(0,0);
  __syncthreads();
  for (int kk=0; kk<nk; ++kk){
    if (kk+1<nk) stage((kk+1)&1, kk+1);
    const u16* ab = aL[kk&1];
    const u16* bb = bL[kk&1];
    bf16x8 af[4], bv[4];
#pragma unroll
    for (int m=0;m<4;++m){
      const int ra = wm*64+m*16+lr;
      af[m] = ldsr8(&ab[(ra*64 + ((lg*16) ^ (((ra>>1)&3)<<4)))>>1]);
    }
#pragma unroll
    for (int n=0;n<4;++n){
      const int rb = wn*64+n*16+lr;
      bv[n] = ldsr8(&bb[(rb*64 + ((lg*16) ^ (((rb>>1)&3)<<4)))>>1]);
    }
#pragma unroll
    for (int m=0;m<4;++m)
#pragma unroll
      for (int n=0;n<4;++n)
        acc[m][n] = mfma16(af[m], bv[n], acc[m][n]);
    __syncthreads();
  }
#pragma unroll
  for (int m=0;m<4;++m)
#pragma unroll
    for (int n=0;n<4;++n)
#pragma unroll
      for (int r=0;r<4;++r){
        const int row = m0 + wm*64 + m*16 + lg*4 + r;
        const int col = n0 + wn*64 + n*16 + lr;
        float v = acc[m][n][r] + bf2f(bias[col]);
        if constexpr (ADD_RES){
          size_t ri = (size_t)row*256 + col;
          if constexpr (RES_PAD) ri = ((size_t)row + (row>>11)*8 + 4)*256 + col;
          if constexpr (RES_F32) v += ((const float*)res)[ri];
          else                   v += bf2f(((const u16*)res)[ri]);
        }
        if constexpr (OUT_F32) ((float*)out)[(size_t)row*256 + col] = v;
        else                   ((u16*)out)[(size_t)row*256 + col] = f2bf(v);
      }
}

// ------- fused QKV GEMM: W = [wq;wk;wv] (768 x 256); out array picked by col>>8 -------
__global__ __launch_bounds__(256)
void gemm_qkv(const u16* __restrict__ A, const u16* __restrict__ W,
              const u16* __restrict__ bias, u16* __restrict__ qbase,
              const u16* __restrict__ cmask)
{
  __shared__ __align__(16) u16 aL[2][4096];
  __shared__ __align__(16) u16 bL[2][4096];
  const int tid = threadIdx.x, lane = tid&63, w = tid>>6;
  const int wm = w>>1, wn = w&1, lr = lane&15, lg = lane>>4;
  int mi, ni; xcd_remap(mi, ni);
  const int m0 = mi*128, n0 = ni*128;
  if (cmask[m0] != 0) return;

  f32x4 acc[4][4];
#pragma unroll
  for (int i=0;i<4;++i)
#pragma unroll
    for (int j=0;j<4;++j) acc[i][j] = f32x4{0.f,0.f,0.f,0.f};

  auto stage = [&](int buf, int kk){
#pragma unroll
    for (int i=0;i<2;++i){
      const int chunk = w*2+i;
      const int boff  = chunk*1024 + lane*16;
      const int r = boff>>6;
      const int cb = (boff&63) ^ (((r>>1)&3)<<4);
      const int c = cb>>1;
      gll16(&A[(size_t)(m0+r)*256 + kk*32 + c], &aL[buf][chunk*512]);
      gll16(&W[(size_t)(n0+r)*256 + kk*32 + c], &bL[buf][chunk*512]);
    }
  };

  stage(0,0);
  __syncthreads();
  for (int kk=0; kk<8; ++kk){
    if (kk+1<8) stage((kk+1)&1, kk+1);
    const u16* ab = aL[kk&1];
    const u16* bb = bL[kk&1];
    bf16x8 af[4], bv[4];
#pragma unroll
    for (int m=0;m<4;++m){
      const int ra = wm*64+m*16+lr;
      af[m] = ldsr8(&ab[(ra*64 + ((lg*16) ^ (((ra>>1)&3)<<4)))>>1]);
    }
#pragma unroll
    for (int n=0;n<4;++n){
      const int rb = wn*64+n*16+lr;
      bv[n] = ldsr8(&bb[(rb*64 + ((lg*16) ^ (((rb>>1)&3)<<4)))>>1]);
    }
#pragma unroll
    for (int m=0;m<4;++m)
#pragma unroll
      for (int n=0;n<4;++n)
        acc[m][n] = mfma16(af[m], bv[n], acc[m][n]);
    __syncthreads();
  }
#pragma unroll
  for (int m=0;m<4;++m)
#pragma unroll
    for (int n=0;n<4;++n)
#pragma unroll
      for (int r=0;r<4;++r){
        const int row = m0 + wm*64 + m*16 + lg*4 + r;
        const int col = n0 + wn*64 + n*16 + lr;
        const int which = col>>8, ch = col&255;
        float v = acc[m][n][r] + bf2f(bias[col]);
        qbase[(size_t)which*4194304 + (size_t)row*256 + ch] = f2bf(v);
      }
}

// ------- conv1 as m97-style GEMM over padded input: K = 2304 (tap-major) -------
__global__ __launch_bounds__(256, 4)
void conv1_gemm(const u16* __restrict__ Ap, const u16* __restrict__ W1r,
                const u16* __restrict__ b1, u16* __restrict__ Hout,
                const u16* __restrict__ cmask, int nbase)
{
  __shared__ __align__(16) u16 aL[2][4096];
  __shared__ __align__(16) u16 bL[2][4096];
  const int tid = threadIdx.x, lane = tid&63, w = tid>>6;
  const int wm = w>>1, wn = w&1, lr = lane&15, lg = lane>>4;
  int mi, ni; xcd_remap(mi, ni);
  const int m0 = mi*128, n0 = ni*128 + nbase;
  if (cmask[m0] != 0) return;
  const int b = m0>>11, s0 = m0&2047;
  const size_t abase = ((size_t)b*2056 + s0)*256;

  f32x4 acc[4][4];
#pragma unroll
  for (int i=0;i<4;++i)
#pragma unroll
    for (int j=0;j<4;++j) acc[i][j] = f32x4{0.f,0.f,0.f,0.f};

  auto stage = [&](int buf, int kk){
    const int tap = kk>>3, ch0 = (kk&7)*32;
#pragma unroll
    for (int i=0;i<2;++i){
      const int chunk = w*2+i;
      const int boff  = chunk*1024 + lane*16;
      const int r = boff>>6;
      const int cb = (boff&63) ^ (((r>>1)&3)<<4);
      const int c = cb>>1;
      gll16(&Ap[abase + (size_t)(tap + r)*256 + ch0 + c], &aL[buf][chunk*512]);
      gll16(&W1r[(size_t)(n0+r)*2304 + kk*32 + c], &bL[buf][chunk*512]);
    }
  };

  stage(0,0);
  __syncthreads();
  for (int kk=0; kk<72; ++kk){
    if (kk+1<72) stage((kk+1)&1, kk+1);
    const u16* ab = aL[kk&1];
    const u16* bb = bL[kk&1];
    bf16x8 af[4], bv[4];
#pragma unroll
    for (int m=0;m<4;++m){
      const int ra = wm*64+m*16+lr;
      af[m] = ldsr8(&ab[(ra*64 + ((lg*16) ^ (((ra>>1)&3)<<4)))>>1]);
    }
#pragma unroll
    for (int n=0;n<4;++n){
      const int rb = wn*64+n*16+lr;
      bv[n] = ldsr8(&bb[(rb*64 + ((lg*16) ^ (((rb>>1)&3)<<4)))>>1]);
    }
#pragma unroll
    for (int m=0;m<4;++m)
#pragma unroll
      for (int n=0;n<4;++n)
        acc[m][n] = mfma16(af[m], bv[n], acc[m][n]);
    __syncthreads();
  }
#pragma unroll
  for (int m=0;m<4;++m)
#pragma unroll
    for (int n=0;n<4;++n)
#pragma unroll
      for (int r=0;r<4;++r){
        const int row = m0 + wm*64 + m*16 + lg*4 + r;
        const int col = n0 + wn*64 + n*16 + lr;
        float v = acc[m][n][r] + bf2f(b1[col]);
        v = v>0.f ? v : 0.f;
        Hout[(size_t)row*1024 + col] = f2bf(v);
      }
}

// ------- V [16384][256] -> VT [b][h][128][2048] -------
__global__ __launch_bounds__(256)
void vtrans(const u16* __restrict__ V, u16* __restrict__ VT)
{
  __shared__ u16 t[64][72];
  const int tid = threadIdx.x;
  const int s0 = blockIdx.x*64;
  const int d0 = blockIdx.y*64;
#pragma unroll
  for (int i=0;i<2;++i){
    const int chunk = tid + i*256;
    const int sr = chunk>>3, c8 = (chunk&7)*8;
    u32x4 raw = *(const u32x4*)&V[(size_t)(s0+sr)*256 + d0 + c8];
#pragma unroll
    for (int j=0;j<4;++j){
      t[sr][c8+2*j]   = (u16)(raw[j]&0xffffu);
      t[sr][c8+2*j+1] = (u16)(raw[j]>>16);
    }
  }
  __syncthreads();
  const int b = s0>>11;
#pragma unroll
  for (int i=0;i<2;++i){
    const int chunk = tid + i*256;
    const int dr = chunk>>3, s8 = (chunk&7)*8;
    const int dg = d0 + dr;
    const int hh = dg>>7, dh = dg&127;
    u32x4 o;
#pragma unroll
    for (int j=0;j<4;++j)
      o[j] = (u32)t[s8+2*j][dr] | ((u32)t[s8+2*j+1][dr]<<16);
    *(u32x4*)&VT[((size_t)((b*2+hh)*128 + dh))*2048 + (s0&2047) + s8] = o;
  }
}

// ------- flash attention: KVBLK=64, dbuf gll16 staging, 1 barrier/tile, arithmetic mask -------
// flat grid 512; fid = qt*16 + pair (pair = b*2+hh): fid%8 = pair%8 -> each XCD owns
// 2 (b,h) pairs; their K/VT stripes (<=2MB) stay L2-resident on that XCD.
__global__ __launch_bounds__(256)
void attn_fwd(const u16* __restrict__ Q, const u16* __restrict__ Kb,
              const u16* __restrict__ VT, const u32* __restrict__ lengths,
              u16* __restrict__ ctx)
{
  __shared__ __align__(16) u16 kls[2][64*128];
  __shared__ __align__(16) u16 vtls[2][128*64];
  __shared__ __align__(16) u16 pls[4][16*64];
  const int tid = threadIdx.x, lane = tid&63, w = tid>>6;
  const int fid = blockIdx.x;
  const int pair = fid & 15;
  const int qt = fid >> 4;
  const int b  = pair >> 1;
  const int hh = pair & 1;
  const int q0 = qt*64;
  const int L  = (int)lengths[b];
  if (q0 >= L) return;
  const int nkt = (L + 63) >> 6;
  const int lr = lane&15, lg = lane>>4;
  u16* pw = pls[w];

  bf16x8 qf[4];
#pragma unroll
  for (int d=0;d<4;++d)
    qf[d] = *(const bf16x8*)&Q[((size_t)(b*2048+q0+w*16+lr))*256 + hh*128 + d*32 + lg*8];

  f32x4 oacc[8];
  float mrun[4], lrun[4];
#pragma unroll
  for (int n=0;n<8;++n) oacc[n] = f32x4{0.f,0.f,0.f,0.f};
#pragma unroll
  for (int r=0;r<4;++r){ mrun[r] = -1e30f; lrun[r] = 0.f; }

  const size_t kbase = (size_t)(b*2048)*256 + hh*128;
  const size_t vbase = (size_t)((b*2+hh)*128)*2048;

  auto stage = [&](int buf, int kt){
    const int kv0 = kt*64;
#pragma unroll
    for (int i=0;i<4;++i){
      const int chunk = w*4+i;
      const int boff = chunk*1024 + lane*16;
      const int r = boff>>8;
      const int cb = (boff&255) ^ ((r&7)<<4);
      gll16(&Kb[kbase + (size_t)(kv0+r)*256 + (cb>>1)], &kls[buf][chunk*512]);
    }
#pragma unroll
    for (int i=0;i<4;++i){
      const int chunk = w*4+i;
      const int boff = chunk*1024 + lane*16;
      const int r = boff>>7;
      const int cb = (boff&127) ^ ((r&7)<<4);
      gll16(&VT[vbase + (size_t)r*2048 + kv0 + (cb>>1)], &vtls[buf][chunk*512]);
    }
  };

  stage(0, 0);
  __syncthreads();

  for (int kt=0; kt<nkt; ++kt){
    const int kv0 = kt*64;
    const int buf = kt&1;
    if (kt+1 < nkt) stage(buf^1, kt+1);
    // ---- QK^T ----
    f32x4 sacc[4];
#pragma unroll
    for (int n=0;n<4;++n) sacc[n] = f32x4{0.f,0.f,0.f,0.f};
    __builtin_amdgcn_s_setprio(1);
#pragma unroll
    for (int dk=0;dk<4;++dk){
      bf16x8 bk[4];
#pragma unroll
      for (int n=0;n<4;++n){
        const int rb = n*16+lr;
        bk[n] = ldsr8(&kls[buf][(rb*256 + ((dk*64+lg*16) ^ ((rb&7)<<4)))>>1]);
      }
#pragma unroll
      for (int n=0;n<4;++n)
        sacc[n] = mfma16(qf[dk], bk[n], sacc[n]);
    }
    __builtin_amdgcn_s_setprio(0);
    // ---- scale + arithmetic key mask ----
#pragma unroll
    for (int n=0;n<4;++n){
      const float madd = (kv0 + n*16 + lr < L) ? 0.f : -1e30f;
#pragma unroll
      for (int r=0;r<4;++r)
        sacc[n][r] = sacc[n][r]*0.0625f + madd;
    }
    // ---- online softmax ----
#pragma unroll
    for (int r=0;r<4;++r){
      float rm = sacc[0][r];
#pragma unroll
      for (int n=1;n<4;++n) rm = fmaxf(rm, sacc[n][r]);
#pragma unroll
      for (int x=1;x<16;x<<=1) rm = fmaxf(rm, __shfl_xor(rm, x));
      const float mnew = fmaxf(mrun[r], rm);
      const float alpha = __expf(mrun[r] - mnew);
      float rsum = 0.f;
#pragma unroll
      for (int n=0;n<4;++n){
        float p = __expf(sacc[n][r] - mnew);
        sacc[n][r] = p;
        rsum += p;
      }
#pragma unroll
      for (int x=1;x<16;x<<=1) rsum += __shfl_xor(rsum, x);
      lrun[r] = alpha*lrun[r] + rsum;
      mrun[r] = mnew;
#pragma unroll
      for (int n=0;n<8;++n) oacc[n][r] *= alpha;
    }
    // ---- P -> per-wave LDS (same-wave only, no barrier) ----
#pragma unroll
    for (int n=0;n<4;++n)
#pragma unroll
      for (int r=0;r<4;++r){
        const int row = lg*4 + r;
        pw[(row*128 + (((n*16+lr)*2) ^ ((row&7)<<4)))>>1] = f2bf(sacc[n][r]);
      }
    // ---- PV ----
    __builtin_amdgcn_s_setprio(1);
#pragma unroll
    for (int ks=0;ks<2;++ks){
      bf16x8 pa = ldsr8(&pw[(lr*128 + ((ks*64+lg*16) ^ ((lr&7)<<4)))>>1]);
#pragma unroll
      for (int n=0;n<8;++n){
        const int rv = n*16+lr;
        bf16x8 bvv = ldsr8(&vtls[buf][(rv*128 + ((ks*64+lg*16) ^ ((rv&7)<<4)))>>1]);
        oacc[n] = mfma16(pa, bvv, oacc[n]);
      }
    }
    __builtin_amdgcn_s_setprio(0);
    __syncthreads();
  }
#pragma unroll
  for (int r=0;r<4;++r){
    const float inv = lrun[r] > 0.f ? 1.f/lrun[r] : 0.f;
    const int row = q0 + w*16 + lg*4 + r;
#pragma unroll
    for (int n=0;n<8;++n){
      const int col = hh*128 + n*16 + lr;
      ctx[((size_t)(b*2048+row))*256 + col] = f2bf(oacc[n][r]*inv);
    }
  }
}

// ------- LayerNorm + mask-zero (bf16 in -> padded bf16 out) -------
__global__ __launch_bounds__(256)
void ln_mask_b(const u16* __restrict__ X, const u16* __restrict__ g,
               const u16* __restrict__ bta, const u16* __restrict__ cmask,
               u16* __restrict__ outp)
{
  const int w = threadIdx.x>>6, lane = threadIdx.x&63;
  const int row = blockIdx.x*4 + w;
  const u16* xr = X + (size_t)row*256;
  u32x2 rawv = *(const u32x2*)&xr[lane*4];
  float xv[4];
  xv[0]=bf2f((u16)(rawv[0]&0xffffu)); xv[1]=bf2f((u16)(rawv[0]>>16));
  xv[2]=bf2f((u16)(rawv[1]&0xffffu)); xv[3]=bf2f((u16)(rawv[1]>>16));
  float s = xv[0]+xv[1]+xv[2]+xv[3];
#pragma unroll
  for (int x=1;x<64;x<<=1) s += __shfl_xor(s, x);
  const float mu = s * (1.f/256.f);
  float d[4];
#pragma unroll
  for (int j=0;j<4;++j) d[j]=xv[j]-mu;
  float sq = d[0]*d[0]+d[1]*d[1]+d[2]*d[2]+d[3]*d[3];
#pragma unroll
  for (int x=1;x<64;x<<=1) sq += __shfl_xor(sq, x);
  const float rs = rsqrtf(sq*(1.f/256.f) + 1e-5f);
  const int msk = cmask[row];
  u16 o4[4];
#pragma unroll
  for (int j=0;j<4;++j){
    const int c = lane*4 + j;
    float y = d[j]*rs*bf2f(g[c]) + bf2f(bta[c]);
    o4[j] = msk ? (u16)0 : f2bf(y);
  }
  u32x2 ov;
  ov[0] = (u32)o4[0] | ((u32)o4[1]<<16);
  ov[1] = (u32)o4[2] | ((u32)o4[3]<<16);
  const size_t prow = (size_t)row + (row>>11)*8 + 4;
  *(u32x2*)&outp[prow*256 + lane*4] = ov;
}

// ------- final LayerNorm + mask-zero (bf16 in -> f32 out) -------
__global__ __launch_bounds__(256)
void ln_out(const u16* __restrict__ X, const u16* __restrict__ g,
            const u16* __restrict__ bta, const u16* __restrict__ cmask,
            float* __restrict__ out)
{
  const int w = threadIdx.x>>6, lane = threadIdx.x&63;
  const int row = blockIdx.x*4 + w;
  const u16* xr = X + (size_t)row*256;
  u32x2 rawv = *(const u32x2*)&xr[lane*4];
  float xv[4];
  xv[0]=bf2f((u16)(rawv[0]&0xffffu)); xv[1]=bf2f((u16)(rawv[0]>>16));
  xv[2]=bf2f((u16)(rawv[1]&0xffffu)); xv[3]=bf2f((u16)(rawv[1]>>16));
  float s = xv[0]+xv[1]+xv[2]+xv[3];
#pragma unroll
  for (int x=1;x<64;x<<=1) s += __shfl_xor(s, x);
  const float mu = s * (1.f/256.f);
  float d[4];
#pragma unroll
  for (int j=0;j<4;++j) d[j]=xv[j]-mu;
  float sq = d[0]*d[0]+d[1]*d[1]+d[2]*d[2]+d[3]*d[3];
#pragma unroll
  for (int x=1;x<64;x<<=1) sq += __shfl_xor(sq, x);
  const float rs = rsqrtf(sq*(1.f/256.f) + 1e-5f);
  const int msk = cmask[row];
  f32x4 ov;
#pragma unroll
  for (int j=0;j<4;++j){
    const int c = lane*4 + j;
    float y = d[j]*rs*bf2f(g[c]) + bf2f(bta[c]);
    ov[j] = msk ? 0.f : y;
  }
  *(f32x4*)&out[(size_t)row*256 + lane*4] = ov;
}

extern "C" void kernel_launch(void* const* d_in, const int* in_sizes, int n_in,
                              void* d_out, int out_size, void* d_ws, size_t ws_size,
                              hipStream_t stream)
{
  (void)in_sizes; (void)n_in; (void)out_size; (void)ws_size;
  const float* batch=(const float*)d_in[0];  const void* mraw = d_in[1];
  const float* wq=(const float*)d_in[2];  const float* bq=(const float*)d_in[3];
  const float* wk=(const float*)d_in[4];  const float* bk=(const float*)d_in[5];
  const float* wv=(const float*)d_in[6];  const float* bvv=(const float*)d_in[7];
  const float* wo=(const float*)d_in[8];  const float* bo=(const float*)d_in[9];
  const float* g1=(const float*)d_in[10]; const float* be1=(const float*)d_in[11];
  const float* w1=(const float*)d_in[12]; const float* b1=(const float*)d_in[13];
  const float* w2=(const float*)d_in[14]; const float* b2=(const float*)d_in[15];
  const float* g2=(const float*)d_in[16]; const float* be2=(const float*)d_in[17];

  char* ws = (char*)d_ws;
  const size_t M = 1024u*1024u;
  u16*   batchc = (u16*)(ws);          // 0..8M   (dead after QKV gemm)
  u16*   VT     = (u16*)(ws);          // 0..8M   (over batchc; live vtrans..attn)
  u16*   q      = (u16*)(ws + 8*M);    // 8..16M  (dead after attn)
  u16*   tmpb   = (u16*)(ws + 8*M);    // 8..16M  (over q; outproj out, live ..ln_mask_b)
  u16*   kbuf   = (u16*)(ws + 16*M);   // 16..24M (dead after attn)
  u16*   v      = (u16*)(ws + 24*M);   // 24..32M (dead after vtrans)
  u16*   ctx    = (u16*)(ws + 32*M);   // 32..40M (dead after outproj)
  u16*   h      = (u16*)(ws);          // 0..32M  (over VT,tmpb,kbuf,v; live conv1..conv2)
  u16*   x2     = (u16*)(ws + 32*M);   // 32..40M (over ctx; conv2 out, live ..ln_out)
  u16*   seq1p  = (u16*)(ws + 40*M);   // 40..48.1M padded [8][2056][256]
  u16*   wqc    = (u16*)(ws + 49*M);   // wq|wk|wv (768x256), then wo, then w2
  u16*   woc    = wqc + 196608;
  u16*   w2c    = wqc + 262144;
  u16*   w1r    = (u16*)(ws + 50*M);   // 2359296 u16 (4.5 MB)
  u16*   params = w1r + 2359296;
  u16*   cmask  = params + 4096;
  u32*   lengths= (u32*)(cmask + 16384);

  dim3 blk(256,1,1);

  prep_big<<<dim3(13824,1,1), blk, 0, stream>>>(batch, wq, wk, wv, wo, w2, w1,
                                                batchc, wqc, w1r);
  prep_small<<<dim3(66,1,1), blk, 0, stream>>>(bq,bk,bvv,bo,g1,be1,g2,be2,b1,b2,
                                               params, mraw, cmask, lengths, seq1p);

  gemm_qkv<<<dim3(128,6,1), blk, 0, stream>>>(batchc, wqc, params, q, cmask);

  vtrans<<<dim3(256,4,1), blk, 0, stream>>>(v, VT);

  attn_fwd<<<dim3(512,1,1), blk, 0, stream>>>(q, kbuf, VT, lengths, ctx);

  gemm_nt<false,true,true,false,true><<<dim3(128,2,1), blk, 0, stream>>>(ctx, woc, params+768, (const void*)batch, (void*)tmpb, 256, cmask);
  ln_mask_b<<<dim3(4096,1,1), blk, 0, stream>>>(tmpb, params+1024, params+1280, cmask, seq1p);

  conv1_gemm<<<dim3(128,4,1), blk, 0, stream>>>(seq1p, w1r, params+2048, h, cmask, 0);
  conv1_gemm<<<dim3(128,4,1), blk, 0, stream>>>(seq1p, w1r, params+2048, h, cmask, 512);

  gemm_nt<false,true,false,true,true><<<dim3(128,2,1), blk, 0, stream>>>(h, w2c, params+3072, (const void*)seq1p, (void*)x2, 1024, cmask);
  ln_out<<<dim3(4096,1,1), blk, 0, stream>>>(x2, params+1536, params+1792, cmask, (float*)d_out);
}

// Round 18
// 292.579 us; speedup vs baseline: 1.6290x; 1.0737x over previous
//
#include <hip/hip_runtime.h>

typedef unsigned char  u8;
typedef unsigned short u16;
typedef unsigned int   u32;
typedef __attribute__((ext_vector_type(4))) float f32x4;
typedef __attribute__((ext_vector_type(8))) __bf16 bf16x8;
typedef __attribute__((ext_vector_type(4))) u32  u32x4;
typedef __attribute__((ext_vector_type(2))) u32  u32x2;

__device__ __forceinline__ float bf2f(u16 h){ u32 u = ((u32)h)<<16; return __builtin_bit_cast(float, u); }
__device__ __forceinline__ u16  f2bf(float f){
  u32 u = __builtin_bit_cast(u32, f);
  u32 r = u + 0x7FFFu + ((u>>16)&1u);
  return (u16)(r>>16);
}

typedef const __attribute__((address_space(1))) u32 gas_u32;
typedef __attribute__((address_space(3))) u32 las_u32;
__device__ __forceinline__ void gll16(const void* g, void* l){
  __builtin_amdgcn_global_load_lds((gas_u32*)g, (las_u32*)l, 16, 0, 0);
}

__device__ __forceinline__ f32x4 mfma16(bf16x8 a, bf16x8 b, f32x4 c){
  return __builtin_amdgcn_mfma_f32_16x16x32_bf16(a, b, c, 0, 0, 0);
}

__device__ __forceinline__ bf16x8 ldsr8(const u16* p){
  u32x4 v = *(const u32x4*)p;
  return __builtin_bit_cast(bf16x8, v);
}

// XCD co-locate remap: blocks sharing an A-panel (same m-tile) land on one XCD.
__device__ __forceinline__ void xcd_remap(int &m_idx, int &n_idx){
  const int Mt = gridDim.x;
  const int fid = blockIdx.x + Mt*blockIdx.y;
  const int xcd = fid & 7, k = fid >> 3;
  const int mpx = Mt >> 3;
  m_idx = xcd*mpx + (k % mpx);
  n_idx = k / mpx;
}

// ------- prologue A: batch cvt + weight cvt + conv1 weight repack -------
__global__ __launch_bounds__(256)
void prep_big(const float* __restrict__ batch,
              const float* __restrict__ wq, const float* __restrict__ wk,
              const float* __restrict__ wv, const float* __restrict__ wo,
              const float* __restrict__ w2, const float* __restrict__ w1,
              u16* __restrict__ batchc, u16* __restrict__ wqc, u16* __restrict__ w1r)
{
  const int bid = blockIdx.x, tid = threadIdx.x;
  if (bid < 4096){
    const int i = bid*1024 + tid*4;
    f32x4 v = *(const f32x4*)&batch[i];
    u32x2 o;
    o[0] = (u32)f2bf(v[0]) | ((u32)f2bf(v[1])<<16);
    o[1] = (u32)f2bf(v[2]) | ((u32)f2bf(v[3])<<16);
    *(u32x2*)&batchc[i] = o;
  } else if (bid < 4608){
    const int i = (bid-4096)*1024 + tid*4;
    const float* s; int off;
    if      (i < 65536)  { s = wq; off = i; }
    else if (i < 131072) { s = wk; off = i - 65536; }
    else if (i < 196608) { s = wv; off = i - 131072; }
    else if (i < 262144) { s = wo; off = i - 196608; }
    else                 { s = w2; off = i - 262144; }
    f32x4 v = *(const f32x4*)&s[off];
    u32x2 o;
    o[0] = (u32)f2bf(v[0]) | ((u32)f2bf(v[1])<<16);
    o[1] = (u32)f2bf(v[2]) | ((u32)f2bf(v[3])<<16);
    *(u32x2*)&wqc[i] = o;
  } else {
    const int idx = (bid-4608)*256 + tid;
    const int c = idx / 2304;
    const int t = idx - c*2304;
    const int i = t / 9;
    const int kk = t - i*9;
    w1r[c*2304 + kk*256 + i] = f2bf(w1[idx]);
  }
}

// ------- prologue B: params + mask canon + lengths + seq1p halo zero -------
__global__ __launch_bounds__(256)
void prep_small(const float* p0,const float* p1,const float* p2,const float* p3,
                const float* p4,const float* p5,const float* p6,const float* p7,
                const float* p8,const float* p9,
                u16* __restrict__ params, const void* __restrict__ mraw,
                u16* __restrict__ cmask, u32* __restrict__ lengths,
                u16* __restrict__ seq1p)
{
  const int bid = blockIdx.x, tid = threadIdx.x;
  if (bid == 0){
    const float* ps[10] = {p0,p1,p2,p3,p4,p5,p6,p7,p8,p9};
    const int  off[10] = {0,256,512,768,1024,1280,1536,1792,2048,3072};
    const int  len[10] = {256,256,256,256,256,256,256,256,1024,256};
    for (int a=0;a<10;++a)
      for (int i=tid;i<len[a];i+=256)
        params[off[a]+i] = f2bf(ps[a][i]);
  } else if (bid == 1){
    const u8*  pb8  = (const u8*)mraw;
    const u16* pb16 = (const u16*)mraw;
    const u32* pb32 = (const u32*)mraw;
    __shared__ int bad8, bad16, nz8, nz16;
    __shared__ int slen[8];
    if (tid==0){ bad8=0; bad16=0; nz8=0; nz16=0; }
    if (tid<8) slen[tid] = 2048;
    __syncthreads();
    for (int i=tid;i<16384;i+=256){
      u8 v = pb8[i]; int row = i & 2047;
      if (v>1) atomicOr(&bad8,1);
      if (v){ atomicOr(&nz8,1); if (row<1024) atomicOr(&bad8,1); }
      if (row>0 && pb8[i-1]==1 && v==0) atomicOr(&bad8,1);
    }
    for (int i=tid;i<8192;i+=256){
      u16 v = pb16[i]; int row = i & 2047;
      if (!(v==0 || v==0x3F80)) atomicOr(&bad16,1);
      if (v){ atomicOr(&nz16,1); if (row<1024) atomicOr(&bad16,1); }
      if (row>0 && pb16[i-1]==0x3F80 && v==0) atomicOr(&bad16,1);
    }
    __syncthreads();
    const int mode = (!bad8 && nz8) ? 1 : ((!bad16 && nz16) ? 2 : 0);
    for (int i=tid;i<16384;i+=256){
      u16 m;
      if (mode==1)      m = pb8[i]  ? 1 : 0;
      else if (mode==2) m = pb16[i] ? 1 : 0;
      else              m = pb32[i] ? 1 : 0;
      cmask[i] = m;
      if (m) atomicMin(&slen[i>>11], i&2047);
    }
    __syncthreads();
    if (tid<8) lengths[tid] = (u32)slen[tid];
  } else {
    const int idx = (bid-2)*256 + tid;     // 16384 halo elems
    const int b = idx>>11, t = idx&2047;
    const int r = t>>8, c = t&255;
    const int row = (r<4) ? r : (2052 + r - 4);
    seq1p[((size_t)b*2056 + row)*256 + c] = 0;
  }
}

// ------- GEMM: C = A·W^T + bias [+res]; optional padded residual; optional masked-tile skip -------
template<bool OUT_F32, bool ADD_RES, bool RES_F32, bool RES_PAD, bool SKIPM>
__global__ __launch_bounds__(256)
void gemm_nt(const u16* __restrict__ A, const u16* __restrict__ W,
             const u16* __restrict__ bias, const void* __restrict__ res,
             void* __restrict__ out, int K, const u16* __restrict__ cmask)
{
  __shared__ __align__(16) u16 aL[2][4096];
  __shared__ __align__(16) u16 bL[2][4096];
  const int tid = threadIdx.x, lane = tid&63, w = tid>>6;
  const int wm = w>>1, wn = w&1, lr = lane&15, lg = lane>>4;
  int mi, ni; xcd_remap(mi, ni);
  const int m0 = mi*128, n0 = ni*128;
  if constexpr (SKIPM){
    if (cmask[m0] != 0) return;
  }
  const int nk = K>>5;

  f32x4 acc[4][4];
#pragma unroll
  for (int i=0;i<4;++i)
#pragma unroll
    for (int j=0;j<4;++j) acc[i][j] = f32x4{0.f,0.f,0.f,0.f};

  auto stage = [&](int buf, int kk){
#pragma unroll
    for (int i=0;i<2;++i){
      const int chunk = w*2+i;
      const int boff  = chunk*1024 + lane*16;
      const int r = boff>>6;
      const int cb = (boff&63) ^ (((r>>1)&3)<<4);
      const int c = cb>>1;
      gll16(&A[(size_t)(m0+r)*K + kk*32 + c], &aL[buf][chunk*512]);
      gll16(&W[(size_t)(n0+r)*K + kk*32 + c], &bL[buf][chunk*512]);
    }
  };

  stage(0,0);
  __syncthreads();
  for (int kk=0; kk<nk; ++kk){
    if (kk+1<nk) stage((kk+1)&1, kk+1);
    const u16* ab = aL[kk&1];
    const u16* bb = bL[kk&1];
    bf16x8 af[4], bv[4];
#pragma unroll
    for (int m=0;m<4;++m){
      const int ra = wm*64+m*16+lr;
      af[m] = ldsr8(&ab[(ra*64 + ((lg*16) ^ (((ra>>1)&3)<<4)))>>1]);
    }
#pragma unroll
    for (int n=0;n<4;++n){
      const int rb = wn*64+n*16+lr;
      bv[n] = ldsr8(&bb[(rb*64 + ((lg*16) ^ (((rb>>1)&3)<<4)))>>1]);
    }
#pragma unroll
    for (int m=0;m<4;++m)
#pragma unroll
      for (int n=0;n<4;++n)
        acc[m][n] = mfma16(af[m], bv[n], acc[m][n]);
    __syncthreads();
  }
#pragma unroll
  for (int m=0;m<4;++m)
#pragma unroll
    for (int n=0;n<4;++n)
#pragma unroll
      for (int r=0;r<4;++r){
        const int row = m0 + wm*64 + m*16 + lg*4 + r;
        const int col = n0 + wn*64 + n*16 + lr;
        float v = acc[m][n][r] + bf2f(bias[col]);
        if constexpr (ADD_RES){
          size_t ri = (size_t)row*256 + col;
          if constexpr (RES_PAD) ri = ((size_t)row + (row>>11)*8 + 4)*256 + col;
          if constexpr (RES_F32) v += ((const float*)res)[ri];
          else                   v += bf2f(((const u16*)res)[ri]);
        }
        if constexpr (OUT_F32) ((float*)out)[(size_t)row*256 + col] = v;
        else                   ((u16*)out)[(size_t)row*256 + col] = f2bf(v);
      }
}

// ------- fused QKV GEMM: W = [wq;wk;wv] (768 x 256); out array picked by col>>8 -------
__global__ __launch_bounds__(256)
void gemm_qkv(const u16* __restrict__ A, const u16* __restrict__ W,
              const u16* __restrict__ bias, u16* __restrict__ qbase,
              const u16* __restrict__ cmask)
{
  __shared__ __align__(16) u16 aL[2][4096];
  __shared__ __align__(16) u16 bL[2][4096];
  const int tid = threadIdx.x, lane = tid&63, w = tid>>6;
  const int wm = w>>1, wn = w&1, lr = lane&15, lg = lane>>4;
  int mi, ni; xcd_remap(mi, ni);
  const int m0 = mi*128, n0 = ni*128;
  if (cmask[m0] != 0) return;

  f32x4 acc[4][4];
#pragma unroll
  for (int i=0;i<4;++i)
#pragma unroll
    for (int j=0;j<4;++j) acc[i][j] = f32x4{0.f,0.f,0.f,0.f};

  auto stage = [&](int buf, int kk){
#pragma unroll
    for (int i=0;i<2;++i){
      const int chunk = w*2+i;
      const int boff  = chunk*1024 + lane*16;
      const int r = boff>>6;
      const int cb = (boff&63) ^ (((r>>1)&3)<<4);
      const int c = cb>>1;
      gll16(&A[(size_t)(m0+r)*256 + kk*32 + c], &aL[buf][chunk*512]);
      gll16(&W[(size_t)(n0+r)*256 + kk*32 + c], &bL[buf][chunk*512]);
    }
  };

  stage(0,0);
  __syncthreads();
  for (int kk=0; kk<8; ++kk){
    if (kk+1<8) stage((kk+1)&1, kk+1);
    const u16* ab = aL[kk&1];
    const u16* bb = bL[kk&1];
    bf16x8 af[4], bv[4];
#pragma unroll
    for (int m=0;m<4;++m){
      const int ra = wm*64+m*16+lr;
      af[m] = ldsr8(&ab[(ra*64 + ((lg*16) ^ (((ra>>1)&3)<<4)))>>1]);
    }
#pragma unroll
    for (int n=0;n<4;++n){
      const int rb = wn*64+n*16+lr;
      bv[n] = ldsr8(&bb[(rb*64 + ((lg*16) ^ (((rb>>1)&3)<<4)))>>1]);
    }
#pragma unroll
    for (int m=0;m<4;++m)
#pragma unroll
      for (int n=0;n<4;++n)
        acc[m][n] = mfma16(af[m], bv[n], acc[m][n]);
    __syncthreads();
  }
#pragma unroll
  for (int m=0;m<4;++m)
#pragma unroll
    for (int n=0;n<4;++n)
#pragma unroll
      for (int r=0;r<4;++r){
        const int row = m0 + wm*64 + m*16 + lg*4 + r;
        const int col = n0 + wn*64 + n*16 + lr;
        const int which = col>>8, ch = col&255;
        float v = acc[m][n][r] + bf2f(bias[col]);
        qbase[(size_t)which*4194304 + (size_t)row*256 + ch] = f2bf(v);
      }
}

// ------- conv1 as m97-style GEMM over padded input: K = 2304 (tap-major) -------
__global__ __launch_bounds__(256, 4)
void conv1_gemm(const u16* __restrict__ Ap, const u16* __restrict__ W1r,
                const u16* __restrict__ b1, u16* __restrict__ Hout,
                const u16* __restrict__ cmask)
{
  __shared__ __align__(16) u16 aL[2][4096];
  __shared__ __align__(16) u16 bL[2][4096];
  const int tid = threadIdx.x, lane = tid&63, w = tid>>6;
  const int wm = w>>1, wn = w&1, lr = lane&15, lg = lane>>4;
  int mi, ni; xcd_remap(mi, ni);
  const int m0 = mi*128, n0 = ni*128;
  if (cmask[m0] != 0) return;
  const int b = m0>>11, s0 = m0&2047;
  const size_t abase = ((size_t)b*2056 + s0)*256;

  f32x4 acc[4][4];
#pragma unroll
  for (int i=0;i<4;++i)
#pragma unroll
    for (int j=0;j<4;++j) acc[i][j] = f32x4{0.f,0.f,0.f,0.f};

  auto stage = [&](int buf, int kk){
    const int tap = kk>>3, ch0 = (kk&7)*32;
#pragma unroll
    for (int i=0;i<2;++i){
      const int chunk = w*2+i;
      const int boff  = chunk*1024 + lane*16;
      const int r = boff>>6;
      const int cb = (boff&63) ^ (((r>>1)&3)<<4);
      const int c = cb>>1;
      gll16(&Ap[abase + (size_t)(tap + r)*256 + ch0 + c], &aL[buf][chunk*512]);
      gll16(&W1r[(size_t)(n0+r)*2304 + kk*32 + c], &bL[buf][chunk*512]);
    }
  };

  stage(0,0);
  __syncthreads();
  for (int kk=0; kk<72; ++kk){
    if (kk+1<72) stage((kk+1)&1, kk+1);
    const u16* ab = aL[kk&1];
    const u16* bb = bL[kk&1];
    bf16x8 af[4], bv[4];
#pragma unroll
    for (int m=0;m<4;++m){
      const int ra = wm*64+m*16+lr;
      af[m] = ldsr8(&ab[(ra*64 + ((lg*16) ^ (((ra>>1)&3)<<4)))>>1]);
    }
#pragma unroll
    for (int n=0;n<4;++n){
      const int rb = wn*64+n*16+lr;
      bv[n] = ldsr8(&bb[(rb*64 + ((lg*16) ^ (((rb>>1)&3)<<4)))>>1]);
    }
#pragma unroll
    for (int m=0;m<4;++m)
#pragma unroll
      for (int n=0;n<4;++n)
        acc[m][n] = mfma16(af[m], bv[n], acc[m][n]);
    __syncthreads();
  }
#pragma unroll
  for (int m=0;m<4;++m)
#pragma unroll
    for (int n=0;n<4;++n)
#pragma unroll
      for (int r=0;r<4;++r){
        const int row = m0 + wm*64 + m*16 + lg*4 + r;
        const int col = n0 + wn*64 + n*16 + lr;
        float v = acc[m][n][r] + bf2f(b1[col]);
        v = v>0.f ? v : 0.f;
        Hout[(size_t)row*1024 + col] = f2bf(v);
      }
}

// ------- V [16384][256] -> VT [b][h][128][2048] -------
__global__ __launch_bounds__(256)
void vtrans(const u16* __restrict__ V, u16* __restrict__ VT)
{
  __shared__ u16 t[64][72];
  const int tid = threadIdx.x;
  const int s0 = blockIdx.x*64;
  const int d0 = blockIdx.y*64;
#pragma unroll
  for (int i=0;i<2;++i){
    const int chunk = tid + i*256;
    const int sr = chunk>>3, c8 = (chunk&7)*8;
    u32x4 raw = *(const u32x4*)&V[(size_t)(s0+sr)*256 + d0 + c8];
#pragma unroll
    for (int j=0;j<4;++j){
      t[sr][c8+2*j]   = (u16)(raw[j]&0xffffu);
      t[sr][c8+2*j+1] = (u16)(raw[j]>>16);
    }
  }
  __syncthreads();
  const int b = s0>>11;
#pragma unroll
  for (int i=0;i<2;++i){
    const int chunk = tid + i*256;
    const int dr = chunk>>3, s8 = (chunk&7)*8;
    const int dg = d0 + dr;
    const int hh = dg>>7, dh = dg&127;
    u32x4 o;
#pragma unroll
    for (int j=0;j<4;++j)
      o[j] = (u32)t[s8+2*j][dr] | ((u32)t[s8+2*j+1][dr]<<16);
    *(u32x4*)&VT[((size_t)((b*2+hh)*128 + dh))*2048 + (s0&2047) + s8] = o;
  }
}

// ------- flash attention: q-tile 128, 8 waves, KVBLK=64, dbuf gll16, 1 barrier/tile -------
// flat grid 256; fid = qt*16 + pair (pair = b*2+hh): fid%8 = pair%8 -> XCD-pair locality.
__global__ __launch_bounds__(512)
void attn_fwd(const u16* __restrict__ Q, const u16* __restrict__ Kb,
              const u16* __restrict__ VT, const u32* __restrict__ lengths,
              u16* __restrict__ ctx)
{
  __shared__ __align__(16) u16 kls[2][64*128];   // K tile   (16 KB x2)
  __shared__ __align__(16) u16 vtls[2][128*64];  // V^T tile (16 KB x2)
  __shared__ __align__(16) u16 pls[8][16*64];    // per-wave P (16 KB)
  const int tid = threadIdx.x, lane = tid&63, w = tid>>6;   // w in [0,8)
  const int fid = blockIdx.x;
  const int pair = fid & 15;
  const int qt = fid >> 4;                        // [0,16)
  const int b  = pair >> 1;
  const int hh = pair & 1;
  const int q0 = qt*128;
  const int L  = (int)lengths[b];
  if (q0 >= L) return;
  const int nkt = (L + 63) >> 6;
  const int lr = lane&15, lg = lane>>4;
  u16* pw = pls[w];

  bf16x8 qf[4];
#pragma unroll
  for (int d=0;d<4;++d)
    qf[d] = *(const bf16x8*)&Q[((size_t)(b*2048+q0+w*16+lr))*256 + hh*128 + d*32 + lg*8];

  f32x4 oacc[8];
  float mrun[4], lrun[4];
#pragma unroll
  for (int n=0;n<8;++n) oacc[n] = f32x4{0.f,0.f,0.f,0.f};
#pragma unroll
  for (int r=0;r<4;++r){ mrun[r] = -1e30f; lrun[r] = 0.f; }

  const size_t kbase = (size_t)(b*2048)*256 + hh*128;
  const size_t vbase = (size_t)((b*2+hh)*128)*2048;

  auto stage = [&](int buf, int kt){
    const int kv0 = kt*64;
#pragma unroll
    for (int i=0;i<2;++i){                       // K tile: 16 chunks over 8 waves
      const int chunk = w*2+i;
      const int boff = chunk*1024 + lane*16;
      const int r = boff>>8;
      const int cb = (boff&255) ^ ((r&7)<<4);
      gll16(&Kb[kbase + (size_t)(kv0+r)*256 + (cb>>1)], &kls[buf][chunk*512]);
    }
#pragma unroll
    for (int i=0;i<2;++i){                       // VT tile: 16 chunks over 8 waves
      const int chunk = w*2+i;
      const int boff = chunk*1024 + lane*16;
      const int r = boff>>7;
      const int cb = (boff&127) ^ ((r&7)<<4);
      gll16(&VT[vbase + (size_t)r*2048 + kv0 + (cb>>1)], &vtls[buf][chunk*512]);
    }
  };

  stage(0, 0);
  __syncthreads();

  for (int kt=0; kt<nkt; ++kt){
    const int kv0 = kt*64;
    const int buf = kt&1;
    if (kt+1 < nkt) stage(buf^1, kt+1);
    // ---- QK^T ----
    f32x4 sacc[4];
#pragma unroll
    for (int n=0;n<4;++n) sacc[n] = f32x4{0.f,0.f,0.f,0.f};
    __builtin_amdgcn_s_setprio(1);
#pragma unroll
    for (int dk=0;dk<4;++dk){
      bf16x8 bk[4];
#pragma unroll
      for (int n=0;n<4;++n){
        const int rb = n*16+lr;
        bk[n] = ldsr8(&kls[buf][(rb*256 + ((dk*64+lg*16) ^ ((rb&7)<<4)))>>1]);
      }
#pragma unroll
      for (int n=0;n<4;++n)
        sacc[n] = mfma16(qf[dk], bk[n], sacc[n]);
    }
    __builtin_amdgcn_s_setprio(0);
    // ---- scale + arithmetic key mask ----
#pragma unroll
    for (int n=0;n<4;++n){
      const float madd = (kv0 + n*16 + lr < L) ? 0.f : -1e30f;
#pragma unroll
      for (int r=0;r<4;++r)
        sacc[n][r] = sacc[n][r]*0.0625f + madd;
    }
    // ---- online softmax ----
#pragma unroll
    for (int r=0;r<4;++r){
      float rm = sacc[0][r];
#pragma unroll
      for (int n=1;n<4;++n) rm = fmaxf(rm, sacc[n][r]);
#pragma unroll
      for (int x=1;x<16;x<<=1) rm = fmaxf(rm, __shfl_xor(rm, x));
      const float mnew = fmaxf(mrun[r], rm);
      const float alpha = __expf(mrun[r] - mnew);
      float rsum = 0.f;
#pragma unroll
      for (int n=0;n<4;++n){
        float p = __expf(sacc[n][r] - mnew);
        sacc[n][r] = p;
        rsum += p;
      }
#pragma unroll
      for (int x=1;x<16;x<<=1) rsum += __shfl_xor(rsum, x);
      lrun[r] = alpha*lrun[r] + rsum;
      mrun[r] = mnew;
#pragma unroll
      for (int n=0;n<8;++n) oacc[n][r] *= alpha;
    }
    // ---- P -> per-wave LDS (same-wave only, no barrier) ----
#pragma unroll
    for (int n=0;n<4;++n)
#pragma unroll
      for (int r=0;r<4;++r){
        const int row = lg*4 + r;
        pw[(row*128 + (((n*16+lr)*2) ^ ((row&7)<<4)))>>1] = f2bf(sacc[n][r]);
      }
    // ---- PV ----
    __builtin_amdgcn_s_setprio(1);
#pragma unroll
    for (int ks=0;ks<2;++ks){
      bf16x8 pa = ldsr8(&pw[(lr*128 + ((ks*64+lg*16) ^ ((lr&7)<<4)))>>1]);
#pragma unroll
      for (int n=0;n<8;++n){
        const int rv = n*16+lr;
        bf16x8 bvv = ldsr8(&vtls[buf][(rv*128 + ((ks*64+lg*16) ^ ((rv&7)<<4)))>>1]);
        oacc[n] = mfma16(pa, bvv, oacc[n]);
      }
    }
    __builtin_amdgcn_s_setprio(0);
    __syncthreads();
  }
#pragma unroll
  for (int r=0;r<4;++r){
    const float inv = lrun[r] > 0.f ? 1.f/lrun[r] : 0.f;
    const int row = q0 + w*16 + lg*4 + r;
#pragma unroll
    for (int n=0;n<8;++n){
      const int col = hh*128 + n*16 + lr;
      ctx[((size_t)(b*2048+row))*256 + col] = f2bf(oacc[n][r]*inv);
    }
  }
}

// ------- LayerNorm + mask-zero (bf16 in -> padded bf16 out) -------
__global__ __launch_bounds__(256)
void ln_mask_b(const u16* __restrict__ X, const u16* __restrict__ g,
               const u16* __restrict__ bta, const u16* __restrict__ cmask,
               u16* __restrict__ outp)
{
  const int w = threadIdx.x>>6, lane = threadIdx.x&63;
  const int row = blockIdx.x*4 + w;
  const u16* xr = X + (size_t)row*256;
  u32x2 rawv = *(const u32x2*)&xr[lane*4];
  float xv[4];
  xv[0]=bf2f((u16)(rawv[0]&0xffffu)); xv[1]=bf2f((u16)(rawv[0]>>16));
  xv[2]=bf2f((u16)(rawv[1]&0xffffu)); xv[3]=bf2f((u16)(rawv[1]>>16));
  float s = xv[0]+xv[1]+xv[2]+xv[3];
#pragma unroll
  for (int x=1;x<64;x<<=1) s += __shfl_xor(s, x);
  const float mu = s * (1.f/256.f);
  float d[4];
#pragma unroll
  for (int j=0;j<4;++j) d[j]=xv[j]-mu;
  float sq = d[0]*d[0]+d[1]*d[1]+d[2]*d[2]+d[3]*d[3];
#pragma unroll
  for (int x=1;x<64;x<<=1) sq += __shfl_xor(sq, x);
  const float rs = rsqrtf(sq*(1.f/256.f) + 1e-5f);
  const int msk = cmask[row];
  u16 o4[4];
#pragma unroll
  for (int j=0;j<4;++j){
    const int c = lane*4 + j;
    float y = d[j]*rs*bf2f(g[c]) + bf2f(bta[c]);
    o4[j] = msk ? (u16)0 : f2bf(y);
  }
  u32x2 ov;
  ov[0] = (u32)o4[0] | ((u32)o4[1]<<16);
  ov[1] = (u32)o4[2] | ((u32)o4[3]<<16);
  const size_t prow = (size_t)row + (row>>11)*8 + 4;
  *(u32x2*)&outp[prow*256 + lane*4] = ov;
}

// ------- final LayerNorm + mask-zero (bf16 in -> f32 out) -------
__global__ __launch_bounds__(256)
void ln_out(const u16* __restrict__ X, const u16* __restrict__ g,
            const u16* __restrict__ bta, const u16* __restrict__ cmask,
            float* __restrict__ out)
{
  const int w = threadIdx.x>>6, lane = threadIdx.x&63;
  const int row = blockIdx.x*4 + w;
  const u16* xr = X + (size_t)row*256;
  u32x2 rawv = *(const u32x2*)&xr[lane*4];
  float xv[4];
  xv[0]=bf2f((u16)(rawv[0]&0xffffu)); xv[1]=bf2f((u16)(rawv[0]>>16));
  xv[2]=bf2f((u16)(rawv[1]&0xffffu)); xv[3]=bf2f((u16)(rawv[1]>>16));
  float s = xv[0]+xv[1]+xv[2]+xv[3];
#pragma unroll
  for (int x=1;x<64;x<<=1) s += __shfl_xor(s, x);
  const float mu = s * (1.f/256.f);
  float d[4];
#pragma unroll
  for (int j=0;j<4;++j) d[j]=xv[j]-mu;
  float sq = d[0]*d[0]+d[1]*d[1]+d[2]*d[2]+d[3]*d[3];
#pragma unroll
  for (int x=1;x<64;x<<=1) sq += __shfl_xor(sq, x);
  const float rs = rsqrtf(sq*(1.f/256.f) + 1e-5f);
  const int msk = cmask[row];
  f32x4 ov;
#pragma unroll
  for (int j=0;j<4;++j){
    const int c = lane*4 + j;
    float y = d[j]*rs*bf2f(g[c]) + bf2f(bta[c]);
    ov[j] = msk ? 0.f : y;
  }
  *(f32x4*)&out[(size_t)row*256 + lane*4] = ov;
}

extern "C" void kernel_launch(void* const* d_in, const int* in_sizes, int n_in,
                              void* d_out, int out_size, void* d_ws, size_t ws_size,
                              hipStream_t stream)
{
  (void)in_sizes; (void)n_in; (void)out_size; (void)ws_size;
  const float* batch=(const float*)d_in[0];  const void* mraw = d_in[1];
  const float* wq=(const float*)d_in[2];  const float* bq=(const float*)d_in[3];
  const float* wk=(const float*)d_in[4];  const float* bk=(const float*)d_in[5];
  const float* wv=(const float*)d_in[6];  const float* bvv=(const float*)d_in[7];
  const float* wo=(const float*)d_in[8];  const float* bo=(const float*)d_in[9];
  const float* g1=(const float*)d_in[10]; const float* be1=(const float*)d_in[11];
  const float* w1=(const float*)d_in[12]; const float* b1=(const float*)d_in[13];
  const float* w2=(const float*)d_in[14]; const float* b2=(const float*)d_in[15];
  const float* g2=(const float*)d_in[16]; const float* be2=(const float*)d_in[17];

  char* ws = (char*)d_ws;
  const size_t M = 1024u*1024u;
  u16*   batchc = (u16*)(ws);          // 0..8M   (dead after QKV gemm)
  u16*   VT     = (u16*)(ws);          // 0..8M   (over batchc; live vtrans..attn)
  u16*   q      = (u16*)(ws + 8*M);    // 8..16M  (dead after attn)
  u16*   tmpb   = (u16*)(ws + 8*M);    // 8..16M  (over q; outproj out, live ..ln_mask_b)
  u16*   kbuf   = (u16*)(ws + 16*M);   // 16..24M (dead after attn)
  u16*   v      = (u16*)(ws + 24*M);   // 24..32M (dead after vtrans)
  u16*   ctx    = (u16*)(ws + 32*M);   // 32..40M (dead after outproj)
  u16*   h      = (u16*)(ws);          // 0..32M  (over VT,tmpb,kbuf,v; live conv1..conv2)
  u16*   x2     = (u16*)(ws + 32*M);   // 32..40M (over ctx; conv2 out, live ..ln_out)
  u16*   seq1p  = (u16*)(ws + 40*M);   // 40..48.1M padded [8][2056][256]
  u16*   wqc    = (u16*)(ws + 49*M);   // wq|wk|wv (768x256), then wo, then w2
  u16*   woc    = wqc + 196608;
  u16*   w2c    = wqc + 262144;
  u16*   w1r    = (u16*)(ws + 50*M);   // 2359296 u16 (4.5 MB)
  u16*   params = w1r + 2359296;
  u16*   cmask  = params + 4096;
  u32*   lengths= (u32*)(cmask + 16384);

  dim3 blk(256,1,1);
  dim3 blk512(512,1,1);

  prep_big<<<dim3(13824,1,1), blk, 0, stream>>>(batch, wq, wk, wv, wo, w2, w1,
                                                batchc, wqc, w1r);
  prep_small<<<dim3(66,1,1), blk, 0, stream>>>(bq,bk,bvv,bo,g1,be1,g2,be2,b1,b2,
                                               params, mraw, cmask, lengths, seq1p);

  gemm_qkv<<<dim3(128,6,1), blk, 0, stream>>>(batchc, wqc, params, q, cmask);

  vtrans<<<dim3(256,4,1), blk, 0, stream>>>(v, VT);

  attn_fwd<<<dim3(256,1,1), blk512, 0, stream>>>(q, kbuf, VT, lengths, ctx);

  gemm_nt<false,true,true,false,true><<<dim3(128,2,1), blk, 0, stream>>>(ctx, woc, params+768, (const void*)batch, (void*)tmpb, 256, cmask);
  ln_mask_b<<<dim3(4096,1,1), blk, 0, stream>>>(tmpb, params+1024, params+1280, cmask, seq1p);

  conv1_gemm<<<dim3(128,8,1), blk, 0, stream>>>(seq1p, w1r, params+2048, h, cmask);

  gemm_nt<false,true,false,true,true><<<dim3(128,2,1), blk, 0, stream>>>(h, w2c, params+3072, (const void*)seq1p, (void*)x2, 1024, cmask);
  ln_out<<<dim3(4096,1,1), blk, 0, stream>>>(x2, params+1536, params+1792, cmask, (float*)d_out);
}